// Round 2
// baseline (3682.925 us; speedup 1.0000x reference)
//
#include <hip/hip_runtime.h>
#include <hip/hip_bf16.h>

#define N_NODES 20000
#define E_EDGES 320000
#define F_INN   64
#define HID     128
#define HEADS   2
#define HC      (HEADS * HID)   // 256
#define G_GR    64
#define MIDD    32
#define EPSV    1e-5f

#define CDIV(a, b) (((a) + (b) - 1) / (b))

__device__ inline void atomicMaxFloat(float* addr, float val) {
    unsigned int* ua = (unsigned int*)addr;
    unsigned int old = __float_as_uint(*addr);
    while (!(__uint_as_float(old) >= val)) {
        unsigned int assumed = old;
        old = atomicCAS(ua, assumed, __float_as_uint(val));
        if (old == assumed) break;
    }
}

// ---------- generic utility kernels ----------
__global__ void k_fill(float* __restrict__ p, float v, int n) {
    int i = blockIdx.x * blockDim.x + threadIdx.x;
    if (i < n) p[i] = v;
}

__global__ void k_copy4(const float4* __restrict__ src, float4* __restrict__ dst, int n4) {
    int i = blockIdx.x * blockDim.x + threadIdx.x;
    if (i < n4) dst[i] = src[i];
}

// ---------- GANConv aggregation: z[row] += x[col], float4-vectorized ----------
// cq_shift = log2(C/4); thread handles one float4 of one edge
__global__ void k_edge_agg(const float4* __restrict__ x, const int* __restrict__ row,
                           const int* __restrict__ col, float* __restrict__ z, int cq_shift) {
    int idx = blockIdx.x * blockDim.x + threadIdx.x;
    int e = idx >> cq_shift;
    if (e >= E_EDGES) return;
    int q = idx & ((1 << cq_shift) - 1);
    float4 v = x[((size_t)col[e] << cq_shift) + q];
    float* p = z + ((((size_t)row[e] << cq_shift) + q) << 2);
    atomicAdd(p + 0, v.x);
    atomicAdd(p + 1, v.y);
    atomicAdd(p + 2, v.z);
    atomicAdd(p + 3, v.w);
}

// ---------- register-blocked fp32 GEMM: C = A[M,K] @ W[K,NC] + bias ----------
// 64x64 tile / block of 256 threads, 4x4 micro-tile per thread, BK=16.
__global__ __launch_bounds__(256) void k_gemm64(const float* __restrict__ A,
                                                const float* __restrict__ W,
                                                const float* __restrict__ bias,
                                                float* __restrict__ Cout,
                                                int M, int K, int NC, int relu) {
    __shared__ float As[16][68];  // [k][m], pad 68 keeps float4 alignment, 2-way banks (free)
    __shared__ float Ws[16][68];  // [k][n]
    const int t  = threadIdx.x;
    const int tx = t & 15, ty = t >> 4;
    const int row0 = blockIdx.y * 64, col0 = blockIdx.x * 64;
    // A-tile load: 64 rows x 16 k; thread: row am, k-quad ak (coalesced float4 along k)
    const int am = t >> 2, ak = (t & 3) << 2;
    // W-tile load: 16 k x 64 cols; thread: k wk, col-quad wc (coalesced float4 along n)
    const int wk = t >> 4, wc = (t & 15) << 2;
    float acc[4][4] = {{0.f}};
    for (int k0 = 0; k0 < K; k0 += 16) {
        float4 av = make_float4(0.f, 0.f, 0.f, 0.f);
        if (row0 + am < M) av = *(const float4*)&A[(size_t)(row0 + am) * K + k0 + ak];
        float4 wv = *(const float4*)&W[(size_t)(k0 + wk) * NC + col0 + wc];
        __syncthreads();
        As[ak + 0][am] = av.x; As[ak + 1][am] = av.y;
        As[ak + 2][am] = av.z; As[ak + 3][am] = av.w;
        *(float4*)&Ws[wk][wc] = wv;
        __syncthreads();
#pragma unroll
        for (int kk = 0; kk < 16; kk++) {
            float4 a = *(const float4*)&As[kk][ty << 2];
            float4 w = *(const float4*)&Ws[kk][tx << 2];
            float ar[4] = {a.x, a.y, a.z, a.w};
            float wr[4] = {w.x, w.y, w.z, w.w};
#pragma unroll
            for (int i = 0; i < 4; i++)
#pragma unroll
                for (int j = 0; j < 4; j++) acc[i][j] += ar[i] * wr[j];
        }
    }
    const float4 bv = *(const float4*)&bias[col0 + (tx << 2)];
    const float br[4] = {bv.x, bv.y, bv.z, bv.w};
#pragma unroll
    for (int i = 0; i < 4; i++) {
        int r = row0 + (ty << 2) + i;
        if (r < M) {
            float4 o;
            float* op = &o.x;
#pragma unroll
            for (int j = 0; j < 4; j++) {
                float v = acc[i][j] + br[j];
                if (relu) v = fmaxf(v, 0.f);
                op[j] = v;
            }
            *(float4*)&Cout[(size_t)r * NC + col0 + (tx << 2)] = o;
        }
    }
}

// ---------- batch norm (training mode), coalesced ----------
// Each thread's grid-stride walk keeps a constant column (stride multiple of 128).
__global__ __launch_bounds__(256) void k_bn_partial(const float* __restrict__ X, int M,
                                                    float* __restrict__ sums /* [2*HID] */) {
    __shared__ float sh[2][256];
    float s = 0.f, s2 = 0.f;
    const size_t total = (size_t)M * HID;
    for (size_t i = (size_t)blockIdx.x * blockDim.x + threadIdx.x; i < total;
         i += (size_t)gridDim.x * blockDim.x) {
        float v = X[i];
        s += v; s2 += v * v;
    }
    sh[0][threadIdx.x] = s; sh[1][threadIdx.x] = s2;
    __syncthreads();
    if (threadIdx.x < 128) {
        int c = threadIdx.x;  // column = thread index mod 128
        s  = sh[0][threadIdx.x] + sh[0][threadIdx.x + 128];
        s2 = sh[1][threadIdx.x] + sh[1][threadIdx.x + 128];
        atomicAdd(&sums[c], s);
        atomicAdd(&sums[HID + c], s2);
    }
}

__global__ void k_bn_finalize(const float* __restrict__ sums, int M,
                              float* __restrict__ mean, float* __restrict__ istd) {
    int c = threadIdx.x;  // 128 threads
    float m = sums[c] / M;
    float var = sums[HID + c] / M - m * m;
    mean[c] = m;
    istd[c] = rsqrtf(var + EPSV);
}

__global__ void k_bn_apply(float* __restrict__ X, int M, int C,
                           const float* __restrict__ mean, const float* __restrict__ istd,
                           const float* __restrict__ g, const float* __restrict__ b, int relu) {
    int idx = blockIdx.x * blockDim.x + threadIdx.x;
    if (idx >= M * C) return;
    int j = idx & (C - 1);  // C is power of two (128)
    float v = (X[idx] - mean[j]) * istd[j] * g[j] + b[j];
    if (relu) v = fmaxf(v, 0.f);
    X[idx] = v;
}

// ---------- ATTConv (GATv2-style) ----------
// Wave-per-edge: 64 lanes x float4 cover the full HC=256 row, coalesced.
// Lanes 0-31 = head 0, lanes 32-63 = head 1; half-wave butterfly reduction.
__global__ __launch_bounds__(256) void k_att_logit(const float4* __restrict__ xl,
                                                   const float4* __restrict__ xr,
                                                   const int* __restrict__ src,
                                                   const int* __restrict__ dst,
                                                   const float* __restrict__ att,
                                                   float* __restrict__ logit,
                                                   float* __restrict__ lmax) {
    int gid = blockIdx.x * blockDim.x + threadIdx.x;
    int e = gid >> 6;
    if (e >= E_EDGES) return;
    int lane = gid & 63;
    int s = src[e], d = dst[e];
    float4 a = xl[((size_t)s << 6) + lane];
    float4 b = xr[((size_t)d << 6) + lane];
    // attention vector slice for this lane: head = lane>>5, channels (lane&31)*4..+3
    float4 pa = *(const float4*)&att[((lane >> 5) * HID) + ((lane & 31) << 2)];
    float v0 = a.x + b.x; v0 = (v0 > 0.f) ? v0 : 0.2f * v0;
    float v1 = a.y + b.y; v1 = (v1 > 0.f) ? v1 : 0.2f * v1;
    float v2 = a.z + b.z; v2 = (v2 > 0.f) ? v2 : 0.2f * v2;
    float v3 = a.w + b.w; v3 = (v3 > 0.f) ? v3 : 0.2f * v3;
    float acc = pa.x * v0 + pa.y * v1 + pa.z * v2 + pa.w * v3;
#pragma unroll
    for (int m = 1; m <= 16; m <<= 1) acc += __shfl_xor(acc, m, 64);
    if ((lane & 31) == 0) {
        int h = lane >> 5;
        logit[e * HEADS + h] = acc;
        atomicMaxFloat(&lmax[(size_t)d * HEADS + h], acc);
    }
}

// w = exp(logit - lmax[dst]); denom[dst] += w   (w written in-place over logit)
__global__ void k_att_expsum(float* __restrict__ logit, const int* __restrict__ dst,
                             const float* __restrict__ lmax, float* __restrict__ denom) {
    int idx = blockIdx.x * blockDim.x + threadIdx.x;
    if (idx >= E_EDGES * HEADS) return;
    int e = idx >> 1;
    int h = idx & 1;
    float w = expf(logit[idx] - lmax[(size_t)dst[e] * HEADS + h]);
    logit[idx] = w;
    atomicAdd(&denom[(size_t)dst[e] * HEADS + h], w);
}

// alpha = w / (denom[dst] + 1e-16); optionally emit alpha to output buffer
__global__ void k_att_alpha(float* __restrict__ w, const int* __restrict__ dst,
                            const float* __restrict__ denom, float* __restrict__ alpha_out) {
    int idx = blockIdx.x * blockDim.x + threadIdx.x;
    if (idx >= E_EDGES * HEADS) return;
    int e = idx >> 1;
    int h = idx & 1;
    float a = w[idx] / (denom[(size_t)dst[e] * HEADS + h] + 1e-16f);
    w[idx] = a;
    if (alpha_out) alpha_out[idx] = a;
}

// out[dst,:] += alpha[e,h] * xl[src,:]; wave-per-edge, float4 gather, coalesced atomics
__global__ __launch_bounds__(256) void k_att_accum(const float4* __restrict__ xl,
                                                   const float* __restrict__ alpha,
                                                   const int* __restrict__ src,
                                                   const int* __restrict__ dst,
                                                   float* __restrict__ out) {
    int gid = blockIdx.x * blockDim.x + threadIdx.x;
    int e = gid >> 6;
    if (e >= E_EDGES) return;
    int lane = gid & 63;
    int h = lane >> 5;
    float a = alpha[e * HEADS + h];
    float4 v = xl[((size_t)src[e] << 6) + lane];
    float* po = out + ((size_t)dst[e] << 8) + (lane << 2);
    atomicAdd(po + 0, a * v.x);
    atomicAdd(po + 1, a * v.y);
    atomicAdd(po + 2, a * v.z);
    atomicAdd(po + 3, a * v.w);
}

// att1 finalize: emb = relu(out + bias)  (concat=True, [N, HC])
__global__ void k_att1_final(float* __restrict__ out, const float* __restrict__ bias) {
    int idx = blockIdx.x * blockDim.x + threadIdx.x;
    if (idx >= N_NODES * HC) return;
    float v = out[idx] + bias[idx & (HC - 1)];
    out[idx] = fmaxf(v, 0.f);
}

// att2 finalize: atten_out = relu(mean_h(out) + bias)  ([N, HID])
__global__ void k_att2_final(const float* __restrict__ out, const float* __restrict__ bias,
                             float* __restrict__ atten_out) {
    int idx = blockIdx.x * blockDim.x + threadIdx.x;
    if (idx >= N_NODES * HID) return;
    int n = idx >> 7;
    int c = idx & (HID - 1);
    float v = 0.5f * (out[((size_t)n << 8) + c] + out[((size_t)n << 8) + HID + c]) + bias[c];
    atten_out[idx] = fmaxf(v, 0.f);
}

// ---------- pooling: pool[batch[n], c] += X[n, c] ----------
__global__ void k_pool(const float* __restrict__ X, const int* __restrict__ batch,
                       float* __restrict__ pool, int C) {
    int idx = blockIdx.x * blockDim.x + threadIdx.x;
    if (idx >= N_NODES * C) return;
    int n = idx / C;
    int c = idx - n * C;
    atomicAdd(&pool[(size_t)batch[n] * C + c], X[idx]);
}

// ---------- final prediction head ----------
__global__ void k_head(const float* __restrict__ pool0, const float* __restrict__ poolL,
                       const float* __restrict__ p0w, const float* __restrict__ p0b,
                       const float* __restrict__ pLw, const float* __restrict__ pLb,
                       const float* __restrict__ ow, const float* __restrict__ ob,
                       float* __restrict__ outputs) {
    int g = blockIdx.x;
    int m = threadIdx.x;
    __shared__ float sh[MIDD];
    if (m < MIDD) {
        float s = p0b[m] + pLb[m];
        for (int k = 0; k < F_INN; k++) s += pool0[g * F_INN + k] * p0w[k * MIDD + m];
        for (int k = 0; k < HID; k++)  s += poolL[g * HID + k] * pLw[k * MIDD + m];
        sh[m] = fmaxf(s, 0.f);
    }
    __syncthreads();
    if (m == 0) {
        float s = ob[0];
        for (int k = 0; k < MIDD; k++) s += sh[k] * ow[k];
        outputs[g] = s;
    }
}

extern "C" void kernel_launch(void* const* d_in, const int* in_sizes, int n_in,
                              void* d_out, int out_size, void* d_ws, size_t ws_size,
                              hipStream_t stream) {
    // ---- inputs ----
    const float* x      = (const float*)d_in[0];
    const int*   ei     = (const int*)d_in[1];
    const int*   aei    = (const int*)d_in[2];
    const int*   batch  = (const int*)d_in[3];
    const float* g0_w1  = (const float*)d_in[4];
    const float* g0_b1  = (const float*)d_in[5];
    const float* g0_bng = (const float*)d_in[6];
    const float* g0_bnb = (const float*)d_in[7];
    const float* g0_w2  = (const float*)d_in[8];
    const float* g0_b2  = (const float*)d_in[9];
    const float* g1_w1  = (const float*)d_in[10];
    const float* g1_b1  = (const float*)d_in[11];
    const float* g1_bng = (const float*)d_in[12];
    const float* g1_bnb = (const float*)d_in[13];
    const float* g1_w2  = (const float*)d_in[14];
    const float* g1_b2  = (const float*)d_in[15];
    const float* bn0_g  = (const float*)d_in[16];
    const float* bn0_b  = (const float*)d_in[17];
    const float* bn1_g  = (const float*)d_in[18];
    const float* bn1_b  = (const float*)d_in[19];
    const float* a1_wl  = (const float*)d_in[20];
    const float* a1_bl  = (const float*)d_in[21];
    const float* a1_wr  = (const float*)d_in[22];
    const float* a1_br  = (const float*)d_in[23];
    const float* a1_att = (const float*)d_in[24];
    const float* a1_bias= (const float*)d_in[25];
    const float* a2_wl  = (const float*)d_in[26];
    const float* a2_bl  = (const float*)d_in[27];
    const float* a2_wr  = (const float*)d_in[28];
    const float* a2_br  = (const float*)d_in[29];
    const float* a2_att = (const float*)d_in[30];
    const float* a2_bias= (const float*)d_in[31];
    const float* p0w    = (const float*)d_in[32];
    const float* p0b    = (const float*)d_in[33];
    const float* pLw    = (const float*)d_in[34];
    const float* pLb    = (const float*)d_in[35];
    const float* ow     = (const float*)d_in[36];
    const float* ob     = (const float*)d_in[37];

    // ---- outputs ----
    float* out_head  = (float*)d_out;
    float* atten_out = out_head + G_GR;
    float* alpha_out = atten_out + (size_t)N_NODES * HID;

    // ---- workspace layout ----
    float* ws = (float*)d_ws;
    const size_t NB = (size_t)N_NODES * HC;
    float* A     = ws;
    float* B     = A + NB;
    float* Cb    = B + NB;
    float* D     = Cb + NB;
    float* logit = D + NB;
    float* lmax  = logit + (size_t)E_EDGES * HEADS;
    float* denom = lmax + (size_t)N_NODES * HEADS;
    float* mean  = denom + (size_t)N_NODES * HEADS;
    float* istd  = mean + 256;
    float* pool0 = istd + 256;
    float* poolL = pool0 + G_GR * F_INN;
    float* sums  = poolL + G_GR * HID;   // 2*HID for bn partial sums

    const int* e_row = ei;
    const int* e_col = ei + E_EDGES;
    const int* a_src = aei;
    const int* a_dst = aei + E_EDGES;

    const int TB = 256;
#define GRID1(n) dim3(CDIV((n), TB))

    // BN helper sequence (C=128 always)
#define RUN_BN(buf, gamma, beta) do { \
        hipMemsetAsync(sums, 0, 2 * HID * sizeof(float), stream); \
        hipLaunchKernelGGL(k_bn_partial, dim3(256), dim3(TB), 0, stream, (buf), N_NODES, sums); \
        hipLaunchKernelGGL(k_bn_finalize, dim3(1), dim3(HID), 0, stream, sums, N_NODES, mean, istd); \
        hipLaunchKernelGGL(k_bn_apply, GRID1(N_NODES * HID), dim3(TB), 0, stream, (buf), N_NODES, HID, mean, istd, (gamma), (beta), 1); \
    } while (0)

    // ===== GANConv 0 =====
    hipLaunchKernelGGL(k_copy4, GRID1(N_NODES * F_INN / 4), dim3(TB), 0, stream,
                       (const float4*)x, (float4*)A, N_NODES * F_INN / 4);
    hipLaunchKernelGGL(k_edge_agg, GRID1(E_EDGES * (F_INN / 4)), dim3(TB), 0, stream,
                       (const float4*)x, e_row, e_col, A, 4);
    hipLaunchKernelGGL(k_gemm64, dim3(HID / 64, CDIV(N_NODES, 64)), dim3(TB), 0, stream,
                       A, g0_w1, g0_b1, B, N_NODES, F_INN, HID, 0);
    RUN_BN(B, g0_bng, g0_bnb);
    hipLaunchKernelGGL(k_gemm64, dim3(HID / 64, CDIV(N_NODES, 64)), dim3(TB), 0, stream,
                       B, g0_w2, g0_b2, Cb, N_NODES, HID, HID, 0);
    RUN_BN(Cb, bn0_g, bn0_b);
    // h1 in Cb [N,HID]

    // ===== GANConv 1 =====
    hipLaunchKernelGGL(k_copy4, GRID1(N_NODES * HID / 4), dim3(TB), 0, stream,
                       (const float4*)Cb, (float4*)A, N_NODES * HID / 4);
    hipLaunchKernelGGL(k_edge_agg, GRID1(E_EDGES * (HID / 4)), dim3(TB), 0, stream,
                       (const float4*)Cb, e_row, e_col, A, 5);
    hipLaunchKernelGGL(k_gemm64, dim3(HID / 64, CDIV(N_NODES, 64)), dim3(TB), 0, stream,
                       A, g1_w1, g1_b1, B, N_NODES, HID, HID, 0);
    RUN_BN(B, g1_bng, g1_bnb);
    hipLaunchKernelGGL(k_gemm64, dim3(HID / 64, CDIV(N_NODES, 64)), dim3(TB), 0, stream,
                       B, g1_w2, g1_b2, A, N_NODES, HID, HID, 0);
    RUN_BN(A, bn1_g, bn1_b);
    // h2 in A [N,HID]

    // ===== ATTConv 1 (edge_index, concat=True) =====
    hipLaunchKernelGGL(k_gemm64, dim3(HC / 64, CDIV(N_NODES, 64)), dim3(TB), 0, stream,
                       A, a1_wl, a1_bl, B, N_NODES, HID, HC, 0);
    hipLaunchKernelGGL(k_gemm64, dim3(HC / 64, CDIV(N_NODES, 64)), dim3(TB), 0, stream,
                       A, a1_wr, a1_br, Cb, N_NODES, HID, HC, 0);
    hipLaunchKernelGGL(k_fill, GRID1(N_NODES * HEADS), dim3(TB), 0, stream, lmax, -INFINITY, N_NODES * HEADS);
    hipMemsetAsync(denom, 0, (size_t)N_NODES * HEADS * sizeof(float), stream);
    hipMemsetAsync(D, 0, NB * sizeof(float), stream);
    hipLaunchKernelGGL(k_att_logit, GRID1(E_EDGES * 64), dim3(TB), 0, stream,
                       (const float4*)B, (const float4*)Cb, e_row, e_col, a1_att, logit, lmax);
    hipLaunchKernelGGL(k_att_expsum, GRID1(E_EDGES * HEADS), dim3(TB), 0, stream, logit, e_col, lmax, denom);
    hipLaunchKernelGGL(k_att_alpha, GRID1(E_EDGES * HEADS), dim3(TB), 0, stream, logit, e_col, denom, (float*)nullptr);
    hipLaunchKernelGGL(k_att_accum, GRID1(E_EDGES * 64), dim3(TB), 0, stream,
                       (const float4*)B, logit, e_row, e_col, D);
    hipLaunchKernelGGL(k_att1_final, GRID1(N_NODES * HC), dim3(TB), 0, stream, D, a1_bias);
    // emb in D [N,HC]

    // ===== ATTConv 2 (atten_edge_index, concat=False) =====
    hipLaunchKernelGGL(k_gemm64, dim3(HC / 64, CDIV(N_NODES, 64)), dim3(TB), 0, stream,
                       D, a2_wl, a2_bl, B, N_NODES, HC, HC, 0);
    hipLaunchKernelGGL(k_gemm64, dim3(HC / 64, CDIV(N_NODES, 64)), dim3(TB), 0, stream,
                       D, a2_wr, a2_br, Cb, N_NODES, HC, HC, 0);
    hipLaunchKernelGGL(k_fill, GRID1(N_NODES * HEADS), dim3(TB), 0, stream, lmax, -INFINITY, N_NODES * HEADS);
    hipMemsetAsync(denom, 0, (size_t)N_NODES * HEADS * sizeof(float), stream);
    hipMemsetAsync(A, 0, NB * sizeof(float), stream);
    hipLaunchKernelGGL(k_att_logit, GRID1(E_EDGES * 64), dim3(TB), 0, stream,
                       (const float4*)B, (const float4*)Cb, a_src, a_dst, a2_att, logit, lmax);
    hipLaunchKernelGGL(k_att_expsum, GRID1(E_EDGES * HEADS), dim3(TB), 0, stream, logit, a_dst, lmax, denom);
    hipLaunchKernelGGL(k_att_alpha, GRID1(E_EDGES * HEADS), dim3(TB), 0, stream, logit, a_dst, denom, alpha_out);
    hipLaunchKernelGGL(k_att_accum, GRID1(E_EDGES * 64), dim3(TB), 0, stream,
                       (const float4*)B, logit, a_src, a_dst, A);
    hipLaunchKernelGGL(k_att2_final, GRID1(N_NODES * HID), dim3(TB), 0, stream, A, a2_bias, atten_out);

    // ===== pooling + head =====
    hipMemsetAsync(pool0, 0, (size_t)G_GR * F_INN * sizeof(float), stream);
    hipMemsetAsync(poolL, 0, (size_t)G_GR * HID * sizeof(float), stream);
    hipLaunchKernelGGL(k_pool, GRID1(N_NODES * F_INN), dim3(TB), 0, stream, x, batch, pool0, F_INN);
    hipLaunchKernelGGL(k_pool, GRID1(N_NODES * HID), dim3(TB), 0, stream, atten_out, batch, poolL, HID);
    hipLaunchKernelGGL(k_head, dim3(G_GR), dim3(64), 0, stream, pool0, poolL, p0w, p0b, pLw, pLb, ow, ob, out_head);
}

// Round 3
// 1234.668 us; speedup vs baseline: 2.9829x; 2.9829x over previous
//
#include <hip/hip_runtime.h>
#include <hip/hip_bf16.h>

#define N_NODES 20000
#define E_EDGES 320000
#define F_INN   64
#define HID     128
#define HEADS   2
#define HC      (HEADS * HID)   // 256
#define G_GR    64
#define MIDD    32
#define EPSV    1e-5f

#define CDIV(a, b) (((a) + (b) - 1) / (b))

// ================= CSR construction (per launch, on device) =================
__global__ void k_hist(const int* __restrict__ key, int* __restrict__ deg) {
    int e = blockIdx.x * blockDim.x + threadIdx.x;
    if (e < E_EDGES) atomicAdd(&deg[key[e]], 1);
}

// single-block inclusive scan of deg[0..n) -> rowptr[1..n], cursor[i]=exclusive
__global__ __launch_bounds__(1024) void k_scan20k(const int* __restrict__ deg,
                                                  int* __restrict__ rowptr,
                                                  int* __restrict__ cursor, int n) {
    __shared__ int sh[1024];
    __shared__ int carry_sh;
    int tid = threadIdx.x;
    if (tid == 0) { carry_sh = 0; rowptr[0] = 0; }
    __syncthreads();
    for (int base = 0; base < n; base += 1024) {
        int v = (base + tid < n) ? deg[base + tid] : 0;
        sh[tid] = v;
        __syncthreads();
        for (int off = 1; off < 1024; off <<= 1) {
            int t = (tid >= off) ? sh[tid - off] : 0;
            __syncthreads();
            sh[tid] += t;
            __syncthreads();
        }
        int incl = sh[tid] + carry_sh;
        if (base + tid < n) { rowptr[base + tid + 1] = incl; cursor[base + tid] = incl - v; }
        __syncthreads();
        if (tid == 1023) carry_sh = incl;
        __syncthreads();
    }
}

__global__ void k_csr_scatter(const int* __restrict__ key, const int* __restrict__ other,
                              int* __restrict__ cursor, int* __restrict__ eids,
                              int* __restrict__ srcs) {
    int e = blockIdx.x * blockDim.x + threadIdx.x;
    if (e >= E_EDGES) return;
    int pos = atomicAdd(&cursor[key[e]], 1);
    eids[pos] = e;
    srcs[pos] = other[e];
}

// ============ GANConv aggregation (gather): z[n] = x[n] + sum x[srcs] ============
__global__ __launch_bounds__(256) void k_seg_gather_add(const float4* __restrict__ x,
                                                        const int* __restrict__ rowptr,
                                                        const int* __restrict__ srcs,
                                                        float4* __restrict__ z, int cq_shift) {
    int gid = blockIdx.x * blockDim.x + threadIdx.x;
    int n = gid >> cq_shift;
    if (n >= N_NODES) return;
    int q = gid & ((1 << cq_shift) - 1);
    float4 acc = x[((size_t)n << cq_shift) + q];
    int p1 = rowptr[n + 1];
    for (int p = rowptr[n]; p < p1; p++) {
        float4 v = x[((size_t)srcs[p] << cq_shift) + q];
        acc.x += v.x; acc.y += v.y; acc.z += v.z; acc.w += v.w;
    }
    z[((size_t)n << cq_shift) + q] = acc;
}

// ================= register-blocked fp32 GEMM: C = A@W + bias =================
__global__ __launch_bounds__(256) void k_gemm64(const float* __restrict__ A,
                                                const float* __restrict__ W,
                                                const float* __restrict__ bias,
                                                float* __restrict__ Cout,
                                                int M, int K, int NC, int relu) {
    __shared__ float As[16][68];
    __shared__ float Ws[16][68];
    const int t  = threadIdx.x;
    const int tx = t & 15, ty = t >> 4;
    const int row0 = blockIdx.y * 64, col0 = blockIdx.x * 64;
    const int am = t >> 2, ak = (t & 3) << 2;
    const int wk = t >> 4, wc = (t & 15) << 2;
    float acc[4][4] = {{0.f}};
    for (int k0 = 0; k0 < K; k0 += 16) {
        float4 av = make_float4(0.f, 0.f, 0.f, 0.f);
        if (row0 + am < M) av = *(const float4*)&A[(size_t)(row0 + am) * K + k0 + ak];
        float4 wv = *(const float4*)&W[(size_t)(k0 + wk) * NC + col0 + wc];
        __syncthreads();
        As[ak + 0][am] = av.x; As[ak + 1][am] = av.y;
        As[ak + 2][am] = av.z; As[ak + 3][am] = av.w;
        *(float4*)&Ws[wk][wc] = wv;
        __syncthreads();
#pragma unroll
        for (int kk = 0; kk < 16; kk++) {
            float4 a = *(const float4*)&As[kk][ty << 2];
            float4 w = *(const float4*)&Ws[kk][tx << 2];
            float ar[4] = {a.x, a.y, a.z, a.w};
            float wr[4] = {w.x, w.y, w.z, w.w};
#pragma unroll
            for (int i = 0; i < 4; i++)
#pragma unroll
                for (int j = 0; j < 4; j++) acc[i][j] += ar[i] * wr[j];
        }
    }
    const float4 bv = *(const float4*)&bias[col0 + (tx << 2)];
    const float br[4] = {bv.x, bv.y, bv.z, bv.w};
#pragma unroll
    for (int i = 0; i < 4; i++) {
        int r = row0 + (ty << 2) + i;
        if (r < M) {
            float4 o;
            float* op = &o.x;
#pragma unroll
            for (int j = 0; j < 4; j++) {
                float v = acc[i][j] + br[j];
                if (relu) v = fmaxf(v, 0.f);
                op[j] = v;
            }
            *(float4*)&Cout[(size_t)r * NC + col0 + (tx << 2)] = o;
        }
    }
}

// ================= batch norm (training mode) =================
__global__ __launch_bounds__(256) void k_bn_partial(const float* __restrict__ X, int M,
                                                    float* __restrict__ sums) {
    __shared__ float sh[2][256];
    float s = 0.f, s2 = 0.f;
    const size_t total = (size_t)M * HID;
    for (size_t i = (size_t)blockIdx.x * blockDim.x + threadIdx.x; i < total;
         i += (size_t)gridDim.x * blockDim.x) {
        float v = X[i];
        s += v; s2 += v * v;
    }
    sh[0][threadIdx.x] = s; sh[1][threadIdx.x] = s2;
    __syncthreads();
    if (threadIdx.x < 128) {
        s  = sh[0][threadIdx.x] + sh[0][threadIdx.x + 128];
        s2 = sh[1][threadIdx.x] + sh[1][threadIdx.x + 128];
        atomicAdd(&sums[threadIdx.x], s);
        atomicAdd(&sums[HID + threadIdx.x], s2);
    }
}

__global__ void k_bn_finalize(const float* __restrict__ sums, int M,
                              float* __restrict__ mean, float* __restrict__ istd) {
    int c = threadIdx.x;
    float m = sums[c] / M;
    float var = sums[HID + c] / M - m * m;
    mean[c] = m;
    istd[c] = rsqrtf(var + EPSV);
}

__global__ void k_bn_apply(float* __restrict__ X, int M,
                           const float* __restrict__ mean, const float* __restrict__ istd,
                           const float* __restrict__ g, const float* __restrict__ b) {
    int idx = blockIdx.x * blockDim.x + threadIdx.x;
    if (idx >= M * HID) return;
    int j = idx & (HID - 1);
    float v = (X[idx] - mean[j]) * istd[j] * g[j] + b[j];
    X[idx] = fmaxf(v, 0.f);
}

// ================= ATTConv (GATv2-style) =================
// Wave-per-edge logit: 64 lanes x float4 cover HC=256; half-wave reduce per head.
__global__ __launch_bounds__(256) void k_att_logit(const float4* __restrict__ xl,
                                                   const float4* __restrict__ xr,
                                                   const int* __restrict__ src,
                                                   const int* __restrict__ dst,
                                                   const float* __restrict__ att,
                                                   float* __restrict__ logit) {
    int gid = blockIdx.x * blockDim.x + threadIdx.x;
    int e = gid >> 6;
    if (e >= E_EDGES) return;
    int lane = gid & 63;
    float4 a = xl[((size_t)src[e] << 6) + lane];
    float4 b = xr[((size_t)dst[e] << 6) + lane];
    float4 pa = *(const float4*)&att[((lane >> 5) * HID) + ((lane & 31) << 2)];
    float v0 = a.x + b.x; v0 = (v0 > 0.f) ? v0 : 0.2f * v0;
    float v1 = a.y + b.y; v1 = (v1 > 0.f) ? v1 : 0.2f * v1;
    float v2 = a.z + b.z; v2 = (v2 > 0.f) ? v2 : 0.2f * v2;
    float v3 = a.w + b.w; v3 = (v3 > 0.f) ? v3 : 0.2f * v3;
    float acc = pa.x * v0 + pa.y * v1 + pa.z * v2 + pa.w * v3;
#pragma unroll
    for (int m = 1; m <= 16; m <<= 1) acc += __shfl_xor(acc, m, 64);
    if ((lane & 31) == 0) logit[e * HEADS + (lane >> 5)] = acc;
}

// per (node,head): lmax = max over incident logits; denom = sum exp(l - lmax)
__global__ void k_att_max_denom(const float* __restrict__ logit,
                                const int* __restrict__ rowptr,
                                const int* __restrict__ eids,
                                float* __restrict__ lmax, float* __restrict__ denom) {
    int idx = blockIdx.x * blockDim.x + threadIdx.x;
    if (idx >= N_NODES * HEADS) return;
    int n = idx >> 1, h = idx & 1;
    int p0 = rowptr[n], p1 = rowptr[n + 1];
    float m = -INFINITY;
    for (int p = p0; p < p1; p++) m = fmaxf(m, logit[eids[p] * HEADS + h]);
    float s = 0.f;
    for (int p = p0; p < p1; p++) s += expf(logit[eids[p] * HEADS + h] - m);
    lmax[idx] = m;
    denom[idx] = s;
}

// per edge: alpha = exp(l - lmax[dst]) / (denom[dst] + 1e-16)
__global__ void k_att_alpha(const float* __restrict__ logit, const int* __restrict__ dst,
                            const float* __restrict__ lmax, const float* __restrict__ denom,
                            float* __restrict__ albuf, float* __restrict__ alpha_out) {
    int idx = blockIdx.x * blockDim.x + threadIdx.x;
    if (idx >= E_EDGES * HEADS) return;
    int e = idx >> 1, h = idx & 1;
    int d = dst[e] * HEADS + h;
    float a = expf(logit[idx] - lmax[d]) / (denom[d] + 1e-16f);
    albuf[idx] = a;
    if (alpha_out) alpha_out[idx] = a;
}

// att1 gather (concat): emb[n,:] = relu( sum alpha[e,h]*xl[src,:] + bias )
__global__ __launch_bounds__(256) void k_att_gather_cat(const float4* __restrict__ xl,
                                                        const float* __restrict__ albuf,
                                                        const int* __restrict__ rowptr,
                                                        const int* __restrict__ eids,
                                                        const int* __restrict__ srcs,
                                                        const float* __restrict__ bias,
                                                        float4* __restrict__ emb) {
    int gid = blockIdx.x * blockDim.x + threadIdx.x;
    int n = gid >> 6;
    if (n >= N_NODES) return;
    int lane = gid & 63;
    int h = lane >> 5;
    float4 acc = make_float4(0.f, 0.f, 0.f, 0.f);
    int p1 = rowptr[n + 1];
    for (int p = rowptr[n]; p < p1; p++) {
        float a = albuf[eids[p] * HEADS + h];
        float4 v = xl[((size_t)srcs[p] << 6) + lane];
        acc.x += a * v.x; acc.y += a * v.y; acc.z += a * v.z; acc.w += a * v.w;
    }
    float4 b = *(const float4*)&bias[lane << 2];
    acc.x = fmaxf(acc.x + b.x, 0.f); acc.y = fmaxf(acc.y + b.y, 0.f);
    acc.z = fmaxf(acc.z + b.z, 0.f); acc.w = fmaxf(acc.w + b.w, 0.f);
    emb[((size_t)n << 6) + lane] = acc;
}

// att2 gather (mean over heads): atten_out[n,:] = relu( 0.5*(h0+h1) + bias )
__global__ __launch_bounds__(256) void k_att_gather_mean(const float4* __restrict__ xl,
                                                         const float* __restrict__ albuf,
                                                         const int* __restrict__ rowptr,
                                                         const int* __restrict__ eids,
                                                         const int* __restrict__ srcs,
                                                         const float* __restrict__ bias,
                                                         float4* __restrict__ atten_out) {
    int gid = blockIdx.x * blockDim.x + threadIdx.x;
    int n = gid >> 6;
    if (n >= N_NODES) return;
    int lane = gid & 63;
    int h = lane >> 5;
    float4 acc = make_float4(0.f, 0.f, 0.f, 0.f);
    int p1 = rowptr[n + 1];
    for (int p = rowptr[n]; p < p1; p++) {
        float a = albuf[eids[p] * HEADS + h];
        float4 v = xl[((size_t)srcs[p] << 6) + lane];
        acc.x += a * v.x; acc.y += a * v.y; acc.z += a * v.z; acc.w += a * v.w;
    }
    float ox = __shfl_xor(acc.x, 32, 64);
    float oy = __shfl_xor(acc.y, 32, 64);
    float oz = __shfl_xor(acc.z, 32, 64);
    float ow4 = __shfl_xor(acc.w, 32, 64);
    if (lane < 32) {
        float4 b = *(const float4*)&bias[lane << 2];
        float4 o;
        o.x = fmaxf(0.5f * (acc.x + ox) + b.x, 0.f);
        o.y = fmaxf(0.5f * (acc.y + oy) + b.y, 0.f);
        o.z = fmaxf(0.5f * (acc.z + oz) + b.z, 0.f);
        o.w = fmaxf(0.5f * (acc.w + ow4) + b.w, 0.f);
        atten_out[((size_t)n << 5) + lane] = o;
    }
}

// ================= pooling over sorted batch_index =================
__global__ void k_gbounds(const int* __restrict__ batch, int* __restrict__ gstart) {
    int g = threadIdx.x;  // 64 threads
    int lo = 0, hi = N_NODES;
    while (lo < hi) { int mid = (lo + hi) >> 1; if (batch[mid] < g) lo = mid + 1; else hi = mid; }
    gstart[g] = lo;
    if (g == 0) gstart[G_GR] = N_NODES;
}

__global__ void k_pool_seg(const float4* __restrict__ X, const int* __restrict__ gstart,
                           float4* __restrict__ pool, int cq_shift) {
    int gid = blockIdx.x * blockDim.x + threadIdx.x;
    int g = gid >> cq_shift;
    if (g >= G_GR) return;
    int q = gid & ((1 << cq_shift) - 1);
    float4 acc = make_float4(0.f, 0.f, 0.f, 0.f);
    int i1 = gstart[g + 1];
    for (int i = gstart[g]; i < i1; i++) {
        float4 v = X[((size_t)i << cq_shift) + q];
        acc.x += v.x; acc.y += v.y; acc.z += v.z; acc.w += v.w;
    }
    pool[((size_t)g << cq_shift) + q] = acc;
}

// ================= final prediction head =================
__global__ void k_head(const float* __restrict__ pool0, const float* __restrict__ poolL,
                       const float* __restrict__ p0w, const float* __restrict__ p0b,
                       const float* __restrict__ pLw, const float* __restrict__ pLb,
                       const float* __restrict__ ow, const float* __restrict__ ob,
                       float* __restrict__ outputs) {
    int g = blockIdx.x;
    int m = threadIdx.x;
    __shared__ float sh[MIDD];
    if (m < MIDD) {
        float s = p0b[m] + pLb[m];
        for (int k = 0; k < F_INN; k++) s += pool0[g * F_INN + k] * p0w[k * MIDD + m];
        for (int k = 0; k < HID; k++)  s += poolL[g * HID + k] * pLw[k * MIDD + m];
        sh[m] = fmaxf(s, 0.f);
    }
    __syncthreads();
    if (m == 0) {
        float s = ob[0];
        for (int k = 0; k < MIDD; k++) s += sh[k] * ow[k];
        outputs[g] = s;
    }
}

extern "C" void kernel_launch(void* const* d_in, const int* in_sizes, int n_in,
                              void* d_out, int out_size, void* d_ws, size_t ws_size,
                              hipStream_t stream) {
    // ---- inputs ----
    const float* x      = (const float*)d_in[0];
    const int*   ei     = (const int*)d_in[1];
    const int*   aei    = (const int*)d_in[2];
    const int*   batch  = (const int*)d_in[3];
    const float* g0_w1  = (const float*)d_in[4];
    const float* g0_b1  = (const float*)d_in[5];
    const float* g0_bng = (const float*)d_in[6];
    const float* g0_bnb = (const float*)d_in[7];
    const float* g0_w2  = (const float*)d_in[8];
    const float* g0_b2  = (const float*)d_in[9];
    const float* g1_w1  = (const float*)d_in[10];
    const float* g1_b1  = (const float*)d_in[11];
    const float* g1_bng = (const float*)d_in[12];
    const float* g1_bnb = (const float*)d_in[13];
    const float* g1_w2  = (const float*)d_in[14];
    const float* g1_b2  = (const float*)d_in[15];
    const float* bn0_g  = (const float*)d_in[16];
    const float* bn0_b  = (const float*)d_in[17];
    const float* bn1_g  = (const float*)d_in[18];
    const float* bn1_b  = (const float*)d_in[19];
    const float* a1_wl  = (const float*)d_in[20];
    const float* a1_bl  = (const float*)d_in[21];
    const float* a1_wr  = (const float*)d_in[22];
    const float* a1_br  = (const float*)d_in[23];
    const float* a1_att = (const float*)d_in[24];
    const float* a1_bias= (const float*)d_in[25];
    const float* a2_wl  = (const float*)d_in[26];
    const float* a2_bl  = (const float*)d_in[27];
    const float* a2_wr  = (const float*)d_in[28];
    const float* a2_br  = (const float*)d_in[29];
    const float* a2_att = (const float*)d_in[30];
    const float* a2_bias= (const float*)d_in[31];
    const float* p0w    = (const float*)d_in[32];
    const float* p0b    = (const float*)d_in[33];
    const float* pLw    = (const float*)d_in[34];
    const float* pLb    = (const float*)d_in[35];
    const float* ow     = (const float*)d_in[36];
    const float* ob     = (const float*)d_in[37];

    // ---- outputs ----
    float* out_head  = (float*)d_out;
    float* atten_out = out_head + G_GR;
    float* alpha_out = atten_out + (size_t)N_NODES * HID;

    // ---- workspace: floats then ints ----
    float* ws = (float*)d_ws;
    const size_t NB = (size_t)N_NODES * HC;
    float* A     = ws;            // N x HC scratch (z / h2 / emb)
    float* B     = A + NB;        // N x HC scratch (xl)
    float* Cb    = B + NB;        // N x HC scratch (xr)
    float* logit = Cb + NB;                          // E*2
    float* albuf = logit + (size_t)E_EDGES * HEADS;  // E*2
    float* lmax  = albuf + (size_t)E_EDGES * HEADS;  // N*2
    float* denom = lmax + (size_t)N_NODES * HEADS;   // N*2
    float* mean  = denom + (size_t)N_NODES * HEADS;  // 128
    float* istd  = mean + 128;                       // 128
    float* pool0 = istd + 128;                       // G*64
    float* poolL = pool0 + G_GR * F_INN;             // G*128
    float* sums  = poolL + G_GR * HID;               // 256
    int* ip = (int*)(sums + 256);
    int* deg = ip; ip += N_NODES;
    int* gstart = ip; ip += G_GR + 1;
    // three CSRs: 0=GAN (key=ei[0]), 1=ATT1 (key=ei[1]), 2=ATT2 (key=aei[1])
    int* rowptr[3]; int* eids[3]; int* srcs[3]; int* cursor[3];
    for (int c = 0; c < 3; c++) {
        rowptr[c] = ip; ip += N_NODES + 1;
        cursor[c] = ip; ip += N_NODES;
        eids[c]   = ip; ip += E_EDGES;
        srcs[c]   = ip; ip += E_EDGES;
    }

    const int* e_row = ei;
    const int* e_col = ei + E_EDGES;
    const int* a_src = aei;
    const int* a_dst = aei + E_EDGES;

    const int TB = 256;
#define GRID1(n) dim3(CDIV((n), TB))

    // ===== build CSRs =====
    const int* keys[3]   = {e_row, e_col, a_dst};
    const int* others[3] = {e_col, e_row, a_src};
    for (int c = 0; c < 3; c++) {
        hipMemsetAsync(deg, 0, N_NODES * sizeof(int), stream);
        hipLaunchKernelGGL(k_hist, GRID1(E_EDGES), dim3(TB), 0, stream, keys[c], deg);
        hipLaunchKernelGGL(k_scan20k, dim3(1), dim3(1024), 0, stream, deg, rowptr[c], cursor[c], N_NODES);
        hipLaunchKernelGGL(k_csr_scatter, GRID1(E_EDGES), dim3(TB), 0, stream,
                           keys[c], others[c], cursor[c], eids[c], srcs[c]);
    }
    hipLaunchKernelGGL(k_gbounds, dim3(1), dim3(G_GR), 0, stream, batch, gstart);

#define RUN_BN(buf, gamma, beta) do { \
        hipMemsetAsync(sums, 0, 2 * HID * sizeof(float), stream); \
        hipLaunchKernelGGL(k_bn_partial, dim3(256), dim3(TB), 0, stream, (buf), N_NODES, sums); \
        hipLaunchKernelGGL(k_bn_finalize, dim3(1), dim3(HID), 0, stream, sums, N_NODES, mean, istd); \
        hipLaunchKernelGGL(k_bn_apply, GRID1(N_NODES * HID), dim3(TB), 0, stream, (buf), N_NODES, mean, istd, (gamma), (beta)); \
    } while (0)

    // ===== GANConv 0: z = x + gather =====
    hipLaunchKernelGGL(k_seg_gather_add, GRID1(N_NODES * (F_INN / 4)), dim3(TB), 0, stream,
                       (const float4*)x, rowptr[0], srcs[0], (float4*)A, 4);
    hipLaunchKernelGGL(k_gemm64, dim3(HID / 64, CDIV(N_NODES, 64)), dim3(TB), 0, stream,
                       A, g0_w1, g0_b1, B, N_NODES, F_INN, HID, 0);
    RUN_BN(B, g0_bng, g0_bnb);
    hipLaunchKernelGGL(k_gemm64, dim3(HID / 64, CDIV(N_NODES, 64)), dim3(TB), 0, stream,
                       B, g0_w2, g0_b2, Cb, N_NODES, HID, HID, 0);
    RUN_BN(Cb, bn0_g, bn0_b);
    // h1 in Cb [N,HID]

    // ===== GANConv 1 =====
    hipLaunchKernelGGL(k_seg_gather_add, GRID1(N_NODES * (HID / 4)), dim3(TB), 0, stream,
                       (const float4*)Cb, rowptr[0], srcs[0], (float4*)A, 5);
    hipLaunchKernelGGL(k_gemm64, dim3(HID / 64, CDIV(N_NODES, 64)), dim3(TB), 0, stream,
                       A, g1_w1, g1_b1, B, N_NODES, HID, HID, 0);
    RUN_BN(B, g1_bng, g1_bnb);
    hipLaunchKernelGGL(k_gemm64, dim3(HID / 64, CDIV(N_NODES, 64)), dim3(TB), 0, stream,
                       B, g1_w2, g1_b2, A, N_NODES, HID, HID, 0);
    RUN_BN(A, bn1_g, bn1_b);
    // h2 in A [N,HID]

    // ===== ATTConv 1 (edge_index: src=e_row, dst=e_col, concat=True) =====
    hipLaunchKernelGGL(k_gemm64, dim3(HC / 64, CDIV(N_NODES, 64)), dim3(TB), 0, stream,
                       A, a1_wl, a1_bl, B, N_NODES, HID, HC, 0);
    hipLaunchKernelGGL(k_gemm64, dim3(HC / 64, CDIV(N_NODES, 64)), dim3(TB), 0, stream,
                       A, a1_wr, a1_br, Cb, N_NODES, HID, HC, 0);
    hipLaunchKernelGGL(k_att_logit, GRID1(E_EDGES * 64), dim3(TB), 0, stream,
                       (const float4*)B, (const float4*)Cb, e_row, e_col, a1_att, logit);
    hipLaunchKernelGGL(k_att_max_denom, GRID1(N_NODES * HEADS), dim3(TB), 0, stream,
                       logit, rowptr[1], eids[1], lmax, denom);
    hipLaunchKernelGGL(k_att_alpha, GRID1(E_EDGES * HEADS), dim3(TB), 0, stream,
                       logit, e_col, lmax, denom, albuf, (float*)nullptr);
    hipLaunchKernelGGL(k_att_gather_cat, GRID1(N_NODES * 64), dim3(TB), 0, stream,
                       (const float4*)B, albuf, rowptr[1], eids[1], srcs[1], a1_bias, (float4*)A);
    // emb in A [N,HC]

    // ===== ATTConv 2 (atten_edge_index: src=a_src, dst=a_dst, concat=False) =====
    hipLaunchKernelGGL(k_gemm64, dim3(HC / 64, CDIV(N_NODES, 64)), dim3(TB), 0, stream,
                       A, a2_wl, a2_bl, B, N_NODES, HC, HC, 0);
    hipLaunchKernelGGL(k_gemm64, dim3(HC / 64, CDIV(N_NODES, 64)), dim3(TB), 0, stream,
                       A, a2_wr, a2_br, Cb, N_NODES, HC, HC, 0);
    hipLaunchKernelGGL(k_att_logit, GRID1(E_EDGES * 64), dim3(TB), 0, stream,
                       (const float4*)B, (const float4*)Cb, a_src, a_dst, a2_att, logit);
    hipLaunchKernelGGL(k_att_max_denom, GRID1(N_NODES * HEADS), dim3(TB), 0, stream,
                       logit, rowptr[2], eids[2], lmax, denom);
    hipLaunchKernelGGL(k_att_alpha, GRID1(E_EDGES * HEADS), dim3(TB), 0, stream,
                       logit, a_dst, lmax, denom, albuf, alpha_out);
    hipLaunchKernelGGL(k_att_gather_mean, GRID1(N_NODES * 64), dim3(TB), 0, stream,
                       (const float4*)B, albuf, rowptr[2], eids[2], srcs[2], a2_bias, (float4*)atten_out);

    // ===== pooling + head =====
    hipLaunchKernelGGL(k_pool_seg, GRID1(G_GR * (F_INN / 4)), dim3(TB), 0, stream,
                       (const float4*)x, gstart, (float4*)pool0, 4);
    hipLaunchKernelGGL(k_pool_seg, GRID1(G_GR * (HID / 4)), dim3(TB), 0, stream,
                       (const float4*)atten_out, gstart, (float4*)poolL, 5);
    hipLaunchKernelGGL(k_head, dim3(G_GR), dim3(64), 0, stream,
                       pool0, poolL, p0w, p0b, pLw, pLb, ow, ob, out_head);
}

// Round 4
// 1068.436 us; speedup vs baseline: 3.4470x; 1.1556x over previous
//
#include <hip/hip_runtime.h>
#include <hip/hip_bf16.h>

#define N_NODES 20000
#define E_EDGES 320000
#define F_INN   64
#define HID     128
#define HEADS   2
#define HC      (HEADS * HID)   // 256
#define G_GR    64
#define MIDD    32
#define EPSV    1e-5f

#define CDIV(a, b) (((a) + (b) - 1) / (b))

// ================= CSR construction (per launch, on device) =================
__global__ void k_hist(const int* __restrict__ key, int* __restrict__ deg) {
    int e = blockIdx.x * blockDim.x + threadIdx.x;
    if (e < E_EDGES) atomicAdd(&deg[key[e]], 1);
}

__global__ __launch_bounds__(1024) void k_scan20k(const int* __restrict__ deg,
                                                  int* __restrict__ rowptr,
                                                  int* __restrict__ cursor, int n) {
    __shared__ int sh[1024];
    __shared__ int carry_sh;
    int tid = threadIdx.x;
    if (tid == 0) { carry_sh = 0; rowptr[0] = 0; }
    __syncthreads();
    for (int base = 0; base < n; base += 1024) {
        int v = (base + tid < n) ? deg[base + tid] : 0;
        sh[tid] = v;
        __syncthreads();
        for (int off = 1; off < 1024; off <<= 1) {
            int t = (tid >= off) ? sh[tid - off] : 0;
            __syncthreads();
            sh[tid] += t;
            __syncthreads();
        }
        int incl = sh[tid] + carry_sh;
        if (base + tid < n) { rowptr[base + tid + 1] = incl; cursor[base + tid] = incl - v; }
        __syncthreads();
        if (tid == 1023) carry_sh = incl;
        __syncthreads();
    }
}

__global__ void k_csr_scatter(const int* __restrict__ key, const int* __restrict__ other,
                              int* __restrict__ cursor, int* __restrict__ eids,
                              int* __restrict__ srcs, int* __restrict__ epos) {
    int e = blockIdx.x * blockDim.x + threadIdx.x;
    if (e >= E_EDGES) return;
    int pos = atomicAdd(&cursor[key[e]], 1);
    eids[pos] = e;
    srcs[pos] = other[e];
    if (epos) epos[e] = pos;
}

// ============ GANConv aggregation (gather): z[n] = x[n] + sum x[srcs] ============
__global__ __launch_bounds__(256) void k_seg_gather_add(const float4* __restrict__ x,
                                                        const int* __restrict__ rowptr,
                                                        const int* __restrict__ srcs,
                                                        float4* __restrict__ z, int cq_shift) {
    int gid = blockIdx.x * blockDim.x + threadIdx.x;
    int n = gid >> cq_shift;
    if (n >= N_NODES) return;
    int q = gid & ((1 << cq_shift) - 1);
    float4 acc = x[((size_t)n << cq_shift) + q];
    int p1 = rowptr[n + 1];
    for (int p = rowptr[n]; p < p1; p++) {
        float4 v = x[((size_t)srcs[p] << cq_shift) + q];
        acc.x += v.x; acc.y += v.y; acc.z += v.z; acc.w += v.w;
    }
    z[((size_t)n << cq_shift) + q] = acc;
}

// ========== register-blocked fp32 GEMM: C = A[M,K] @ W[K,NC] + bias ==========
// 128x64 tile / 256 threads, 8x4 micro-tile, BK=16.
__global__ __launch_bounds__(256) void k_gemm128(const float* __restrict__ A,
                                                 const float* __restrict__ W,
                                                 const float* __restrict__ bias,
                                                 float* __restrict__ Cout,
                                                 int M, int K, int NC) {
    __shared__ float As[16][132];  // [k][m]; 132%32=4 -> 2-way on stores (free)
    __shared__ float Ws[16][68];   // [k][n]
    const int t  = threadIdx.x;
    const int tx = t & 15, ty = t >> 4;
    const int ty8 = ty << 3, tx4 = tx << 2;
    const int row0 = blockIdx.y * 128, col0 = blockIdx.x * 64;
    // A-tile: 128 rows x 16k = 512 float4, 2 per thread
    const int ar0 = t >> 2, aq = (t & 3) << 2;   // pass0: row ar0, pass1: row ar0+64
    // W-tile: 16k x 64 cols = 256 float4, 1 per thread
    const int wk = t >> 4, wc = (t & 15) << 2;
    float acc[8][4] = {{0.f}};
    for (int k0 = 0; k0 < K; k0 += 16) {
        float4 av0 = make_float4(0.f, 0.f, 0.f, 0.f);
        float4 av1 = make_float4(0.f, 0.f, 0.f, 0.f);
        if (row0 + ar0 < M)      av0 = *(const float4*)&A[(size_t)(row0 + ar0) * K + k0 + aq];
        if (row0 + ar0 + 64 < M) av1 = *(const float4*)&A[(size_t)(row0 + ar0 + 64) * K + k0 + aq];
        float4 wv = *(const float4*)&W[(size_t)(k0 + wk) * NC + col0 + wc];
        __syncthreads();
        As[aq + 0][ar0] = av0.x; As[aq + 1][ar0] = av0.y;
        As[aq + 2][ar0] = av0.z; As[aq + 3][ar0] = av0.w;
        As[aq + 0][ar0 + 64] = av1.x; As[aq + 1][ar0 + 64] = av1.y;
        As[aq + 2][ar0 + 64] = av1.z; As[aq + 3][ar0 + 64] = av1.w;
        *(float4*)&Ws[wk][wc] = wv;
        __syncthreads();
#pragma unroll
        for (int kk = 0; kk < 16; kk++) {
            float4 a0 = *(const float4*)&As[kk][ty8];
            float4 a1 = *(const float4*)&As[kk][ty8 + 4];
            float4 w  = *(const float4*)&Ws[kk][tx4];
            float ar[8] = {a0.x, a0.y, a0.z, a0.w, a1.x, a1.y, a1.z, a1.w};
            float wr[4] = {w.x, w.y, w.z, w.w};
#pragma unroll
            for (int i = 0; i < 8; i++)
#pragma unroll
                for (int j = 0; j < 4; j++) acc[i][j] += ar[i] * wr[j];
        }
    }
    const float4 bv = *(const float4*)&bias[col0 + tx4];
    const float br[4] = {bv.x, bv.y, bv.z, bv.w};
#pragma unroll
    for (int i = 0; i < 8; i++) {
        int r = row0 + ty8 + i;
        if (r < M) {
            float4 o;
            o.x = acc[i][0] + br[0]; o.y = acc[i][1] + br[1];
            o.z = acc[i][2] + br[2]; o.w = acc[i][3] + br[3];
            *(float4*)&Cout[(size_t)r * NC + col0 + tx4] = o;
        }
    }
}

// ================= batch norm (training mode) =================
__global__ __launch_bounds__(256) void k_bn_partial(const float* __restrict__ X, int M,
                                                    float* __restrict__ sums) {
    __shared__ float sh[2][256];
    float s = 0.f, s2 = 0.f;
    const size_t total = (size_t)M * HID;
    for (size_t i = (size_t)blockIdx.x * blockDim.x + threadIdx.x; i < total;
         i += (size_t)gridDim.x * blockDim.x) {
        float v = X[i];
        s += v; s2 += v * v;
    }
    sh[0][threadIdx.x] = s; sh[1][threadIdx.x] = s2;
    __syncthreads();
    if (threadIdx.x < 128) {
        s  = sh[0][threadIdx.x] + sh[0][threadIdx.x + 128];
        s2 = sh[1][threadIdx.x] + sh[1][threadIdx.x + 128];
        atomicAdd(&sums[threadIdx.x], s);
        atomicAdd(&sums[HID + threadIdx.x], s2);
    }
}

__global__ void k_bn_finalize(const float* __restrict__ sums, int M,
                              float* __restrict__ mean, float* __restrict__ istd) {
    int c = threadIdx.x;
    float m = sums[c] / M;
    float var = sums[HID + c] / M - m * m;
    mean[c] = m;
    istd[c] = rsqrtf(var + EPSV);
}

__global__ void k_bn_apply(float* __restrict__ X, int M,
                           const float* __restrict__ mean, const float* __restrict__ istd,
                           const float* __restrict__ g, const float* __restrict__ b) {
    int idx = blockIdx.x * blockDim.x + threadIdx.x;
    if (idx >= M * HID) return;
    int j = idx & (HID - 1);
    float v = (X[idx] - mean[j]) * istd[j] * g[j] + b[j];
    X[idx] = fmaxf(v, 0.f);
}

// ================= ATTConv (GATv2-style) =================
// Wave-per-edge logit, written in CSR-position order via epos.
__global__ __launch_bounds__(256) void k_att_logit(const float4* __restrict__ xl,
                                                   const float4* __restrict__ xr,
                                                   const int* __restrict__ src,
                                                   const int* __restrict__ dst,
                                                   const int* __restrict__ epos,
                                                   const float* __restrict__ att,
                                                   float* __restrict__ logit) {
    int gid = blockIdx.x * blockDim.x + threadIdx.x;
    int e = gid >> 6;
    if (e >= E_EDGES) return;
    int lane = gid & 63;
    float4 a = xl[((size_t)src[e] << 6) + lane];
    float4 b = xr[((size_t)dst[e] << 6) + lane];
    float4 pa = *(const float4*)&att[((lane >> 5) * HID) + ((lane & 31) << 2)];
    float v0 = a.x + b.x; v0 = (v0 > 0.f) ? v0 : 0.2f * v0;
    float v1 = a.y + b.y; v1 = (v1 > 0.f) ? v1 : 0.2f * v1;
    float v2 = a.z + b.z; v2 = (v2 > 0.f) ? v2 : 0.2f * v2;
    float v3 = a.w + b.w; v3 = (v3 > 0.f) ? v3 : 0.2f * v3;
    float acc = pa.x * v0 + pa.y * v1 + pa.z * v2 + pa.w * v3;
#pragma unroll
    for (int m = 1; m <= 16; m <<= 1) acc += __shfl_xor(acc, m, 64);
    if ((lane & 31) == 0) logit[epos[e] * HEADS + (lane >> 5)] = acc;
}

// per (node,head): softmax over CSR-contiguous logits -> albuf (CSR order),
// optional alpha_out scatter back to edge order.
__global__ void k_att_softmax(const float* __restrict__ logit,
                              const int* __restrict__ rowptr,
                              const int* __restrict__ eids,
                              float* __restrict__ albuf,
                              float* __restrict__ alpha_out) {
    int idx = blockIdx.x * blockDim.x + threadIdx.x;
    if (idx >= N_NODES * HEADS) return;
    int n = idx >> 1, h = idx & 1;
    int p0 = rowptr[n], p1 = rowptr[n + 1];
    float m = -INFINITY;
    for (int p = p0; p < p1; p++) m = fmaxf(m, logit[p * HEADS + h]);
    float s = 0.f;
    for (int p = p0; p < p1; p++) s += expf(logit[p * HEADS + h] - m);
    float inv = 1.f / (s + 1e-16f);
    for (int p = p0; p < p1; p++) {
        float a = expf(logit[p * HEADS + h] - m) * inv;
        albuf[p * HEADS + h] = a;
        if (alpha_out) alpha_out[eids[p] * HEADS + h] = a;
    }
}

// att1 gather (concat): emb[n,:] = relu( sum alpha*xl[src,:] + bias )
__global__ __launch_bounds__(256) void k_att_gather_cat(const float4* __restrict__ xl,
                                                        const float* __restrict__ albuf,
                                                        const int* __restrict__ rowptr,
                                                        const int* __restrict__ srcs,
                                                        const float* __restrict__ bias,
                                                        float4* __restrict__ emb) {
    int gid = blockIdx.x * blockDim.x + threadIdx.x;
    int n = gid >> 6;
    if (n >= N_NODES) return;
    int lane = gid & 63;
    int h = lane >> 5;
    float4 acc = make_float4(0.f, 0.f, 0.f, 0.f);
    int p1 = rowptr[n + 1];
    for (int p = rowptr[n]; p < p1; p++) {
        float a = albuf[p * HEADS + h];
        float4 v = xl[((size_t)srcs[p] << 6) + lane];
        acc.x += a * v.x; acc.y += a * v.y; acc.z += a * v.z; acc.w += a * v.w;
    }
    float4 b = *(const float4*)&bias[lane << 2];
    acc.x = fmaxf(acc.x + b.x, 0.f); acc.y = fmaxf(acc.y + b.y, 0.f);
    acc.z = fmaxf(acc.z + b.z, 0.f); acc.w = fmaxf(acc.w + b.w, 0.f);
    emb[((size_t)n << 6) + lane] = acc;
}

// att2 gather (mean over heads): atten_out[n,:] = relu( 0.5*(h0+h1) + bias )
__global__ __launch_bounds__(256) void k_att_gather_mean(const float4* __restrict__ xl,
                                                         const float* __restrict__ albuf,
                                                         const int* __restrict__ rowptr,
                                                         const int* __restrict__ srcs,
                                                         const float* __restrict__ bias,
                                                         float4* __restrict__ atten_out) {
    int gid = blockIdx.x * blockDim.x + threadIdx.x;
    int n = gid >> 6;
    if (n >= N_NODES) return;
    int lane = gid & 63;
    int h = lane >> 5;
    float4 acc = make_float4(0.f, 0.f, 0.f, 0.f);
    int p1 = rowptr[n + 1];
    for (int p = rowptr[n]; p < p1; p++) {
        float a = albuf[p * HEADS + h];
        float4 v = xl[((size_t)srcs[p] << 6) + lane];
        acc.x += a * v.x; acc.y += a * v.y; acc.z += a * v.z; acc.w += a * v.w;
    }
    float ox = __shfl_xor(acc.x, 32, 64);
    float oy = __shfl_xor(acc.y, 32, 64);
    float oz = __shfl_xor(acc.z, 32, 64);
    float ow4 = __shfl_xor(acc.w, 32, 64);
    if (lane < 32) {
        float4 b = *(const float4*)&bias[lane << 2];
        float4 o;
        o.x = fmaxf(0.5f * (acc.x + ox) + b.x, 0.f);
        o.y = fmaxf(0.5f * (acc.y + oy) + b.y, 0.f);
        o.z = fmaxf(0.5f * (acc.z + oz) + b.z, 0.f);
        o.w = fmaxf(0.5f * (acc.w + ow4) + b.w, 0.f);
        atten_out[((size_t)n << 5) + lane] = o;
    }
}

// ================= pooling over sorted batch_index (node-parallel) =================
// Block covers NPB node rows; thread owns column (t & (C-1)), strides rows,
// flushes register accumulator on graph boundary (batch sorted).
template <int C>
__global__ __launch_bounds__(256) void k_pool_atomic(const float* __restrict__ X,
                                                     const int* __restrict__ batch,
                                                     float* __restrict__ pool, int npb) {
    const int RP = 256 / C;
    int c = threadIdx.x & (C - 1);
    int rofs = threadIdx.x / C;
    int i0 = blockIdx.x * npb;
    int i1 = min(i0 + npb, N_NODES);
    float acc = 0.f;
    int gcur = -1;
    for (int i = i0 + rofs; i < i1; i += RP) {
        int g = batch[i];
        if (g != gcur) {
            if (gcur >= 0) atomicAdd(&pool[gcur * C + c], acc);
            acc = 0.f; gcur = g;
        }
        acc += X[(size_t)i * C + c];
    }
    if (gcur >= 0) atomicAdd(&pool[gcur * C + c], acc);
}

// ================= final prediction head =================
__global__ void k_head(const float* __restrict__ pool0, const float* __restrict__ poolL,
                       const float* __restrict__ p0w, const float* __restrict__ p0b,
                       const float* __restrict__ pLw, const float* __restrict__ pLb,
                       const float* __restrict__ ow, const float* __restrict__ ob,
                       float* __restrict__ outputs) {
    int g = blockIdx.x;
    int m = threadIdx.x;
    __shared__ float sh[MIDD];
    if (m < MIDD) {
        float s = p0b[m] + pLb[m];
        for (int k = 0; k < F_INN; k++) s += pool0[g * F_INN + k] * p0w[k * MIDD + m];
        for (int k = 0; k < HID; k++)  s += poolL[g * HID + k] * pLw[k * MIDD + m];
        sh[m] = fmaxf(s, 0.f);
    }
    __syncthreads();
    if (m == 0) {
        float s = ob[0];
        for (int k = 0; k < MIDD; k++) s += sh[k] * ow[k];
        outputs[g] = s;
    }
}

extern "C" void kernel_launch(void* const* d_in, const int* in_sizes, int n_in,
                              void* d_out, int out_size, void* d_ws, size_t ws_size,
                              hipStream_t stream) {
    // ---- inputs ----
    const float* x      = (const float*)d_in[0];
    const int*   ei     = (const int*)d_in[1];
    const int*   aei    = (const int*)d_in[2];
    const int*   batch  = (const int*)d_in[3];
    const float* g0_w1  = (const float*)d_in[4];
    const float* g0_b1  = (const float*)d_in[5];
    const float* g0_bng = (const float*)d_in[6];
    const float* g0_bnb = (const float*)d_in[7];
    const float* g0_w2  = (const float*)d_in[8];
    const float* g0_b2  = (const float*)d_in[9];
    const float* g1_w1  = (const float*)d_in[10];
    const float* g1_b1  = (const float*)d_in[11];
    const float* g1_bng = (const float*)d_in[12];
    const float* g1_bnb = (const float*)d_in[13];
    const float* g1_w2  = (const float*)d_in[14];
    const float* g1_b2  = (const float*)d_in[15];
    const float* bn0_g  = (const float*)d_in[16];
    const float* bn0_b  = (const float*)d_in[17];
    const float* bn1_g  = (const float*)d_in[18];
    const float* bn1_b  = (const float*)d_in[19];
    const float* a1_wl  = (const float*)d_in[20];
    const float* a1_bl  = (const float*)d_in[21];
    const float* a1_wr  = (const float*)d_in[22];
    const float* a1_br  = (const float*)d_in[23];
    const float* a1_att = (const float*)d_in[24];
    const float* a1_bias= (const float*)d_in[25];
    const float* a2_wl  = (const float*)d_in[26];
    const float* a2_bl  = (const float*)d_in[27];
    const float* a2_wr  = (const float*)d_in[28];
    const float* a2_br  = (const float*)d_in[29];
    const float* a2_att = (const float*)d_in[30];
    const float* a2_bias= (const float*)d_in[31];
    const float* p0w    = (const float*)d_in[32];
    const float* p0b    = (const float*)d_in[33];
    const float* pLw    = (const float*)d_in[34];
    const float* pLb    = (const float*)d_in[35];
    const float* ow     = (const float*)d_in[36];
    const float* ob     = (const float*)d_in[37];

    // ---- outputs ----
    float* out_head  = (float*)d_out;
    float* atten_out = out_head + G_GR;
    float* alpha_out = atten_out + (size_t)N_NODES * HID;

    // ---- workspace ----
    float* ws = (float*)d_ws;
    const size_t NB = (size_t)N_NODES * HC;
    float* A     = ws;
    float* B     = A + NB;
    float* Cb    = B + NB;
    float* logit = Cb + NB;                          // E*2 (CSR order)
    float* albuf = logit + (size_t)E_EDGES * HEADS;  // E*2 (CSR order)
    float* mean  = albuf + (size_t)E_EDGES * HEADS;  // 128
    float* istd  = mean + 128;
    float* pool0 = istd + 128;                       // G*64
    float* poolL = pool0 + G_GR * F_INN;             // G*128
    float* sums  = poolL + G_GR * HID;               // 256
    int* ip = (int*)(sums + 256);
    int* deg    = ip; ip += N_NODES;
    int* cursor = ip; ip += N_NODES;
    int* gstart = ip; ip += G_GR + 1;
    int* rowptr[3]; int* eids[3]; int* srcs[3];
    for (int c = 0; c < 3; c++) {
        rowptr[c] = ip; ip += N_NODES + 1;
        eids[c]   = ip; ip += E_EDGES;
        srcs[c]   = ip; ip += E_EDGES;
    }
    int* epos1 = ip; ip += E_EDGES;
    int* epos2 = ip; ip += E_EDGES;

    const int* e_row = ei;
    const int* e_col = ei + E_EDGES;
    const int* a_src = aei;
    const int* a_dst = aei + E_EDGES;

    const int TB = 256;
#define GRID1(n) dim3(CDIV((n), TB))

    // ===== build CSRs: 0=GAN(key=row), 1=ATT1(key=col), 2=ATT2(key=a_dst) =====
    const int* keys[3]   = {e_row, e_col, a_dst};
    const int* others[3] = {e_col, e_row, a_src};
    int* eposs[3] = {nullptr, epos1, epos2};
    for (int c = 0; c < 3; c++) {
        hipMemsetAsync(deg, 0, N_NODES * sizeof(int), stream);
        hipLaunchKernelGGL(k_hist, GRID1(E_EDGES), dim3(TB), 0, stream, keys[c], deg);
        hipLaunchKernelGGL(k_scan20k, dim3(1), dim3(1024), 0, stream, deg, rowptr[c], cursor, N_NODES);
        hipLaunchKernelGGL(k_csr_scatter, GRID1(E_EDGES), dim3(TB), 0, stream,
                           keys[c], others[c], cursor, eids[c], srcs[c], eposs[c]);
    }

#define RUN_BN(buf, gamma, beta) do { \
        hipMemsetAsync(sums, 0, 2 * HID * sizeof(float), stream); \
        hipLaunchKernelGGL(k_bn_partial, dim3(256), dim3(TB), 0, stream, (buf), N_NODES, sums); \
        hipLaunchKernelGGL(k_bn_finalize, dim3(1), dim3(HID), 0, stream, sums, N_NODES, mean, istd); \
        hipLaunchKernelGGL(k_bn_apply, GRID1(N_NODES * HID), dim3(TB), 0, stream, (buf), N_NODES, mean, istd, (gamma), (beta)); \
    } while (0)

    const dim3 gemm_g1(HID / 64, CDIV(N_NODES, 128));   // NC=128
    const dim3 gemm_g2(HC / 64,  CDIV(N_NODES, 128));   // NC=256

    // ===== GANConv 0 =====
    hipLaunchKernelGGL(k_seg_gather_add, GRID1(N_NODES * (F_INN / 4)), dim3(TB), 0, stream,
                       (const float4*)x, rowptr[0], srcs[0], (float4*)A, 4);
    hipLaunchKernelGGL(k_gemm128, gemm_g1, dim3(TB), 0, stream, A, g0_w1, g0_b1, B, N_NODES, F_INN, HID);
    RUN_BN(B, g0_bng, g0_bnb);
    hipLaunchKernelGGL(k_gemm128, gemm_g1, dim3(TB), 0, stream, B, g0_w2, g0_b2, Cb, N_NODES, HID, HID);
    RUN_BN(Cb, bn0_g, bn0_b);
    // h1 in Cb [N,HID]

    // ===== GANConv 1 =====
    hipLaunchKernelGGL(k_seg_gather_add, GRID1(N_NODES * (HID / 4)), dim3(TB), 0, stream,
                       (const float4*)Cb, rowptr[0], srcs[0], (float4*)A, 5);
    hipLaunchKernelGGL(k_gemm128, gemm_g1, dim3(TB), 0, stream, A, g1_w1, g1_b1, B, N_NODES, HID, HID);
    RUN_BN(B, g1_bng, g1_bnb);
    hipLaunchKernelGGL(k_gemm128, gemm_g1, dim3(TB), 0, stream, B, g1_w2, g1_b2, A, N_NODES, HID, HID);
    RUN_BN(A, bn1_g, bn1_b);
    // h2 in A [N,HID]

    // ===== ATTConv 1 (src=e_row, dst=e_col, concat=True) =====
    hipLaunchKernelGGL(k_gemm128, gemm_g2, dim3(TB), 0, stream, A, a1_wl, a1_bl, B, N_NODES, HID, HC);
    hipLaunchKernelGGL(k_gemm128, gemm_g2, dim3(TB), 0, stream, A, a1_wr, a1_br, Cb, N_NODES, HID, HC);
    hipLaunchKernelGGL(k_att_logit, GRID1(E_EDGES * 64), dim3(TB), 0, stream,
                       (const float4*)B, (const float4*)Cb, e_row, e_col, epos1, a1_att, logit);
    hipLaunchKernelGGL(k_att_softmax, GRID1(N_NODES * HEADS), dim3(TB), 0, stream,
                       logit, rowptr[1], eids[1], albuf, (float*)nullptr);
    hipLaunchKernelGGL(k_att_gather_cat, GRID1(N_NODES * 64), dim3(TB), 0, stream,
                       (const float4*)B, albuf, rowptr[1], srcs[1], a1_bias, (float4*)A);
    // emb in A [N,HC]

    // ===== ATTConv 2 (src=a_src, dst=a_dst, concat=False) =====
    hipLaunchKernelGGL(k_gemm128, gemm_g2, dim3(TB), 0, stream, A, a2_wl, a2_bl, B, N_NODES, HC, HC);
    hipLaunchKernelGGL(k_gemm128, gemm_g2, dim3(TB), 0, stream, A, a2_wr, a2_br, Cb, N_NODES, HC, HC);
    hipLaunchKernelGGL(k_att_logit, GRID1(E_EDGES * 64), dim3(TB), 0, stream,
                       (const float4*)B, (const float4*)Cb, a_src, a_dst, epos2, a2_att, logit);
    hipLaunchKernelGGL(k_att_softmax, GRID1(N_NODES * HEADS), dim3(TB), 0, stream,
                       logit, rowptr[2], eids[2], albuf, alpha_out);
    hipLaunchKernelGGL(k_att_gather_mean, GRID1(N_NODES * 64), dim3(TB), 0, stream,
                       (const float4*)B, albuf, rowptr[2], srcs[2], a2_bias, (float4*)atten_out);

    // ===== pooling + head =====
    hipMemsetAsync(pool0, 0, (size_t)G_GR * F_INN * sizeof(float), stream);
    hipMemsetAsync(poolL, 0, (size_t)G_GR * HID * sizeof(float), stream);
    {
        const int npb = 64;  // 313 blocks
        hipLaunchKernelGGL(k_pool_atomic<F_INN>, dim3(CDIV(N_NODES, npb)), dim3(TB), 0, stream,
                           x, batch, pool0, npb);
        hipLaunchKernelGGL(k_pool_atomic<HID>, dim3(CDIV(N_NODES, npb)), dim3(TB), 0, stream,
                           atten_out, batch, poolL, npb);
    }
    hipLaunchKernelGGL(k_head, dim3(G_GR), dim3(64), 0, stream,
                       pool0, poolL, p0w, p0b, pLw, pLb, ow, ob, out_head);
}

// Round 5
// 987.341 us; speedup vs baseline: 3.7301x; 1.0821x over previous
//
#include <hip/hip_runtime.h>
#include <hip/hip_bf16.h>

#define N_NODES 20000
#define E_EDGES 320000
#define F_INN   64
#define HID     128
#define HEADS   2
#define HC      (HEADS * HID)   // 256
#define G_GR    64
#define MIDD    32
#define EPSV    1e-5f

#define CDIV(a, b) (((a) + (b) - 1) / (b))

// ---------- bf16 helpers (RNE) ----------
__device__ inline float bf2f(unsigned short u) { return __uint_as_float((unsigned)u << 16); }
__device__ inline unsigned short f2bf(float f) {
    unsigned u = __float_as_uint(f);
    unsigned r = u + 0x7FFFu + ((u >> 16) & 1u);
    return (unsigned short)(r >> 16);
}
__device__ inline float4 bf4_to_f4(ushort4 u) {
    return make_float4(bf2f(u.x), bf2f(u.y), bf2f(u.z), bf2f(u.w));
}

// ================= CSR construction (per launch, on device) =================
__global__ void k_hist(const int* __restrict__ key, int* __restrict__ deg) {
    int e = blockIdx.x * blockDim.x + threadIdx.x;
    if (e < E_EDGES) atomicAdd(&deg[key[e]], 1);
}

__global__ __launch_bounds__(1024) void k_scan20k(const int* __restrict__ deg,
                                                  int* __restrict__ rowptr,
                                                  int* __restrict__ cursor, int n) {
    __shared__ int sh[1024];
    __shared__ int carry_sh;
    int tid = threadIdx.x;
    if (tid == 0) { carry_sh = 0; rowptr[0] = 0; }
    __syncthreads();
    for (int base = 0; base < n; base += 1024) {
        int v = (base + tid < n) ? deg[base + tid] : 0;
        sh[tid] = v;
        __syncthreads();
        for (int off = 1; off < 1024; off <<= 1) {
            int t = (tid >= off) ? sh[tid - off] : 0;
            __syncthreads();
            sh[tid] += t;
            __syncthreads();
        }
        int incl = sh[tid] + carry_sh;
        if (base + tid < n) { rowptr[base + tid + 1] = incl; cursor[base + tid] = incl - v; }
        __syncthreads();
        if (tid == 1023) carry_sh = incl;
        __syncthreads();
    }
}

__global__ void k_csr_scatter(const int* __restrict__ key, const int* __restrict__ other,
                              int* __restrict__ cursor, int* __restrict__ eids,
                              int* __restrict__ srcs, int* __restrict__ pnode) {
    int e = blockIdx.x * blockDim.x + threadIdx.x;
    if (e >= E_EDGES) return;
    int k = key[e];
    int pos = atomicAdd(&cursor[k], 1);
    eids[pos] = e;
    srcs[pos] = other[e];
    if (pnode) pnode[pos] = k;
}

// ============ GANConv aggregation (gather): z[n] = x[n] + sum x[srcs] ============
__global__ __launch_bounds__(256) void k_seg_gather_add(const float4* __restrict__ x,
                                                        const int* __restrict__ rowptr,
                                                        const int* __restrict__ srcs,
                                                        float4* __restrict__ z, int cq_shift) {
    int gid = blockIdx.x * blockDim.x + threadIdx.x;
    int n = gid >> cq_shift;
    if (n >= N_NODES) return;
    int q = gid & ((1 << cq_shift) - 1);
    float4 acc = x[((size_t)n << cq_shift) + q];
    int p1 = rowptr[n + 1];
    for (int p = rowptr[n]; p < p1; p++) {
        float4 v = x[((size_t)srcs[p] << cq_shift) + q];
        acc.x += v.x; acc.y += v.y; acc.z += v.z; acc.w += v.w;
    }
    z[((size_t)n << cq_shift) + q] = acc;
}

// ========== register-blocked fp32 GEMM: C = A[M,K] @ W[K,NC] + bias ==========
// 128x64 tile / 256 threads, 8x4 micro-tile, BK=16. BF16_OUT writes bf16.
template <int BF16_OUT>
__global__ __launch_bounds__(256) void k_gemm128(const float* __restrict__ A,
                                                 const float* __restrict__ W,
                                                 const float* __restrict__ bias,
                                                 void* __restrict__ Cout,
                                                 int M, int K, int NC) {
    __shared__ float As[16][132];
    __shared__ float Ws[16][68];
    const int t  = threadIdx.x;
    const int tx = t & 15, ty = t >> 4;
    const int ty8 = ty << 3, tx4 = tx << 2;
    const int row0 = blockIdx.y * 128, col0 = blockIdx.x * 64;
    const int ar0 = t >> 2, aq = (t & 3) << 2;
    const int wk = t >> 4, wc = (t & 15) << 2;
    float acc[8][4] = {{0.f}};
    for (int k0 = 0; k0 < K; k0 += 16) {
        float4 av0 = make_float4(0.f, 0.f, 0.f, 0.f);
        float4 av1 = make_float4(0.f, 0.f, 0.f, 0.f);
        if (row0 + ar0 < M)      av0 = *(const float4*)&A[(size_t)(row0 + ar0) * K + k0 + aq];
        if (row0 + ar0 + 64 < M) av1 = *(const float4*)&A[(size_t)(row0 + ar0 + 64) * K + k0 + aq];
        float4 wv = *(const float4*)&W[(size_t)(k0 + wk) * NC + col0 + wc];
        __syncthreads();
        As[aq + 0][ar0] = av0.x; As[aq + 1][ar0] = av0.y;
        As[aq + 2][ar0] = av0.z; As[aq + 3][ar0] = av0.w;
        As[aq + 0][ar0 + 64] = av1.x; As[aq + 1][ar0 + 64] = av1.y;
        As[aq + 2][ar0 + 64] = av1.z; As[aq + 3][ar0 + 64] = av1.w;
        *(float4*)&Ws[wk][wc] = wv;
        __syncthreads();
#pragma unroll
        for (int kk = 0; kk < 16; kk++) {
            float4 a0 = *(const float4*)&As[kk][ty8];
            float4 a1 = *(const float4*)&As[kk][ty8 + 4];
            float4 w  = *(const float4*)&Ws[kk][tx4];
            float ar[8] = {a0.x, a0.y, a0.z, a0.w, a1.x, a1.y, a1.z, a1.w};
            float wr[4] = {w.x, w.y, w.z, w.w};
#pragma unroll
            for (int i = 0; i < 8; i++)
#pragma unroll
                for (int j = 0; j < 4; j++) acc[i][j] += ar[i] * wr[j];
        }
    }
    const float4 bv = *(const float4*)&bias[col0 + tx4];
    const float br[4] = {bv.x, bv.y, bv.z, bv.w};
#pragma unroll
    for (int i = 0; i < 8; i++) {
        int r = row0 + ty8 + i;
        if (r < M) {
            float v0 = acc[i][0] + br[0], v1 = acc[i][1] + br[1];
            float v2 = acc[i][2] + br[2], v3 = acc[i][3] + br[3];
            size_t off = (size_t)r * NC + col0 + tx4;
            if (BF16_OUT) {
                ushort4 o;
                o.x = f2bf(v0); o.y = f2bf(v1); o.z = f2bf(v2); o.w = f2bf(v3);
                ((ushort4*)Cout)[off >> 2] = o;
            } else {
                ((float4*)Cout)[off >> 2] = make_float4(v0, v1, v2, v3);
            }
        }
    }
}

// ================= batch norm (training mode) =================
__global__ __launch_bounds__(256) void k_bn_partial(const float* __restrict__ X, int M,
                                                    float* __restrict__ sums) {
    __shared__ float sh[2][256];
    float s = 0.f, s2 = 0.f;
    const size_t total = (size_t)M * HID;
    for (size_t i = (size_t)blockIdx.x * blockDim.x + threadIdx.x; i < total;
         i += (size_t)gridDim.x * blockDim.x) {
        float v = X[i];
        s += v; s2 += v * v;
    }
    sh[0][threadIdx.x] = s; sh[1][threadIdx.x] = s2;
    __syncthreads();
    if (threadIdx.x < 128) {
        s  = sh[0][threadIdx.x] + sh[0][threadIdx.x + 128];
        s2 = sh[1][threadIdx.x] + sh[1][threadIdx.x + 128];
        atomicAdd(&sums[threadIdx.x], s);
        atomicAdd(&sums[HID + threadIdx.x], s2);
    }
}

__global__ void k_bn_finalize(const float* __restrict__ sums, int M,
                              float* __restrict__ mean, float* __restrict__ istd) {
    int c = threadIdx.x;
    float m = sums[c] / M;
    float var = sums[HID + c] / M - m * m;
    mean[c] = m;
    istd[c] = rsqrtf(var + EPSV);
}

__global__ void k_bn_apply(float* __restrict__ X, int M,
                           const float* __restrict__ mean, const float* __restrict__ istd,
                           const float* __restrict__ g, const float* __restrict__ b) {
    int idx = blockIdx.x * blockDim.x + threadIdx.x;
    if (idx >= M * HID) return;
    int j = idx & (HID - 1);
    float v = (X[idx] - mean[j]) * istd[j] * g[j] + b[j];
    X[idx] = fmaxf(v, 0.f);
}

// ================= ATTConv (GATv2-style), bf16 operands, CSR order =================
// Wave per CSR position p: dst = pnode[p] (sorted -> cached), src = srcs[p] (random).
__global__ __launch_bounds__(256) void k_att_logit_csr(const ushort4* __restrict__ xl,
                                                       const ushort4* __restrict__ xr,
                                                       const int* __restrict__ pnode,
                                                       const int* __restrict__ srcs,
                                                       const float* __restrict__ att,
                                                       float* __restrict__ logit) {
    int gid = blockIdx.x * blockDim.x + threadIdx.x;
    int p = gid >> 6;
    if (p >= E_EDGES) return;
    int lane = gid & 63;
    int s = srcs[p], n = pnode[p];
    float4 a = bf4_to_f4(xl[((size_t)s << 6) + lane]);
    float4 b = bf4_to_f4(xr[((size_t)n << 6) + lane]);
    float4 pa = *(const float4*)&att[((lane >> 5) * HID) + ((lane & 31) << 2)];
    float v0 = a.x + b.x; v0 = (v0 > 0.f) ? v0 : 0.2f * v0;
    float v1 = a.y + b.y; v1 = (v1 > 0.f) ? v1 : 0.2f * v1;
    float v2 = a.z + b.z; v2 = (v2 > 0.f) ? v2 : 0.2f * v2;
    float v3 = a.w + b.w; v3 = (v3 > 0.f) ? v3 : 0.2f * v3;
    float acc = pa.x * v0 + pa.y * v1 + pa.z * v2 + pa.w * v3;
#pragma unroll
    for (int m = 1; m <= 16; m <<= 1) acc += __shfl_xor(acc, m, 64);
    if ((lane & 31) == 0) logit[p * HEADS + (lane >> 5)] = acc;
}

// per (node,head): softmax over CSR-contiguous logits -> albuf (CSR order),
// optional alpha_out scatter back to edge order via eids.
__global__ void k_att_softmax(const float* __restrict__ logit,
                              const int* __restrict__ rowptr,
                              const int* __restrict__ eids,
                              float* __restrict__ albuf,
                              float* __restrict__ alpha_out) {
    int idx = blockIdx.x * blockDim.x + threadIdx.x;
    if (idx >= N_NODES * HEADS) return;
    int n = idx >> 1, h = idx & 1;
    int p0 = rowptr[n], p1 = rowptr[n + 1];
    float m = -INFINITY;
    for (int p = p0; p < p1; p++) m = fmaxf(m, logit[p * HEADS + h]);
    float s = 0.f;
    for (int p = p0; p < p1; p++) s += expf(logit[p * HEADS + h] - m);
    float inv = 1.f / (s + 1e-16f);
    for (int p = p0; p < p1; p++) {
        float a = expf(logit[p * HEADS + h] - m) * inv;
        albuf[p * HEADS + h] = a;
        if (alpha_out) alpha_out[eids[p] * HEADS + h] = a;
    }
}

// att1 gather (concat): emb[n,:] = relu( sum alpha*xl[src,:] + bias ), fp32 out
__global__ __launch_bounds__(256) void k_att_gather_cat(const ushort4* __restrict__ xl,
                                                        const float* __restrict__ albuf,
                                                        const int* __restrict__ rowptr,
                                                        const int* __restrict__ srcs,
                                                        const float* __restrict__ bias,
                                                        float4* __restrict__ emb) {
    int gid = blockIdx.x * blockDim.x + threadIdx.x;
    int n = gid >> 6;
    if (n >= N_NODES) return;
    int lane = gid & 63;
    int h = lane >> 5;
    float4 acc = make_float4(0.f, 0.f, 0.f, 0.f);
    int p1 = rowptr[n + 1];
    for (int p = rowptr[n]; p < p1; p++) {
        float a = albuf[p * HEADS + h];
        float4 v = bf4_to_f4(xl[((size_t)srcs[p] << 6) + lane]);
        acc.x += a * v.x; acc.y += a * v.y; acc.z += a * v.z; acc.w += a * v.w;
    }
    float4 b = *(const float4*)&bias[lane << 2];
    acc.x = fmaxf(acc.x + b.x, 0.f); acc.y = fmaxf(acc.y + b.y, 0.f);
    acc.z = fmaxf(acc.z + b.z, 0.f); acc.w = fmaxf(acc.w + b.w, 0.f);
    emb[((size_t)n << 6) + lane] = acc;
}

// att2 gather (mean over heads): atten_out[n,:] = relu( 0.5*(h0+h1) + bias )
__global__ __launch_bounds__(256) void k_att_gather_mean(const ushort4* __restrict__ xl,
                                                         const float* __restrict__ albuf,
                                                         const int* __restrict__ rowptr,
                                                         const int* __restrict__ srcs,
                                                         const float* __restrict__ bias,
                                                         float4* __restrict__ atten_out) {
    int gid = blockIdx.x * blockDim.x + threadIdx.x;
    int n = gid >> 6;
    if (n >= N_NODES) return;
    int lane = gid & 63;
    int h = lane >> 5;
    float4 acc = make_float4(0.f, 0.f, 0.f, 0.f);
    int p1 = rowptr[n + 1];
    for (int p = rowptr[n]; p < p1; p++) {
        float a = albuf[p * HEADS + h];
        float4 v = bf4_to_f4(xl[((size_t)srcs[p] << 6) + lane]);
        acc.x += a * v.x; acc.y += a * v.y; acc.z += a * v.z; acc.w += a * v.w;
    }
    float ox = __shfl_xor(acc.x, 32, 64);
    float oy = __shfl_xor(acc.y, 32, 64);
    float oz = __shfl_xor(acc.z, 32, 64);
    float ow4 = __shfl_xor(acc.w, 32, 64);
    if (lane < 32) {
        float4 b = *(const float4*)&bias[lane << 2];
        float4 o;
        o.x = fmaxf(0.5f * (acc.x + ox) + b.x, 0.f);
        o.y = fmaxf(0.5f * (acc.y + oy) + b.y, 0.f);
        o.z = fmaxf(0.5f * (acc.z + oz) + b.z, 0.f);
        o.w = fmaxf(0.5f * (acc.w + ow4) + b.w, 0.f);
        atten_out[((size_t)n << 5) + lane] = o;
    }
}

// ================= pooling over sorted batch_index (node-parallel) =================
template <int C>
__global__ __launch_bounds__(256) void k_pool_atomic(const float* __restrict__ X,
                                                     const int* __restrict__ batch,
                                                     float* __restrict__ pool, int npb) {
    const int RP = 256 / C;
    int c = threadIdx.x & (C - 1);
    int rofs = threadIdx.x / C;
    int i0 = blockIdx.x * npb;
    int i1 = min(i0 + npb, N_NODES);
    float acc = 0.f;
    int gcur = -1;
    for (int i = i0 + rofs; i < i1; i += RP) {
        int g = batch[i];
        if (g != gcur) {
            if (gcur >= 0) atomicAdd(&pool[gcur * C + c], acc);
            acc = 0.f; gcur = g;
        }
        acc += X[(size_t)i * C + c];
    }
    if (gcur >= 0) atomicAdd(&pool[gcur * C + c], acc);
}

// ================= final prediction head =================
__global__ void k_head(const float* __restrict__ pool0, const float* __restrict__ poolL,
                       const float* __restrict__ p0w, const float* __restrict__ p0b,
                       const float* __restrict__ pLw, const float* __restrict__ pLb,
                       const float* __restrict__ ow, const float* __restrict__ ob,
                       float* __restrict__ outputs) {
    int g = blockIdx.x;
    int m = threadIdx.x;
    __shared__ float sh[MIDD];
    if (m < MIDD) {
        float s = p0b[m] + pLb[m];
        for (int k = 0; k < F_INN; k++) s += pool0[g * F_INN + k] * p0w[k * MIDD + m];
        for (int k = 0; k < HID; k++)  s += poolL[g * HID + k] * pLw[k * MIDD + m];
        sh[m] = fmaxf(s, 0.f);
    }
    __syncthreads();
    if (m == 0) {
        float s = ob[0];
        for (int k = 0; k < MIDD; k++) s += sh[k] * ow[k];
        outputs[g] = s;
    }
}

extern "C" void kernel_launch(void* const* d_in, const int* in_sizes, int n_in,
                              void* d_out, int out_size, void* d_ws, size_t ws_size,
                              hipStream_t stream) {
    // ---- inputs ----
    const float* x      = (const float*)d_in[0];
    const int*   ei     = (const int*)d_in[1];
    const int*   aei    = (const int*)d_in[2];
    const int*   batch  = (const int*)d_in[3];
    const float* g0_w1  = (const float*)d_in[4];
    const float* g0_b1  = (const float*)d_in[5];
    const float* g0_bng = (const float*)d_in[6];
    const float* g0_bnb = (const float*)d_in[7];
    const float* g0_w2  = (const float*)d_in[8];
    const float* g0_b2  = (const float*)d_in[9];
    const float* g1_w1  = (const float*)d_in[10];
    const float* g1_b1  = (const float*)d_in[11];
    const float* g1_bng = (const float*)d_in[12];
    const float* g1_bnb = (const float*)d_in[13];
    const float* g1_w2  = (const float*)d_in[14];
    const float* g1_b2  = (const float*)d_in[15];
    const float* bn0_g  = (const float*)d_in[16];
    const float* bn0_b  = (const float*)d_in[17];
    const float* bn1_g  = (const float*)d_in[18];
    const float* bn1_b  = (const float*)d_in[19];
    const float* a1_wl  = (const float*)d_in[20];
    const float* a1_bl  = (const float*)d_in[21];
    const float* a1_wr  = (const float*)d_in[22];
    const float* a1_br  = (const float*)d_in[23];
    const float* a1_att = (const float*)d_in[24];
    const float* a1_bias= (const float*)d_in[25];
    const float* a2_wl  = (const float*)d_in[26];
    const float* a2_bl  = (const float*)d_in[27];
    const float* a2_wr  = (const float*)d_in[28];
    const float* a2_br  = (const float*)d_in[29];
    const float* a2_att = (const float*)d_in[30];
    const float* a2_bias= (const float*)d_in[31];
    const float* p0w    = (const float*)d_in[32];
    const float* p0b    = (const float*)d_in[33];
    const float* pLw    = (const float*)d_in[34];
    const float* pLb    = (const float*)d_in[35];
    const float* ow     = (const float*)d_in[36];
    const float* ob     = (const float*)d_in[37];

    // ---- outputs ----
    float* out_head  = (float*)d_out;
    float* atten_out = out_head + G_GR;
    float* alpha_out = atten_out + (size_t)N_NODES * HID;

    // ---- workspace ----
    float* ws = (float*)d_ws;
    const size_t NB = (size_t)N_NODES * HC;
    float* A     = ws;        // h-chain fp32 [N,HC]
    float* B     = A + NB;    // fp32 scratch; also aliased as bf16 xl
    float* Cb    = B + NB;    // fp32 scratch; also aliased as bf16 xr
    float* logit = Cb + NB;                          // E*2 (CSR order)
    float* albuf = logit + (size_t)E_EDGES * HEADS;  // E*2 (CSR order)
    float* mean  = albuf + (size_t)E_EDGES * HEADS;  // 128
    float* istd  = mean + 128;
    float* pool0 = istd + 128;                       // G*64
    float* poolL = pool0 + G_GR * F_INN;             // G*128
    float* sums  = poolL + G_GR * HID;               // 256
    int* ip = (int*)(sums + 256);
    int* deg    = ip; ip += N_NODES;
    int* cursor = ip; ip += N_NODES;
    int* rowptr[3]; int* eids[3]; int* srcs[3];
    for (int c = 0; c < 3; c++) {
        rowptr[c] = ip; ip += N_NODES + 1;
        eids[c]   = ip; ip += E_EDGES;
        srcs[c]   = ip; ip += E_EDGES;
    }
    int* pnode1 = ip; ip += E_EDGES;
    int* pnode2 = ip; ip += E_EDGES;

    unsigned short* xl_bf = (unsigned short*)B;   // [N,HC] bf16
    unsigned short* xr_bf = (unsigned short*)Cb;  // [N,HC] bf16

    const int* e_row = ei;
    const int* e_col = ei + E_EDGES;
    const int* a_src = aei;
    const int* a_dst = aei + E_EDGES;

    const int TB = 256;
#define GRID1(n) dim3(CDIV((n), TB))

    // ===== build CSRs: 0=GAN(key=row), 1=ATT1(key=dst=e_col), 2=ATT2(key=a_dst) =====
    const int* keys[3]   = {e_row, e_col, a_dst};
    const int* others[3] = {e_col, e_row, a_src};
    int* pnodes[3] = {nullptr, pnode1, pnode2};
    for (int c = 0; c < 3; c++) {
        hipMemsetAsync(deg, 0, N_NODES * sizeof(int), stream);
        hipLaunchKernelGGL(k_hist, GRID1(E_EDGES), dim3(TB), 0, stream, keys[c], deg);
        hipLaunchKernelGGL(k_scan20k, dim3(1), dim3(1024), 0, stream, deg, rowptr[c], cursor, N_NODES);
        hipLaunchKernelGGL(k_csr_scatter, GRID1(E_EDGES), dim3(TB), 0, stream,
                           keys[c], others[c], cursor, eids[c], srcs[c], pnodes[c]);
    }

#define RUN_BN(buf, gamma, beta) do { \
        hipMemsetAsync(sums, 0, 2 * HID * sizeof(float), stream); \
        hipLaunchKernelGGL(k_bn_partial, dim3(256), dim3(TB), 0, stream, (buf), N_NODES, sums); \
        hipLaunchKernelGGL(k_bn_finalize, dim3(1), dim3(HID), 0, stream, sums, N_NODES, mean, istd); \
        hipLaunchKernelGGL(k_bn_apply, GRID1(N_NODES * HID), dim3(TB), 0, stream, (buf), N_NODES, mean, istd, (gamma), (beta)); \
    } while (0)

    const dim3 gemm_g1(HID / 64, CDIV(N_NODES, 128));   // NC=128
    const dim3 gemm_g2(HC / 64,  CDIV(N_NODES, 128));   // NC=256

    // ===== GANConv 0 =====
    hipLaunchKernelGGL(k_seg_gather_add, GRID1(N_NODES * (F_INN / 4)), dim3(TB), 0, stream,
                       (const float4*)x, rowptr[0], srcs[0], (float4*)A, 4);
    hipLaunchKernelGGL(k_gemm128<0>, gemm_g1, dim3(TB), 0, stream, A, g0_w1, g0_b1, (void*)B, N_NODES, F_INN, HID);
    RUN_BN(B, g0_bng, g0_bnb);
    hipLaunchKernelGGL(k_gemm128<0>, gemm_g1, dim3(TB), 0, stream, B, g0_w2, g0_b2, (void*)Cb, N_NODES, HID, HID);
    RUN_BN(Cb, bn0_g, bn0_b);
    // h1 in Cb [N,HID]

    // ===== GANConv 1 =====
    hipLaunchKernelGGL(k_seg_gather_add, GRID1(N_NODES * (HID / 4)), dim3(TB), 0, stream,
                       (const float4*)Cb, rowptr[0], srcs[0], (float4*)A, 5);
    hipLaunchKernelGGL(k_gemm128<0>, gemm_g1, dim3(TB), 0, stream, A, g1_w1, g1_b1, (void*)B, N_NODES, HID, HID);
    RUN_BN(B, g1_bng, g1_bnb);
    hipLaunchKernelGGL(k_gemm128<0>, gemm_g1, dim3(TB), 0, stream, B, g1_w2, g1_b2, (void*)A, N_NODES, HID, HID);
    RUN_BN(A, bn1_g, bn1_b);
    // h2 in A [N,HID]

    // ===== ATTConv 1 (src=e_row, dst=e_col, concat=True) =====
    hipLaunchKernelGGL(k_gemm128<1>, gemm_g2, dim3(TB), 0, stream, A, a1_wl, a1_bl, (void*)xl_bf, N_NODES, HID, HC);
    hipLaunchKernelGGL(k_gemm128<1>, gemm_g2, dim3(TB), 0, stream, A, a1_wr, a1_br, (void*)xr_bf, N_NODES, HID, HC);
    hipLaunchKernelGGL(k_att_logit_csr, GRID1(E_EDGES * 64), dim3(TB), 0, stream,
                       (const ushort4*)xl_bf, (const ushort4*)xr_bf, pnode1, srcs[1], a1_att, logit);
    hipLaunchKernelGGL(k_att_softmax, GRID1(N_NODES * HEADS), dim3(TB), 0, stream,
                       logit, rowptr[1], eids[1], albuf, (float*)nullptr);
    hipLaunchKernelGGL(k_att_gather_cat, GRID1(N_NODES * 64), dim3(TB), 0, stream,
                       (const ushort4*)xl_bf, albuf, rowptr[1], srcs[1], a1_bias, (float4*)A);
    // emb in A [N,HC] (h2 dead)

    // ===== ATTConv 2 (src=a_src, dst=a_dst, concat=False) =====
    hipLaunchKernelGGL(k_gemm128<1>, gemm_g2, dim3(TB), 0, stream, A, a2_wl, a2_bl, (void*)xl_bf, N_NODES, HC, HC);
    hipLaunchKernelGGL(k_gemm128<1>, gemm_g2, dim3(TB), 0, stream, A, a2_wr, a2_br, (void*)xr_bf, N_NODES, HC, HC);
    hipLaunchKernelGGL(k_att_logit_csr, GRID1(E_EDGES * 64), dim3(TB), 0, stream,
                       (const ushort4*)xl_bf, (const ushort4*)xr_bf, pnode2, srcs[2], a2_att, logit);
    hipLaunchKernelGGL(k_att_softmax, GRID1(N_NODES * HEADS), dim3(TB), 0, stream,
                       logit, rowptr[2], eids[2], albuf, alpha_out);
    hipLaunchKernelGGL(k_att_gather_mean, GRID1(N_NODES * 64), dim3(TB), 0, stream,
                       (const ushort4*)xl_bf, albuf, rowptr[2], srcs[2], a2_bias, (float4*)atten_out);

    // ===== pooling + head =====
    hipMemsetAsync(pool0, 0, (size_t)G_GR * F_INN * sizeof(float), stream);
    hipMemsetAsync(poolL, 0, (size_t)G_GR * HID * sizeof(float), stream);
    {
        const int npb = 64;  // 313 blocks
        hipLaunchKernelGGL(k_pool_atomic<F_INN>, dim3(CDIV(N_NODES, npb)), dim3(TB), 0, stream,
                           x, batch, pool0, npb);
        hipLaunchKernelGGL(k_pool_atomic<HID>, dim3(CDIV(N_NODES, npb)), dim3(TB), 0, stream,
                           atten_out, batch, poolL, npb);
    }
    hipLaunchKernelGGL(k_head, dim3(G_GR), dim3(64), 0, stream,
                       pool0, poolL, p0w, p0b, pLw, pLb, ow, ob, out_head);
}

// Round 6
// 783.562 us; speedup vs baseline: 4.7002x; 1.2601x over previous
//
#include <hip/hip_runtime.h>
#include <hip/hip_bf16.h>

#define N_NODES 20000
#define E_EDGES 320000
#define F_INN   64
#define HID     128
#define HEADS   2
#define HC      (HEADS * HID)   // 256
#define G_GR    64
#define MIDD    32
#define EPSV    1e-5f

#define CDIV(a, b) (((a) + (b) - 1) / (b))

typedef __attribute__((ext_vector_type(8))) short          bf16x8;  // MFMA A/B frag
typedef __attribute__((ext_vector_type(4))) float          f32x4;   // MFMA C/D frag
typedef __attribute__((ext_vector_type(8))) unsigned short u16x8;

// ---------- bf16 helpers (RNE) ----------
__device__ inline float bf2f(unsigned short u) { return __uint_as_float((unsigned)u << 16); }
__device__ inline unsigned short f2bf(float f) {
    unsigned u = __float_as_uint(f);
    unsigned r = u + 0x7FFFu + ((u >> 16) & 1u);
    return (unsigned short)(r >> 16);
}

// ================= CSR construction (per launch, on device) =================
__global__ void k_hist(const int* __restrict__ key, int* __restrict__ deg) {
    int e = blockIdx.x * blockDim.x + threadIdx.x;
    if (e < E_EDGES) atomicAdd(&deg[key[e]], 1);
}

// 1024 threads, 20 elems/thread serial + one block scan (n = N_NODES fixed)
__global__ __launch_bounds__(1024) void k_scan20k(const int* __restrict__ deg,
                                                  int* __restrict__ rowptr,
                                                  int* __restrict__ cursor) {
    const int PER = (N_NODES + 1023) / 1024;  // 20
    __shared__ int part[1024];
    const int tid = threadIdx.x;
    const int base = tid * PER;
    int lv[PER];
    int lsum = 0;
#pragma unroll
    for (int i = 0; i < PER; i++) {
        int idx = base + i;
        int v = (idx < N_NODES) ? deg[idx] : 0;
        lv[i] = v; lsum += v;
    }
    part[tid] = lsum;
    __syncthreads();
    for (int off = 1; off < 1024; off <<= 1) {
        int t = (tid >= off) ? part[tid - off] : 0;
        __syncthreads();
        part[tid] += t;
        __syncthreads();
    }
    int run = part[tid] - lsum;  // exclusive prefix
    if (tid == 0) rowptr[0] = 0;
#pragma unroll
    for (int i = 0; i < PER; i++) {
        int idx = base + i;
        if (idx < N_NODES) {
            cursor[idx] = run;
            run += lv[i];
            rowptr[idx + 1] = run;
        }
    }
}

__global__ void k_csr_scatter(const int* __restrict__ key, const int* __restrict__ other,
                              int* __restrict__ cursor, int* __restrict__ eids,
                              int* __restrict__ srcs, int* __restrict__ pnode) {
    int e = blockIdx.x * blockDim.x + threadIdx.x;
    if (e >= E_EDGES) return;
    int k = key[e];
    int pos = atomicAdd(&cursor[k], 1);
    eids[pos] = e;
    srcs[pos] = other[e];
    if (pnode) pnode[pos] = k;
}

// ===== GANConv aggregation (gather): z[n] = bf16(x[n] + sum x[srcs]) =====
__global__ __launch_bounds__(256) void k_seg_gather_add_bf(const float4* __restrict__ x,
                                                           const int* __restrict__ rowptr,
                                                           const int* __restrict__ srcs,
                                                           unsigned short* __restrict__ z,
                                                           int cq_shift) {
    int gid = blockIdx.x * blockDim.x + threadIdx.x;
    int n = gid >> cq_shift;
    if (n >= N_NODES) return;
    int q = gid & ((1 << cq_shift) - 1);
    float4 acc = x[((size_t)n << cq_shift) + q];
    int p1 = rowptr[n + 1];
    for (int p = rowptr[n]; p < p1; p++) {
        float4 v = x[((size_t)srcs[p] << cq_shift) + q];
        acc.x += v.x; acc.y += v.y; acc.z += v.z; acc.w += v.w;
    }
    ushort4 o;
    o.x = f2bf(acc.x); o.y = f2bf(acc.y); o.z = f2bf(acc.z); o.w = f2bf(acc.w);
    *(ushort4*)&z[((size_t)n << (cq_shift + 2)) + (q << 2)] = o;
}

// ===== weight prep: Wt[n][k] = bf16(W[k][n]) for 8 weights in one launch =====
struct WtJob  { const float* src; unsigned short* dst; int K; int N; };
struct WtJobs { WtJob j[8]; };
__global__ void k_wt_cast(WtJobs jobs) {
    WtJob jb = jobs.j[blockIdx.y];
    int total = jb.K * jb.N;
    for (int i = blockIdx.x * blockDim.x + threadIdx.x; i < total; i += gridDim.x * blockDim.x) {
        int nn = i / jb.K, kk = i - nn * jb.K;
        jb.dst[i] = f2bf(jb.src[(size_t)kk * jb.N + nn]);
    }
}

// ===== MFMA bf16 GEMM: C[M,N] = A[M,K] @ Wt[N,K]^T + bias =====
// 128x128 tile, 256 threads (4 waves, each 64x64 = 4x4 frags), BK=32.
// Layouts per guide (m89/m91): A-frag m=lane&15,k=(lane>>4)*8+j; C/D col=lane&15,row=(lane>>4)*4+r.
template <int BF16_OUT>
__global__ __launch_bounds__(256) void k_mfma_gemm(const unsigned short* __restrict__ A,
                                                   const unsigned short* __restrict__ Wt,
                                                   const float* __restrict__ bias,
                                                   void* __restrict__ Cout,
                                                   int M, int K, int N) {
    __shared__ unsigned short As[128][40];  // pad 40: b128 frag reads 2-way banks (free)
    __shared__ unsigned short Bs[128][40];
    const int t = threadIdx.x;
    const int wave = t >> 6, lane = t & 63;
    const int row0 = blockIdx.y * 128, col0 = blockIdx.x * 128;
    const int wm = (wave & 1) << 6, wn = (wave >> 1) << 6;
    const int lm = lane & 15, lk = (lane >> 4) << 3;
    f32x4 acc[4][4] = {};
    for (int k0 = 0; k0 < K; k0 += 32) {
        u16x8 av[2], wv[2];
#pragma unroll
        for (int i = 0; i < 2; i++) {
            int c = t + (i << 8);
            int r = c >> 2, ko = (c & 3) << 3;
            u16x8 zv = {};
            int gr = row0 + r;
            av[i] = (gr < M) ? *(const u16x8*)&A[(size_t)gr * K + k0 + ko] : zv;
            wv[i] = *(const u16x8*)&Wt[(size_t)(col0 + r) * K + k0 + ko];
        }
        __syncthreads();
#pragma unroll
        for (int i = 0; i < 2; i++) {
            int c = t + (i << 8);
            int r = c >> 2, ko = (c & 3) << 3;
            *(u16x8*)&As[r][ko] = av[i];
            *(u16x8*)&Bs[r][ko] = wv[i];
        }
        __syncthreads();
        bf16x8 af[4], bfm[4];
#pragma unroll
        for (int i = 0; i < 4; i++) af[i]  = *(const bf16x8*)&As[wm + (i << 4) + lm][lk];
#pragma unroll
        for (int j = 0; j < 4; j++) bfm[j] = *(const bf16x8*)&Bs[wn + (j << 4) + lm][lk];
#pragma unroll
        for (int i = 0; i < 4; i++)
#pragma unroll
            for (int j = 0; j < 4; j++)
                acc[i][j] = __builtin_amdgcn_mfma_f32_16x16x32_bf16(af[i], bfm[j], acc[i][j], 0, 0, 0);
    }
    const int lr4 = (lane >> 4) << 2;
#pragma unroll
    for (int i = 0; i < 4; i++) {
#pragma unroll
        for (int j = 0; j < 4; j++) {
            int col = col0 + wn + (j << 4) + lm;
            float bv = bias[col];
#pragma unroll
            for (int r = 0; r < 4; r++) {
                int row = row0 + wm + (i << 4) + lr4 + r;
                if (row < M) {
                    float v = acc[i][j][r] + bv;
                    if (BF16_OUT) ((unsigned short*)Cout)[(size_t)row * N + col] = f2bf(v);
                    else          ((float*)Cout)[(size_t)row * N + col] = v;
                }
            }
        }
    }
}

// ================= batch norm (training mode) =================
__global__ __launch_bounds__(256) void k_bn_partial(const float* __restrict__ X, int M,
                                                    float* __restrict__ sums) {
    __shared__ float sh[2][256];
    float s = 0.f, s2 = 0.f;
    const size_t total = (size_t)M * HID;
    for (size_t i = (size_t)blockIdx.x * blockDim.x + threadIdx.x; i < total;
         i += (size_t)gridDim.x * blockDim.x) {
        float v = X[i];
        s += v; s2 += v * v;
    }
    sh[0][threadIdx.x] = s; sh[1][threadIdx.x] = s2;
    __syncthreads();
    if (threadIdx.x < 128) {
        s  = sh[0][threadIdx.x] + sh[0][threadIdx.x + 128];
        s2 = sh[1][threadIdx.x] + sh[1][threadIdx.x + 128];
        atomicAdd(&sums[threadIdx.x], s);
        atomicAdd(&sums[HID + threadIdx.x], s2);
    }
}

// finalize folded in: mean/istd recomputed per thread from sums (cheap, removes a kernel)
__global__ void k_bn_apply(const float* __restrict__ X, float* __restrict__ Xf32,
                           unsigned short* __restrict__ Xbf, int M,
                           const float* __restrict__ sums,
                           const float* __restrict__ g, const float* __restrict__ b) {
    int idx = blockIdx.x * blockDim.x + threadIdx.x;
    if (idx >= M * HID) return;
    int j = idx & (HID - 1);
    float mean = sums[j] / M;
    float istd = rsqrtf(sums[HID + j] / M - mean * mean + EPSV);
    float v = fmaxf((X[idx] - mean) * istd * g[j] + b[j], 0.f);
    if (Xf32) Xf32[idx] = v;
    if (Xbf)  Xbf[idx] = f2bf(v);
}

// ================= ATTConv (GATv2-style), bf16 operands, CSR order =================
// Half-wave (32 lanes) per CSR position; lane handles 8 channels (16B load).
__global__ __launch_bounds__(256) void k_att_logit_csr(const u16x8* __restrict__ xl,
                                                       const u16x8* __restrict__ xr,
                                                       const int* __restrict__ pnode,
                                                       const int* __restrict__ srcs,
                                                       const float* __restrict__ att,
                                                       float* __restrict__ logit) {
    int gid = blockIdx.x * blockDim.x + threadIdx.x;
    int p = gid >> 5;
    if (p >= E_EDGES) return;
    int l = gid & 31;
    int s = srcs[p], n = pnode[p];
    u16x8 ua = xl[((size_t)s << 5) + l];
    u16x8 ub = xr[((size_t)n << 5) + l];
    const float* pa = &att[((l >> 4) * HID) + ((l & 15) << 3)];
    float acc = 0.f;
#pragma unroll
    for (int i = 0; i < 8; i++) {
        float v = bf2f(ua[i]) + bf2f(ub[i]);
        v = (v > 0.f) ? v : 0.2f * v;
        acc = fmaf(pa[i], v, acc);
    }
#pragma unroll
    for (int m = 1; m <= 8; m <<= 1) acc += __shfl_xor(acc, m, 64);
    if ((l & 15) == 0) logit[p * HEADS + (l >> 4)] = acc;
}

// per (node,head): softmax over CSR-contiguous logits -> albuf; optional edge-order alpha_out
__global__ void k_att_softmax(const float* __restrict__ logit,
                              const int* __restrict__ rowptr,
                              const int* __restrict__ eids,
                              float* __restrict__ albuf,
                              float* __restrict__ alpha_out) {
    int idx = blockIdx.x * blockDim.x + threadIdx.x;
    if (idx >= N_NODES * HEADS) return;
    int n = idx >> 1, h = idx & 1;
    int p0 = rowptr[n], p1 = rowptr[n + 1];
    float m = -INFINITY;
    for (int p = p0; p < p1; p++) m = fmaxf(m, logit[p * HEADS + h]);
    float s = 0.f;
    for (int p = p0; p < p1; p++) s += expf(logit[p * HEADS + h] - m);
    float inv = 1.f / (s + 1e-16f);
    for (int p = p0; p < p1; p++) {
        float a = expf(logit[p * HEADS + h] - m) * inv;
        albuf[p * HEADS + h] = a;
        if (alpha_out) alpha_out[eids[p] * HEADS + h] = a;
    }
}

// att1 gather (concat): emb[n,:] = bf16(relu(sum alpha*xl[src,:] + bias)); half-wave per node
__global__ __launch_bounds__(256) void k_att_gather_cat(const u16x8* __restrict__ xl,
                                                        const float* __restrict__ albuf,
                                                        const int* __restrict__ rowptr,
                                                        const int* __restrict__ srcs,
                                                        const float* __restrict__ bias,
                                                        unsigned short* __restrict__ emb) {
    int gid = blockIdx.x * blockDim.x + threadIdx.x;
    int n = gid >> 5;
    if (n >= N_NODES) return;
    int l = gid & 31;
    int h = l >> 4;
    float acc[8] = {0.f, 0.f, 0.f, 0.f, 0.f, 0.f, 0.f, 0.f};
    int p1 = rowptr[n + 1];
    for (int p = rowptr[n]; p < p1; p++) {
        float a = albuf[p * HEADS + h];
        u16x8 v = xl[((size_t)srcs[p] << 5) + l];
#pragma unroll
        for (int i = 0; i < 8; i++) acc[i] = fmaf(a, bf2f(v[i]), acc[i]);
    }
    const float* bp = &bias[l << 3];
    u16x8 o;
#pragma unroll
    for (int i = 0; i < 8; i++) o[i] = f2bf(fmaxf(acc[i] + bp[i], 0.f));
    *(u16x8*)&emb[((size_t)n << 8) + (l << 3)] = o;
}

// att2 gather (mean over heads): atten_out[n,:] = relu(0.5*(h0+h1) + bias), fp32 out
__global__ __launch_bounds__(256) void k_att_gather_mean(const u16x8* __restrict__ xl,
                                                         const float* __restrict__ albuf,
                                                         const int* __restrict__ rowptr,
                                                         const int* __restrict__ srcs,
                                                         const float* __restrict__ bias,
                                                         float* __restrict__ atten_out) {
    int gid = blockIdx.x * blockDim.x + threadIdx.x;
    int n = gid >> 5;
    if (n >= N_NODES) return;
    int l = gid & 31;
    int h = l >> 4;
    float acc[8] = {0.f, 0.f, 0.f, 0.f, 0.f, 0.f, 0.f, 0.f};
    int p1 = rowptr[n + 1];
    for (int p = rowptr[n]; p < p1; p++) {
        float a = albuf[p * HEADS + h];
        u16x8 v = xl[((size_t)srcs[p] << 5) + l];
#pragma unroll
        for (int i = 0; i < 8; i++) acc[i] = fmaf(a, bf2f(v[i]), acc[i]);
    }
#pragma unroll
    for (int i = 0; i < 8; i++) {
        float other = __shfl_xor(acc[i], 16, 64);
        acc[i] = 0.5f * (acc[i] + other);
    }
    if (l < 16) {
        const float* bp = &bias[l << 3];
        float4 o0, o1;
        o0.x = fmaxf(acc[0] + bp[0], 0.f); o0.y = fmaxf(acc[1] + bp[1], 0.f);
        o0.z = fmaxf(acc[2] + bp[2], 0.f); o0.w = fmaxf(acc[3] + bp[3], 0.f);
        o1.x = fmaxf(acc[4] + bp[4], 0.f); o1.y = fmaxf(acc[5] + bp[5], 0.f);
        o1.z = fmaxf(acc[6] + bp[6], 0.f); o1.w = fmaxf(acc[7] + bp[7], 0.f);
        *(float4*)&atten_out[((size_t)n << 7) + (l << 3)] = o0;
        *(float4*)&atten_out[((size_t)n << 7) + (l << 3) + 4] = o1;
    }
}

// ================= pooling over sorted batch_index (node-parallel) =================
template <int C>
__global__ __launch_bounds__(256) void k_pool_atomic(const float* __restrict__ X,
                                                     const int* __restrict__ batch,
                                                     float* __restrict__ pool, int npb) {
    const int RP = 256 / C;
    int c = threadIdx.x & (C - 1);
    int rofs = threadIdx.x / C;
    int i0 = blockIdx.x * npb;
    int i1 = min(i0 + npb, N_NODES);
    float acc = 0.f;
    int gcur = -1;
    for (int i = i0 + rofs; i < i1; i += RP) {
        int g = batch[i];
        if (g != gcur) {
            if (gcur >= 0) atomicAdd(&pool[gcur * C + c], acc);
            acc = 0.f; gcur = g;
        }
        acc += X[(size_t)i * C + c];
    }
    if (gcur >= 0) atomicAdd(&pool[gcur * C + c], acc);
}

// ================= final prediction head =================
__global__ void k_head(const float* __restrict__ pool0, const float* __restrict__ poolL,
                       const float* __restrict__ p0w, const float* __restrict__ p0b,
                       const float* __restrict__ pLw, const float* __restrict__ pLb,
                       const float* __restrict__ ow, const float* __restrict__ ob,
                       float* __restrict__ outputs) {
    int g = blockIdx.x;
    int m = threadIdx.x;
    __shared__ float sh[MIDD];
    if (m < MIDD) {
        float s = p0b[m] + pLb[m];
        for (int k = 0; k < F_INN; k++) s += pool0[g * F_INN + k] * p0w[k * MIDD + m];
        for (int k = 0; k < HID; k++)  s += poolL[g * HID + k] * pLw[k * MIDD + m];
        sh[m] = fmaxf(s, 0.f);
    }
    __syncthreads();
    if (m == 0) {
        float s = ob[0];
        for (int k = 0; k < MIDD; k++) s += sh[k] * ow[k];
        outputs[g] = s;
    }
}

extern "C" void kernel_launch(void* const* d_in, const int* in_sizes, int n_in,
                              void* d_out, int out_size, void* d_ws, size_t ws_size,
                              hipStream_t stream) {
    // ---- inputs ----
    const float* x      = (const float*)d_in[0];
    const int*   ei     = (const int*)d_in[1];
    const int*   aei    = (const int*)d_in[2];
    const int*   batch  = (const int*)d_in[3];
    const float* g0_w1  = (const float*)d_in[4];
    const float* g0_b1  = (const float*)d_in[5];
    const float* g0_bng = (const float*)d_in[6];
    const float* g0_bnb = (const float*)d_in[7];
    const float* g0_w2  = (const float*)d_in[8];
    const float* g0_b2  = (const float*)d_in[9];
    const float* g1_w1  = (const float*)d_in[10];
    const float* g1_b1  = (const float*)d_in[11];
    const float* g1_bng = (const float*)d_in[12];
    const float* g1_bnb = (const float*)d_in[13];
    const float* g1_w2  = (const float*)d_in[14];
    const float* g1_b2  = (const float*)d_in[15];
    const float* bn0_g  = (const float*)d_in[16];
    const float* bn0_b  = (const float*)d_in[17];
    const float* bn1_g  = (const float*)d_in[18];
    const float* bn1_b  = (const float*)d_in[19];
    const float* a1_wl  = (const float*)d_in[20];
    const float* a1_bl  = (const float*)d_in[21];
    const float* a1_wr  = (const float*)d_in[22];
    const float* a1_br  = (const float*)d_in[23];
    const float* a1_att = (const float*)d_in[24];
    const float* a1_bias= (const float*)d_in[25];
    const float* a2_wl  = (const float*)d_in[26];
    const float* a2_bl  = (const float*)d_in[27];
    const float* a2_wr  = (const float*)d_in[28];
    const float* a2_br  = (const float*)d_in[29];
    const float* a2_att = (const float*)d_in[30];
    const float* a2_bias= (const float*)d_in[31];
    const float* p0w    = (const float*)d_in[32];
    const float* p0b    = (const float*)d_in[33];
    const float* pLw    = (const float*)d_in[34];
    const float* pLb    = (const float*)d_in[35];
    const float* ow     = (const float*)d_in[36];
    const float* ob     = (const float*)d_in[37];

    // ---- outputs ----
    float* out_head  = (float*)d_out;
    float* atten_out = out_head + G_GR;
    float* alpha_out = atten_out + (size_t)N_NODES * HID;

    // ---- workspace ----
    float* ws = (float*)d_ws;
    const size_t NB = (size_t)N_NODES * HC;   // 5.12M
    float* F1    = ws;                        // fp32 [N,HC]-capacity scratch
    float* F2    = F1 + NB;
    float* logit = F2 + NB;                          // E*2 (CSR order)
    float* albuf = logit + (size_t)E_EDGES * HEADS;  // E*2
    float* pool0 = albuf + (size_t)E_EDGES * HEADS;  // G*64
    float* poolL = pool0 + G_GR * F_INN;             // G*128
    float* sums  = poolL + G_GR * HID;               // 256
    unsigned short* BFa = (unsigned short*)(sums + 256);  // bf16 [N,HC]
    unsigned short* BFb = BFa + NB;
    unsigned short* BFc = BFb + NB;
    unsigned short* WtB = BFc + NB;                  // 253952 bf16
    unsigned short* g0w1t = WtB;                     // [128,64]
    unsigned short* g0w2t = g0w1t + 128 * 64;        // [128,128]
    unsigned short* g1w1t = g0w2t + 128 * 128;
    unsigned short* g1w2t = g1w1t + 128 * 128;
    unsigned short* a1wlt = g1w2t + 128 * 128;       // [256,128]
    unsigned short* a1wrt = a1wlt + 256 * 128;
    unsigned short* a2wlt = a1wrt + 256 * 128;       // [256,256]
    unsigned short* a2wrt = a2wlt + 256 * 256;
    int* ip = (int*)(a2wrt + 256 * 256);
    int* deg    = ip; ip += N_NODES;
    int* cursor = ip; ip += N_NODES;
    int* rowptr[3]; int* eids[3]; int* srcs[3];
    for (int c = 0; c < 3; c++) {
        rowptr[c] = ip; ip += N_NODES + 1;
        eids[c]   = ip; ip += E_EDGES;
        srcs[c]   = ip; ip += E_EDGES;
    }
    int* pnode1 = ip; ip += E_EDGES;
    int* pnode2 = ip; ip += E_EDGES;

    const int* e_row = ei;
    const int* e_col = ei + E_EDGES;
    const int* a_src = aei;
    const int* a_dst = aei + E_EDGES;

    const int TB = 256;
#define GRID1(n) dim3(CDIV((n), TB))

    // ===== weight transpose+cast (one launch, 8 jobs) =====
    {
        WtJobs jobs;
        jobs.j[0] = {g0_w1, g0w1t, F_INN, HID};
        jobs.j[1] = {g0_w2, g0w2t, HID,   HID};
        jobs.j[2] = {g1_w1, g1w1t, HID,   HID};
        jobs.j[3] = {g1_w2, g1w2t, HID,   HID};
        jobs.j[4] = {a1_wl, a1wlt, HID,   HC};
        jobs.j[5] = {a1_wr, a1wrt, HID,   HC};
        jobs.j[6] = {a2_wl, a2wlt, HC,    HC};
        jobs.j[7] = {a2_wr, a2wrt, HC,    HC};
        hipLaunchKernelGGL(k_wt_cast, dim3(32, 8), dim3(TB), 0, stream, jobs);
    }

    // ===== build CSRs: 0=GAN(key=row), 1=ATT1(key=e_col), 2=ATT2(key=a_dst) =====
    const int* keys[3]   = {e_row, e_col, a_dst};
    const int* others[3] = {e_col, e_row, a_src};
    int* pnodes[3] = {nullptr, pnode1, pnode2};
    for (int c = 0; c < 3; c++) {
        hipMemsetAsync(deg, 0, N_NODES * sizeof(int), stream);
        hipLaunchKernelGGL(k_hist, GRID1(E_EDGES), dim3(TB), 0, stream, keys[c], deg);
        hipLaunchKernelGGL(k_scan20k, dim3(1), dim3(1024), 0, stream, deg, rowptr[c], cursor);
        hipLaunchKernelGGL(k_csr_scatter, GRID1(E_EDGES), dim3(TB), 0, stream,
                           keys[c], others[c], cursor, eids[c], srcs[c], pnodes[c]);
    }

#define RUN_BN(Fbuf, F32out, BFout, gamma, beta) do { \
        hipMemsetAsync(sums, 0, 2 * HID * sizeof(float), stream); \
        hipLaunchKernelGGL(k_bn_partial, dim3(256), dim3(TB), 0, stream, (Fbuf), N_NODES, sums); \
        hipLaunchKernelGGL(k_bn_apply, GRID1(N_NODES * HID), dim3(TB), 0, stream, \
                           (Fbuf), (F32out), (BFout), N_NODES, sums, (gamma), (beta)); \
    } while (0)

    const dim3 gemm_g1(1, CDIV(N_NODES, 128));   // N=128
    const dim3 gemm_g2(2, CDIV(N_NODES, 128));   // N=256

    // ===== GANConv 0 =====
    hipLaunchKernelGGL(k_seg_gather_add_bf, GRID1(N_NODES * (F_INN / 4)), dim3(TB), 0, stream,
                       (const float4*)x, rowptr[0], srcs[0], BFa, 4);
    hipLaunchKernelGGL(k_mfma_gemm<0>, gemm_g1, dim3(TB), 0, stream,
                       BFa, g0w1t, g0_b1, (void*)F1, N_NODES, F_INN, HID);
    RUN_BN(F1, (float*)nullptr, BFa, g0_bng, g0_bnb);
    hipLaunchKernelGGL(k_mfma_gemm<0>, gemm_g1, dim3(TB), 0, stream,
                       BFa, g0w2t, g0_b2, (void*)F2, N_NODES, HID, HID);
    RUN_BN(F2, F2, (unsigned short*)nullptr, bn0_g, bn0_b);  // h1 fp32 in F2

    // ===== GANConv 1 =====
    hipLaunchKernelGGL(k_seg_gather_add_bf, GRID1(N_NODES * (HID / 4)), dim3(TB), 0, stream,
                       (const float4*)F2, rowptr[0], srcs[0], BFa, 5);
    hipLaunchKernelGGL(k_mfma_gemm<0>, gemm_g1, dim3(TB), 0, stream,
                       BFa, g1w1t, g1_b1, (void*)F1, N_NODES, HID, HID);
    RUN_BN(F1, (float*)nullptr, BFa, g1_bng, g1_bnb);
    hipLaunchKernelGGL(k_mfma_gemm<0>, gemm_g1, dim3(TB), 0, stream,
                       BFa, g1w2t, g1_b2, (void*)F2, N_NODES, HID, HID);
    RUN_BN(F2, (float*)nullptr, BFa, bn1_g, bn1_b);  // h2 bf16 in BFa

    // ===== ATTConv 1 (src=e_row, dst=e_col, concat=True) =====
    hipLaunchKernelGGL(k_mfma_gemm<1>, gemm_g2, dim3(TB), 0, stream,
                       BFa, a1wlt, a1_bl, (void*)BFb, N_NODES, HID, HC);
    hipLaunchKernelGGL(k_mfma_gemm<1>, gemm_g2, dim3(TB), 0, stream,
                       BFa, a1wrt, a1_br, (void*)BFc, N_NODES, HID, HC);
    hipLaunchKernelGGL(k_att_logit_csr, GRID1(E_EDGES * 32), dim3(TB), 0, stream,
                       (const u16x8*)BFb, (const u16x8*)BFc, pnode1, srcs[1], a1_att, logit);
    hipLaunchKernelGGL(k_att_softmax, GRID1(N_NODES * HEADS), dim3(TB), 0, stream,
                       logit, rowptr[1], eids[1], albuf, (float*)nullptr);
    hipLaunchKernelGGL(k_att_gather_cat, GRID1(N_NODES * 32), dim3(TB), 0, stream,
                       (const u16x8*)BFb, albuf, rowptr[1], srcs[1], a1_bias, BFa);
    // emb bf16 in BFa [N,HC]

    // ===== ATTConv 2 (src=a_src, dst=a_dst, concat=False) =====
    hipLaunchKernelGGL(k_mfma_gemm<1>, gemm_g2, dim3(TB), 0, stream,
                       BFa, a2wlt, a2_bl, (void*)BFb, N_NODES, HC, HC);
    hipLaunchKernelGGL(k_mfma_gemm<1>, gemm_g2, dim3(TB), 0, stream,
                       BFa, a2wrt, a2_br, (void*)BFc, N_NODES, HC, HC);
    hipLaunchKernelGGL(k_att_logit_csr, GRID1(E_EDGES * 32), dim3(TB), 0, stream,
                       (const u16x8*)BFb, (const u16x8*)BFc, pnode2, srcs[2], a2_att, logit);
    hipLaunchKernelGGL(k_att_softmax, GRID1(N_NODES * HEADS), dim3(TB), 0, stream,
                       logit, rowptr[2], eids[2], albuf, alpha_out);
    hipLaunchKernelGGL(k_att_gather_mean, GRID1(N_NODES * 32), dim3(TB), 0, stream,
                       (const u16x8*)BFb, albuf, rowptr[2], srcs[2], a2_bias, atten_out);

    // ===== pooling + head =====
    hipMemsetAsync(pool0, 0, (size_t)G_GR * F_INN * sizeof(float), stream);
    hipMemsetAsync(poolL, 0, (size_t)G_GR * HID * sizeof(float), stream);
    {
        const int npb = 64;  // 313 blocks
        hipLaunchKernelGGL(k_pool_atomic<F_INN>, dim3(CDIV(N_NODES, npb)), dim3(TB), 0, stream,
                           x, batch, pool0, npb);
        hipLaunchKernelGGL(k_pool_atomic<HID>, dim3(CDIV(N_NODES, npb)), dim3(TB), 0, stream,
                           atten_out, batch, poolL, npb);
    }
    hipLaunchKernelGGL(k_head, dim3(G_GR), dim3(64), 0, stream,
                       pool0, poolL, p0w, p0b, pLw, pLb, ow, ob, out_head);
}

// Round 7
// 719.180 us; speedup vs baseline: 5.1210x; 1.0895x over previous
//
#include <hip/hip_runtime.h>
#include <hip/hip_bf16.h>

#define N_NODES 20000
#define E_EDGES 320000
#define F_INN   64
#define HID     128
#define HEADS   2
#define HC      (HEADS * HID)   // 256
#define G_GR    64
#define MIDD    32
#define EPSV    1e-5f

#define CDIV(a, b) (((a) + (b) - 1) / (b))

typedef __attribute__((ext_vector_type(8))) short          bf16x8;  // MFMA A/B frag
typedef __attribute__((ext_vector_type(4))) float          f32x4;   // MFMA C/D frag
typedef __attribute__((ext_vector_type(8))) unsigned short u16x8;

// ---------- bf16 helpers (RNE) ----------
__device__ inline float bf2f(unsigned short u) { return __uint_as_float((unsigned)u << 16); }
__device__ inline unsigned short f2bf(float f) {
    unsigned u = __float_as_uint(f);
    unsigned r = u + 0x7FFFu + ((u >> 16) & 1u);
    return (unsigned short)(r >> 16);
}

// ================= CSR construction (3 CSRs batched) =================
struct Csr3 {
    const int* key[3];
    const int* other[3];
    int* deg;       // [3*N]
    int* cursor;    // [3*N]
    int* rowptr[3]; // [N+1]
    int* eids[3];   // [E]
    int* srcs[3];   // [E]
};

__global__ void k_hist3(Csr3 c) {
    int e = blockIdx.x * blockDim.x + threadIdx.x;
    int y = blockIdx.y;
    if (e < E_EDGES) atomicAdd(&c.deg[y * N_NODES + c.key[y][e]], 1);
}

// 3 blocks, 1024 threads each; 20 elems/thread serial + block scan
__global__ __launch_bounds__(1024) void k_scan3(Csr3 c) {
    const int PER = (N_NODES + 1023) / 1024;  // 20
    __shared__ int part[1024];
    const int y = blockIdx.x;
    const int* deg = c.deg + y * N_NODES;
    int* cursor = c.cursor + y * N_NODES;
    int* rowptr = c.rowptr[y];
    const int tid = threadIdx.x;
    const int base = tid * PER;
    int lv[PER];
    int lsum = 0;
#pragma unroll
    for (int i = 0; i < PER; i++) {
        int idx = base + i;
        int v = (idx < N_NODES) ? deg[idx] : 0;
        lv[i] = v; lsum += v;
    }
    part[tid] = lsum;
    __syncthreads();
    for (int off = 1; off < 1024; off <<= 1) {
        int t = (tid >= off) ? part[tid - off] : 0;
        __syncthreads();
        part[tid] += t;
        __syncthreads();
    }
    int run = part[tid] - lsum;
    if (tid == 0) rowptr[0] = 0;
#pragma unroll
    for (int i = 0; i < PER; i++) {
        int idx = base + i;
        if (idx < N_NODES) {
            cursor[idx] = run;
            run += lv[i];
            rowptr[idx + 1] = run;
        }
    }
}

__global__ void k_scatter3(Csr3 c) {
    int e = blockIdx.x * blockDim.x + threadIdx.x;
    int y = blockIdx.y;
    if (e >= E_EDGES) return;
    int k = c.key[y][e];
    int pos = atomicAdd(&c.cursor[y * N_NODES + k], 1);
    c.eids[y][pos] = e;
    c.srcs[y][pos] = c.other[y][e];
}

// ===== GANConv aggregation (gather): z[n] = bf16(x[n] + sum x[srcs]) =====
// fp32 input variant (x [N,64]): thread per (n, float4-chunk)
__global__ __launch_bounds__(256) void k_gather_f32(const float4* __restrict__ x,
                                                    const int* __restrict__ rowptr,
                                                    const int* __restrict__ srcs,
                                                    unsigned short* __restrict__ z) {
    int gid = blockIdx.x * blockDim.x + threadIdx.x;
    int n = gid >> 4;
    if (n >= N_NODES) return;
    int q = gid & 15;
    float4 acc = x[((size_t)n << 4) + q];
    int p1 = rowptr[n + 1];
    for (int p = rowptr[n]; p < p1; p++) {
        float4 v = x[((size_t)srcs[p] << 4) + q];
        acc.x += v.x; acc.y += v.y; acc.z += v.z; acc.w += v.w;
    }
    ushort4 o;
    o.x = f2bf(acc.x); o.y = f2bf(acc.y); o.z = f2bf(acc.z); o.w = f2bf(acc.w);
    *(ushort4*)&z[((size_t)n << 6) + (q << 2)] = o;
}

// bf16 input variant (x [N,128]): thread per (n, ushort8-chunk)
__global__ __launch_bounds__(256) void k_gather_bf(const u16x8* __restrict__ x,
                                                   const int* __restrict__ rowptr,
                                                   const int* __restrict__ srcs,
                                                   u16x8* __restrict__ z) {
    int gid = blockIdx.x * blockDim.x + threadIdx.x;
    int n = gid >> 4;
    if (n >= N_NODES) return;
    int q = gid & 15;
    u16x8 u0 = x[((size_t)n << 4) + q];
    float acc[8];
#pragma unroll
    for (int i = 0; i < 8; i++) acc[i] = bf2f(u0[i]);
    int p1 = rowptr[n + 1];
    for (int p = rowptr[n]; p < p1; p++) {
        u16x8 v = x[((size_t)srcs[p] << 4) + q];
#pragma unroll
        for (int i = 0; i < 8; i++) acc[i] += bf2f(v[i]);
    }
    u16x8 o;
#pragma unroll
    for (int i = 0; i < 8; i++) o[i] = f2bf(acc[i]);
    z[((size_t)n << 4) + q] = o;
}

// ===== weight prep: Wt[n][k] = bf16(W[k][n]) for 8 weights in one launch =====
struct WtJob  { const float* src; unsigned short* dst; int K; int N; };
struct WtJobs { WtJob j[8]; };
__global__ void k_wt_cast(WtJobs jobs) {
    WtJob jb = jobs.j[blockIdx.y];
    int total = jb.K * jb.N;
    for (int i = blockIdx.x * blockDim.x + threadIdx.x; i < total; i += gridDim.x * blockDim.x) {
        int nn = i / jb.K, kk = i - nn * jb.K;
        jb.dst[i] = f2bf(jb.src[(size_t)kk * jb.N + nn]);
    }
}

// ===== MFMA bf16 GEMM: C[M,N] = A[M,K] @ Wt[N,K]^T + bias; bf16 out =====
// 128x128 tile, 256 threads (4 waves). STATS: atomicAdd per-column sum/sumsq (incl bias).
template <int STATS>
__global__ __launch_bounds__(256) void k_mfma_gemm(const unsigned short* __restrict__ A,
                                                   const unsigned short* __restrict__ Wt,
                                                   const float* __restrict__ bias,
                                                   unsigned short* __restrict__ Cout,
                                                   int M, int K, int N,
                                                   float* __restrict__ sums) {
    __shared__ unsigned short As[128][40];
    __shared__ unsigned short Bs[128][40];
    const int t = threadIdx.x;
    const int wave = t >> 6, lane = t & 63;
    const int row0 = blockIdx.y * 128, col0 = blockIdx.x * 128;
    const int wm = (wave & 1) << 6, wn = (wave >> 1) << 6;
    const int lm = lane & 15, lk = (lane >> 4) << 3;
    f32x4 acc[4][4] = {};
    for (int k0 = 0; k0 < K; k0 += 32) {
        u16x8 av[2], wv[2];
#pragma unroll
        for (int i = 0; i < 2; i++) {
            int c = t + (i << 8);
            int r = c >> 2, ko = (c & 3) << 3;
            u16x8 zv = {};
            int gr = row0 + r;
            av[i] = (gr < M) ? *(const u16x8*)&A[(size_t)gr * K + k0 + ko] : zv;
            wv[i] = *(const u16x8*)&Wt[(size_t)(col0 + r) * K + k0 + ko];
        }
        __syncthreads();
#pragma unroll
        for (int i = 0; i < 2; i++) {
            int c = t + (i << 8);
            int r = c >> 2, ko = (c & 3) << 3;
            *(u16x8*)&As[r][ko] = av[i];
            *(u16x8*)&Bs[r][ko] = wv[i];
        }
        __syncthreads();
        bf16x8 af[4], bfm[4];
#pragma unroll
        for (int i = 0; i < 4; i++) af[i]  = *(const bf16x8*)&As[wm + (i << 4) + lm][lk];
#pragma unroll
        for (int j = 0; j < 4; j++) bfm[j] = *(const bf16x8*)&Bs[wn + (j << 4) + lm][lk];
#pragma unroll
        for (int i = 0; i < 4; i++)
#pragma unroll
            for (int j = 0; j < 4; j++)
                acc[i][j] = __builtin_amdgcn_mfma_f32_16x16x32_bf16(af[i], bfm[j], acc[i][j], 0, 0, 0);
    }
    const int lr4 = (lane >> 4) << 2;
    float s1[4] = {0.f, 0.f, 0.f, 0.f}, s2[4] = {0.f, 0.f, 0.f, 0.f};
#pragma unroll
    for (int j = 0; j < 4; j++) {
        int col = col0 + wn + (j << 4) + lm;
        float bv = bias[col];
#pragma unroll
        for (int i = 0; i < 4; i++) {
#pragma unroll
            for (int r = 0; r < 4; r++) {
                int row = row0 + wm + (i << 4) + lr4 + r;
                if (row < M) {
                    float v = acc[i][j][r] + bv;
                    Cout[(size_t)row * N + col] = f2bf(v);
                    if (STATS) { s1[j] += v; s2[j] += v * v; }
                }
            }
        }
    }
    if (STATS) {
#pragma unroll
        for (int j = 0; j < 4; j++) {
            s1[j] += __shfl_xor(s1[j], 16, 64); s1[j] += __shfl_xor(s1[j], 32, 64);
            s2[j] += __shfl_xor(s2[j], 16, 64); s2[j] += __shfl_xor(s2[j], 32, 64);
        }
        if ((lane >> 4) == 0) {
#pragma unroll
            for (int j = 0; j < 4; j++) {
                int col = col0 + wn + (j << 4) + lm;   // < 128 for stats GEMMs
                atomicAdd(&sums[col], s1[j]);
                atomicAdd(&sums[HID + col], s2[j]);
            }
        }
    }
}

// ===== BN apply (training mode): bf16 in -> relu-normalized bf16 out =====
__global__ void k_bn_apply_bf(const unsigned short* __restrict__ X,
                              unsigned short* __restrict__ Y, int M,
                              const float* __restrict__ sums,
                              const float* __restrict__ g, const float* __restrict__ b) {
    int idx = blockIdx.x * blockDim.x + threadIdx.x;
    if (idx >= M * HID) return;
    int j = idx & (HID - 1);
    float mean = sums[j] / M;
    float istd = rsqrtf(sums[HID + j] / M - mean * mean + EPSV);
    float v = fmaxf((bf2f(X[idx]) - mean) * istd * g[j] + b[j], 0.f);
    Y[idx] = f2bf(v);
}

// ================= fused ATTConv (GATv2): logit + softmax + gather =================
// One wave per node; lane l -> channels 4l..4l+3, head h = l>>5.
// xr[n] and att cached in registers; logits cached in LDS (online max/denom);
// pass 2 re-gathers xl for the weighted sum. CAP overflow -> recompute.
#define ATT_CAP 192
template <int CONCAT, int WITH_ALPHA>
__global__ __launch_bounds__(256) void k_att_fused(const ushort4* __restrict__ xl,
                                                   const ushort4* __restrict__ xr,
                                                   const int* __restrict__ rowptr,
                                                   const int* __restrict__ srcs,
                                                   const int* __restrict__ eids,
                                                   const float* __restrict__ att,
                                                   const float* __restrict__ bias,
                                                   void* __restrict__ outp,
                                                   float* __restrict__ alpha_out) {
    __shared__ float s_lg[4][ATT_CAP][2];
    const int t = threadIdx.x;
    const int wave = t >> 6, l = t & 63;
    const int n = blockIdx.x * 4 + wave;   // N_NODES % 4 == 0
    const int h = l >> 5;
    // cached xr row + att slice
    ushort4 ur = xr[((size_t)n << 6) + l];
    float xr4[4] = {bf2f(ur.x), bf2f(ur.y), bf2f(ur.z), bf2f(ur.w)};
    const float* ap = &att[h * HID + ((l & 31) << 2)];
    float at4[4] = {ap[0], ap[1], ap[2], ap[3]};
    const int p0 = rowptr[n], p1 = rowptr[n + 1];
    // ---- pass 1: logits (LDS cache) + online max/denom ----
    float m = -INFINITY, ssum = 0.f;
    for (int p = p0; p < p1; p++) {
        ushort4 uv = xl[((size_t)srcs[p] << 6) + l];
        float v0 = bf2f(uv.x) + xr4[0]; v0 = (v0 > 0.f) ? v0 : 0.2f * v0;
        float v1 = bf2f(uv.y) + xr4[1]; v1 = (v1 > 0.f) ? v1 : 0.2f * v1;
        float v2 = bf2f(uv.z) + xr4[2]; v2 = (v2 > 0.f) ? v2 : 0.2f * v2;
        float v3 = bf2f(uv.w) + xr4[3]; v3 = (v3 > 0.f) ? v3 : 0.2f * v3;
        float tl = at4[0] * v0 + at4[1] * v1 + at4[2] * v2 + at4[3] * v3;
#pragma unroll
        for (int k = 1; k <= 16; k <<= 1) tl += __shfl_xor(tl, k, 64);
        if ((p - p0) < ATT_CAP && (l & 31) == 0) s_lg[wave][p - p0][h] = tl;
        float mn = fmaxf(m, tl);
        ssum = ssum * __expf(m - mn) + __expf(tl - mn);
        m = mn;
    }
    float inv = 1.f / (ssum + 1e-16f);
    // ---- pass 2: weighted gather ----
    float acc[4] = {0.f, 0.f, 0.f, 0.f};
    for (int p = p0; p < p1; p++) {
        ushort4 uv = xl[((size_t)srcs[p] << 6) + l];
        float lg;
        if ((p - p0) < ATT_CAP) {
            lg = s_lg[wave][p - p0][h];
        } else {  // recompute (cold path)
            float v0 = bf2f(uv.x) + xr4[0]; v0 = (v0 > 0.f) ? v0 : 0.2f * v0;
            float v1 = bf2f(uv.y) + xr4[1]; v1 = (v1 > 0.f) ? v1 : 0.2f * v1;
            float v2 = bf2f(uv.z) + xr4[2]; v2 = (v2 > 0.f) ? v2 : 0.2f * v2;
            float v3 = bf2f(uv.w) + xr4[3]; v3 = (v3 > 0.f) ? v3 : 0.2f * v3;
            lg = at4[0] * v0 + at4[1] * v1 + at4[2] * v2 + at4[3] * v3;
#pragma unroll
            for (int k = 1; k <= 16; k <<= 1) lg += __shfl_xor(lg, k, 64);
        }
        float a = __expf(lg - m) * inv;
        acc[0] = fmaf(a, bf2f(uv.x), acc[0]);
        acc[1] = fmaf(a, bf2f(uv.y), acc[1]);
        acc[2] = fmaf(a, bf2f(uv.z), acc[2]);
        acc[3] = fmaf(a, bf2f(uv.w), acc[3]);
        if (WITH_ALPHA && (l & 31) == 0) alpha_out[eids[p] * HEADS + h] = a;
    }
    // ---- epilogue ----
    if (CONCAT) {
        const float* bp = &bias[l << 2];
        ushort4 o;
        o.x = f2bf(fmaxf(acc[0] + bp[0], 0.f));
        o.y = f2bf(fmaxf(acc[1] + bp[1], 0.f));
        o.z = f2bf(fmaxf(acc[2] + bp[2], 0.f));
        o.w = f2bf(fmaxf(acc[3] + bp[3], 0.f));
        ((ushort4*)outp)[((size_t)n << 6) + l] = o;
    } else {
        float o[4];
#pragma unroll
        for (int i = 0; i < 4; i++) {
            float other = __shfl_xor(acc[i], 32, 64);
            o[i] = 0.5f * (acc[i] + other);
        }
        if (l < 32) {
            const float* bp = &bias[(l & 31) << 2];
            float4 ov;
            ov.x = fmaxf(o[0] + bp[0], 0.f); ov.y = fmaxf(o[1] + bp[1], 0.f);
            ov.z = fmaxf(o[2] + bp[2], 0.f); ov.w = fmaxf(o[3] + bp[3], 0.f);
            ((float4*)outp)[((size_t)n << 5) + l] = ov;
        }
    }
}

// ================= pooling over sorted batch_index (node-parallel) =================
template <int C>
__global__ __launch_bounds__(256) void k_pool_atomic(const float* __restrict__ X,
                                                     const int* __restrict__ batch,
                                                     float* __restrict__ pool, int npb) {
    const int RP = 256 / C;
    int c = threadIdx.x & (C - 1);
    int rofs = threadIdx.x / C;
    int i0 = blockIdx.x * npb;
    int i1 = min(i0 + npb, N_NODES);
    float acc = 0.f;
    int gcur = -1;
    for (int i = i0 + rofs; i < i1; i += RP) {
        int g = batch[i];
        if (g != gcur) {
            if (gcur >= 0) atomicAdd(&pool[gcur * C + c], acc);
            acc = 0.f; gcur = g;
        }
        acc += X[(size_t)i * C + c];
    }
    if (gcur >= 0) atomicAdd(&pool[gcur * C + c], acc);
}

// ================= final prediction head =================
__global__ void k_head(const float* __restrict__ pool0, const float* __restrict__ poolL,
                       const float* __restrict__ p0w, const float* __restrict__ p0b,
                       const float* __restrict__ pLw, const float* __restrict__ pLb,
                       const float* __restrict__ ow, const float* __restrict__ ob,
                       float* __restrict__ outputs) {
    int g = blockIdx.x;
    int m = threadIdx.x;
    __shared__ float sh[MIDD];
    if (m < MIDD) {
        float s = p0b[m] + pLb[m];
        for (int k = 0; k < F_INN; k++) s += pool0[g * F_INN + k] * p0w[k * MIDD + m];
        for (int k = 0; k < HID; k++)  s += poolL[g * HID + k] * pLw[k * MIDD + m];
        sh[m] = fmaxf(s, 0.f);
    }
    __syncthreads();
    if (m == 0) {
        float s = ob[0];
        for (int k = 0; k < MIDD; k++) s += sh[k] * ow[k];
        outputs[g] = s;
    }
}

extern "C" void kernel_launch(void* const* d_in, const int* in_sizes, int n_in,
                              void* d_out, int out_size, void* d_ws, size_t ws_size,
                              hipStream_t stream) {
    // ---- inputs ----
    const float* x      = (const float*)d_in[0];
    const int*   ei     = (const int*)d_in[1];
    const int*   aei    = (const int*)d_in[2];
    const int*   batch  = (const int*)d_in[3];
    const float* g0_w1  = (const float*)d_in[4];
    const float* g0_b1  = (const float*)d_in[5];
    const float* g0_bng = (const float*)d_in[6];
    const float* g0_bnb = (const float*)d_in[7];
    const float* g0_w2  = (const float*)d_in[8];
    const float* g0_b2  = (const float*)d_in[9];
    const float* g1_w1  = (const float*)d_in[10];
    const float* g1_b1  = (const float*)d_in[11];
    const float* g1_bng = (const float*)d_in[12];
    const float* g1_bnb = (const float*)d_in[13];
    const float* g1_w2  = (const float*)d_in[14];
    const float* g1_b2  = (const float*)d_in[15];
    const float* bn0_g  = (const float*)d_in[16];
    const float* bn0_b  = (const float*)d_in[17];
    const float* bn1_g  = (const float*)d_in[18];
    const float* bn1_b  = (const float*)d_in[19];
    const float* a1_wl  = (const float*)d_in[20];
    const float* a1_bl  = (const float*)d_in[21];
    const float* a1_wr  = (const float*)d_in[22];
    const float* a1_br  = (const float*)d_in[23];
    const float* a1_att = (const float*)d_in[24];
    const float* a1_bias= (const float*)d_in[25];
    const float* a2_wl  = (const float*)d_in[26];
    const float* a2_bl  = (const float*)d_in[27];
    const float* a2_wr  = (const float*)d_in[28];
    const float* a2_br  = (const float*)d_in[29];
    const float* a2_att = (const float*)d_in[30];
    const float* a2_bias= (const float*)d_in[31];
    const float* p0w    = (const float*)d_in[32];
    const float* p0b    = (const float*)d_in[33];
    const float* pLw    = (const float*)d_in[34];
    const float* pLb    = (const float*)d_in[35];
    const float* ow     = (const float*)d_in[36];
    const float* ob     = (const float*)d_in[37];

    // ---- outputs ----
    float* out_head  = (float*)d_out;
    float* atten_out = out_head + G_GR;
    float* alpha_out = atten_out + (size_t)N_NODES * HID;

    // ---- workspace ----
    // zero-region (one memset): sums4 | pool0 | poolL | deg3
    float* ws = (float*)d_ws;
    float* sums4 = ws;                                 // 4*256
    float* pool0 = sums4 + 4 * 256;                    // G*64
    float* poolL = pool0 + G_GR * F_INN;               // G*128
    int*   deg3  = (int*)(poolL + G_GR * HID);         // 3*N
    const size_t zero_bytes = (4 * 256 + G_GR * F_INN + G_GR * HID + 3 * N_NODES) * 4;

    int* ip = deg3 + 3 * N_NODES;
    int* cursor3 = ip; ip += 3 * N_NODES;
    int* rowptr[3]; int* eids[3]; int* srcs[3];
    for (int c = 0; c < 3; c++) {
        rowptr[c] = ip; ip += N_NODES + 1;
        eids[c]   = ip; ip += E_EDGES;
        srcs[c]   = ip; ip += E_EDGES;
    }
    const size_t NB = (size_t)N_NODES * HC;
    unsigned short* BFa = (unsigned short*)ip;         // [N,HC] bf16
    unsigned short* BFb = BFa + NB;
    unsigned short* BFc = BFb + NB;
    unsigned short* BFh1 = BFc + NB;                   // [N,HID] bf16
    unsigned short* g0w1t = BFh1 + (size_t)N_NODES * HID;
    unsigned short* g0w2t = g0w1t + 128 * 64;
    unsigned short* g1w1t = g0w2t + 128 * 128;
    unsigned short* g1w2t = g1w1t + 128 * 128;
    unsigned short* a1wlt = g1w2t + 128 * 128;
    unsigned short* a1wrt = a1wlt + 256 * 128;
    unsigned short* a2wlt = a1wrt + 256 * 128;
    unsigned short* a2wrt = a2wlt + 256 * 256;

    const int* e_row = ei;
    const int* e_col = ei + E_EDGES;
    const int* a_src = aei;
    const int* a_dst = aei + E_EDGES;

    const int TB = 256;
#define GRID1(n) dim3(CDIV((n), TB))

    // ===== weight transpose+cast =====
    {
        WtJobs jobs;
        jobs.j[0] = {g0_w1, g0w1t, F_INN, HID};
        jobs.j[1] = {g0_w2, g0w2t, HID,   HID};
        jobs.j[2] = {g1_w1, g1w1t, HID,   HID};
        jobs.j[3] = {g1_w2, g1w2t, HID,   HID};
        jobs.j[4] = {a1_wl, a1wlt, HID,   HC};
        jobs.j[5] = {a1_wr, a1wrt, HID,   HC};
        jobs.j[6] = {a2_wl, a2wlt, HC,    HC};
        jobs.j[7] = {a2_wr, a2wrt, HC,    HC};
        k_wt_cast<<<dim3(32, 8), TB, 0, stream>>>(jobs);
    }

    // ===== zero sums/pools/deg in one shot; build 3 CSRs batched =====
    hipMemsetAsync(sums4, 0, zero_bytes, stream);
    {
        Csr3 c;
        c.key[0] = e_row; c.other[0] = e_col;   // GANConv: agg by row
        c.key[1] = e_col; c.other[1] = e_row;   // ATT1: dst = e_col
        c.key[2] = a_dst; c.other[2] = a_src;   // ATT2: dst = a_dst
        c.deg = deg3; c.cursor = cursor3;
        for (int i = 0; i < 3; i++) { c.rowptr[i] = rowptr[i]; c.eids[i] = eids[i]; c.srcs[i] = srcs[i]; }
        k_hist3<<<dim3(CDIV(E_EDGES, TB), 3), TB, 0, stream>>>(c);
        k_scan3<<<dim3(3), 1024, 0, stream>>>(c);
        k_scatter3<<<dim3(CDIV(E_EDGES, TB), 3), TB, 0, stream>>>(c);
    }

    const dim3 gemm_g1(1, CDIV(N_NODES, 128));   // N=128
    const dim3 gemm_g2(2, CDIV(N_NODES, 128));   // N=256

    // ===== GANConv 0 =====
    k_gather_f32<<<GRID1(N_NODES * 16), TB, 0, stream>>>((const float4*)x, rowptr[0], srcs[0], BFa);
    k_mfma_gemm<1><<<gemm_g1, TB, 0, stream>>>(BFa, g0w1t, g0_b1, BFb, N_NODES, F_INN, HID, sums4 + 0);
    k_bn_apply_bf<<<GRID1(N_NODES * HID), TB, 0, stream>>>(BFb, BFa, N_NODES, sums4 + 0, g0_bng, g0_bnb);
    k_mfma_gemm<1><<<gemm_g1, TB, 0, stream>>>(BFa, g0w2t, g0_b2, BFb, N_NODES, HID, HID, sums4 + 256);
    k_bn_apply_bf<<<GRID1(N_NODES * HID), TB, 0, stream>>>(BFb, BFh1, N_NODES, sums4 + 256, bn0_g, bn0_b);
    // h1 bf16 in BFh1

    // ===== GANConv 1 =====
    k_gather_bf<<<GRID1(N_NODES * 16), TB, 0, stream>>>((const u16x8*)BFh1, rowptr[0], srcs[0], (u16x8*)BFa);
    k_mfma_gemm<1><<<gemm_g1, TB, 0, stream>>>(BFa, g1w1t, g1_b1, BFb, N_NODES, HID, HID, sums4 + 512);
    k_bn_apply_bf<<<GRID1(N_NODES * HID), TB, 0, stream>>>(BFb, BFa, N_NODES, sums4 + 512, g1_bng, g1_bnb);
    k_mfma_gemm<1><<<gemm_g1, TB, 0, stream>>>(BFa, g1w2t, g1_b2, BFb, N_NODES, HID, HID, sums4 + 768);
    k_bn_apply_bf<<<GRID1(N_NODES * HID), TB, 0, stream>>>(BFb, BFa, N_NODES, sums4 + 768, bn1_g, bn1_b);
    // h2 bf16 in BFa [N,HID]

    // ===== ATTConv 1 (src=e_row, dst=e_col, concat=True) =====
    k_mfma_gemm<0><<<gemm_g2, TB, 0, stream>>>(BFa, a1wlt, a1_bl, BFb, N_NODES, HID, HC, nullptr);
    k_mfma_gemm<0><<<gemm_g2, TB, 0, stream>>>(BFa, a1wrt, a1_br, BFc, N_NODES, HID, HC, nullptr);
    k_att_fused<1, 0><<<dim3(N_NODES / 4), TB, 0, stream>>>(
        (const ushort4*)BFb, (const ushort4*)BFc, rowptr[1], srcs[1], eids[1],
        a1_att, a1_bias, (void*)BFa, nullptr);
    // emb bf16 in BFa [N,HC]

    // ===== ATTConv 2 (src=a_src, dst=a_dst, concat=False) =====
    k_mfma_gemm<0><<<gemm_g2, TB, 0, stream>>>(BFa, a2wlt, a2_bl, BFb, N_NODES, HC, HC, nullptr);
    k_mfma_gemm<0><<<gemm_g2, TB, 0, stream>>>(BFa, a2wrt, a2_br, BFc, N_NODES, HC, HC, nullptr);
    k_att_fused<0, 1><<<dim3(N_NODES / 4), TB, 0, stream>>>(
        (const ushort4*)BFb, (const ushort4*)BFc, rowptr[2], srcs[2], eids[2],
        a2_att, a2_bias, (void*)atten_out, alpha_out);

    // ===== pooling + head =====
    {
        const int npb = 64;  // 313 blocks
        k_pool_atomic<F_INN><<<dim3(CDIV(N_NODES, npb)), TB, 0, stream>>>(x, batch, pool0, npb);
        k_pool_atomic<HID><<<dim3(CDIV(N_NODES, npb)), TB, 0, stream>>>(atten_out, batch, poolL, npb);
    }
    k_head<<<dim3(G_GR), 64, 0, stream>>>(pool0, poolL, p0w, p0b, pLw, pLb, ow, ob, out_head);
}

// Round 8
// 579.207 us; speedup vs baseline: 6.3586x; 1.2417x over previous
//
#include <hip/hip_runtime.h>
#include <hip/hip_bf16.h>

#define N_NODES 20000
#define E_EDGES 320000
#define F_INN   64
#define HID     128
#define HEADS   2
#define HC      (HEADS * HID)   // 256
#define G_GR    64
#define MIDD    32
#define EPSV    1e-5f

#define CDIV(a, b) (((a) + (b) - 1) / (b))

typedef __attribute__((ext_vector_type(8))) short          bf16x8;  // MFMA A/B frag
typedef __attribute__((ext_vector_type(4))) float          f32x4;   // MFMA C/D frag
typedef __attribute__((ext_vector_type(8))) unsigned short u16x8;

// ---------- bf16 helpers (RNE) ----------
__device__ inline float bf2f(unsigned short u) { return __uint_as_float((unsigned)u << 16); }
__device__ inline unsigned short f2bf(float f) {
    unsigned u = __float_as_uint(f);
    unsigned r = u + 0x7FFFu + ((u >> 16) & 1u);
    return (unsigned short)(r >> 16);
}

// ================= CSR construction (3 CSRs batched) =================
struct Csr3 {
    const int* key[3];
    const int* other[3];
    int* deg;       // [3*N]
    int* cursor;    // [3*N]
    int* rowptr[3]; // [N+1]
    int* eids[3];   // [E]
    int* srcs[3];   // [E]
};

__global__ void k_hist3(Csr3 c) {
    int e = blockIdx.x * blockDim.x + threadIdx.x;
    int y = blockIdx.y;
    if (e < E_EDGES) atomicAdd(&c.deg[y * N_NODES + c.key[y][e]], 1);
}

__global__ __launch_bounds__(1024) void k_scan3(Csr3 c) {
    const int PER = (N_NODES + 1023) / 1024;  // 20
    __shared__ int part[1024];
    const int y = blockIdx.x;
    const int* deg = c.deg + y * N_NODES;
    int* cursor = c.cursor + y * N_NODES;
    int* rowptr = c.rowptr[y];
    const int tid = threadIdx.x;
    const int base = tid * PER;
    int lv[PER];
    int lsum = 0;
#pragma unroll
    for (int i = 0; i < PER; i++) {
        int idx = base + i;
        int v = (idx < N_NODES) ? deg[idx] : 0;
        lv[i] = v; lsum += v;
    }
    part[tid] = lsum;
    __syncthreads();
    for (int off = 1; off < 1024; off <<= 1) {
        int t = (tid >= off) ? part[tid - off] : 0;
        __syncthreads();
        part[tid] += t;
        __syncthreads();
    }
    int run = part[tid] - lsum;
    if (tid == 0) rowptr[0] = 0;
#pragma unroll
    for (int i = 0; i < PER; i++) {
        int idx = base + i;
        if (idx < N_NODES) {
            cursor[idx] = run;
            run += lv[i];
            rowptr[idx + 1] = run;
        }
    }
}

__global__ void k_scatter3(Csr3 c) {
    int e = blockIdx.x * blockDim.x + threadIdx.x;
    int y = blockIdx.y;
    if (e >= E_EDGES) return;
    int k = c.key[y][e];
    int pos = atomicAdd(&c.cursor[y * N_NODES + k], 1);
    c.eids[y][pos] = e;
    c.srcs[y][pos] = c.other[y][e];
}

// ===== GANConv aggregation (gather): z[n] = bf16(x[n] + sum x[srcs]) =====
__global__ __launch_bounds__(256) void k_gather_f32(const float4* __restrict__ x,
                                                    const int* __restrict__ rowptr,
                                                    const int* __restrict__ srcs,
                                                    unsigned short* __restrict__ z) {
    int gid = blockIdx.x * blockDim.x + threadIdx.x;
    int n = gid >> 4;
    if (n >= N_NODES) return;
    int q = gid & 15;
    float4 acc = x[((size_t)n << 4) + q];
    int p1 = rowptr[n + 1];
    for (int p = rowptr[n]; p < p1; p++) {
        float4 v = x[((size_t)srcs[p] << 4) + q];
        acc.x += v.x; acc.y += v.y; acc.z += v.z; acc.w += v.w;
    }
    ushort4 o;
    o.x = f2bf(acc.x); o.y = f2bf(acc.y); o.z = f2bf(acc.z); o.w = f2bf(acc.w);
    *(ushort4*)&z[((size_t)n << 6) + (q << 2)] = o;
}

__global__ __launch_bounds__(256) void k_gather_bf(const u16x8* __restrict__ x,
                                                   const int* __restrict__ rowptr,
                                                   const int* __restrict__ srcs,
                                                   u16x8* __restrict__ z) {
    int gid = blockIdx.x * blockDim.x + threadIdx.x;
    int n = gid >> 4;
    if (n >= N_NODES) return;
    int q = gid & 15;
    u16x8 u0 = x[((size_t)n << 4) + q];
    float acc[8];
#pragma unroll
    for (int i = 0; i < 8; i++) acc[i] = bf2f(u0[i]);
    int p1 = rowptr[n + 1];
    for (int p = rowptr[n]; p < p1; p++) {
        u16x8 v = x[((size_t)srcs[p] << 4) + q];
#pragma unroll
        for (int i = 0; i < 8; i++) acc[i] += bf2f(v[i]);
    }
    u16x8 o;
#pragma unroll
    for (int i = 0; i < 8; i++) o[i] = f2bf(acc[i]);
    z[((size_t)n << 4) + q] = o;
}

// ===== weight prep: Wt[n][k] = bf16(W[k][n]) for 8 weights in one launch =====
struct WtJob  { const float* src; unsigned short* dst; int K; int N; };
struct WtJobs { WtJob j[8]; };
__global__ void k_wt_cast(WtJobs jobs) {
    WtJob jb = jobs.j[blockIdx.y];
    int total = jb.K * jb.N;
    for (int i = blockIdx.x * blockDim.x + threadIdx.x; i < total; i += gridDim.x * blockDim.x) {
        int nn = i / jb.K, kk = i - nn * jb.K;
        jb.dst[i] = f2bf(jb.src[(size_t)kk * jb.N + nn]);
    }
}

// ===== MFMA bf16 GEMM: C[M,N] = A[M,K] @ Wt[N,K]^T + bias; bf16 out =====
// TM=128: 128x128 tile, waves 2x2 (each 64x64). TM=64: 64x128 tile, waves 1x4 (each 64x32).
// STATS: atomicAdd per-column sum/sumsq (incl bias) for BN.
template <int STATS, int TM>
__global__ __launch_bounds__(256) void k_mfma_gemm(const unsigned short* __restrict__ A,
                                                   const unsigned short* __restrict__ Wt,
                                                   const float* __restrict__ bias,
                                                   unsigned short* __restrict__ Cout,
                                                   int M, int K, int N,
                                                   float* __restrict__ sums) {
    constexpr int BNF = (TM == 128) ? 4 : 2;      // n-frags per wave
    __shared__ unsigned short As[TM][40];
    __shared__ unsigned short Bs[128][40];
    const int t = threadIdx.x;
    const int wave = t >> 6, lane = t & 63;
    const int row0 = blockIdx.y * TM, col0 = blockIdx.x * 128;
    const int wm = (TM == 128) ? ((wave & 1) << 6) : 0;
    const int wn = (TM == 128) ? ((wave >> 1) << 6) : (wave << 5);
    const int lm = lane & 15, lk = (lane >> 4) << 3;
    constexpr int APASS = TM / 64;
    f32x4 acc[4][BNF] = {};
    for (int k0 = 0; k0 < K; k0 += 32) {
        u16x8 av[APASS], wv[2];
#pragma unroll
        for (int i = 0; i < APASS; i++) {
            int c = t + (i << 8);
            int r = c >> 2, ko = (c & 3) << 3;
            u16x8 zv = {};
            int gr = row0 + r;
            av[i] = (gr < M) ? *(const u16x8*)&A[(size_t)gr * K + k0 + ko] : zv;
        }
#pragma unroll
        for (int i = 0; i < 2; i++) {
            int c = t + (i << 8);
            int r = c >> 2, ko = (c & 3) << 3;
            wv[i] = *(const u16x8*)&Wt[(size_t)(col0 + r) * K + k0 + ko];
        }
        __syncthreads();
#pragma unroll
        for (int i = 0; i < APASS; i++) {
            int c = t + (i << 8);
            int r = c >> 2, ko = (c & 3) << 3;
            *(u16x8*)&As[r][ko] = av[i];
        }
#pragma unroll
        for (int i = 0; i < 2; i++) {
            int c = t + (i << 8);
            int r = c >> 2, ko = (c & 3) << 3;
            *(u16x8*)&Bs[r][ko] = wv[i];
        }
        __syncthreads();
        bf16x8 af[4], bfm[BNF];
#pragma unroll
        for (int i = 0; i < 4; i++) af[i]  = *(const bf16x8*)&As[wm + (i << 4) + lm][lk];
#pragma unroll
        for (int j = 0; j < BNF; j++) bfm[j] = *(const bf16x8*)&Bs[wn + (j << 4) + lm][lk];
#pragma unroll
        for (int i = 0; i < 4; i++)
#pragma unroll
            for (int j = 0; j < BNF; j++)
                acc[i][j] = __builtin_amdgcn_mfma_f32_16x16x32_bf16(af[i], bfm[j], acc[i][j], 0, 0, 0);
    }
    const int lr4 = (lane >> 4) << 2;
    float s1[BNF], s2[BNF];
#pragma unroll
    for (int j = 0; j < BNF; j++) { s1[j] = 0.f; s2[j] = 0.f; }
#pragma unroll
    for (int j = 0; j < BNF; j++) {
        int col = col0 + wn + (j << 4) + lm;
        float bv = bias[col];
#pragma unroll
        for (int i = 0; i < 4; i++) {
#pragma unroll
            for (int r = 0; r < 4; r++) {
                int row = row0 + wm + (i << 4) + lr4 + r;
                if (row < M) {
                    float v = acc[i][j][r] + bv;
                    Cout[(size_t)row * N + col] = f2bf(v);
                    if (STATS) { s1[j] += v; s2[j] += v * v; }
                }
            }
        }
    }
    if (STATS) {
#pragma unroll
        for (int j = 0; j < BNF; j++) {
            s1[j] += __shfl_xor(s1[j], 16, 64); s1[j] += __shfl_xor(s1[j], 32, 64);
            s2[j] += __shfl_xor(s2[j], 16, 64); s2[j] += __shfl_xor(s2[j], 32, 64);
        }
        if ((lane >> 4) == 0) {
#pragma unroll
            for (int j = 0; j < BNF; j++) {
                int col = col0 + wn + (j << 4) + lm;   // < 128 for stats GEMMs
                atomicAdd(&sums[col], s1[j]);
                atomicAdd(&sums[HID + col], s2[j]);
            }
        }
    }
}

// ===== BN apply (training mode): bf16 in -> relu-normalized bf16 out =====
__global__ void k_bn_apply_bf(const unsigned short* __restrict__ X,
                              unsigned short* __restrict__ Y, int M,
                              const float* __restrict__ sums,
                              const float* __restrict__ g, const float* __restrict__ b) {
    int idx = blockIdx.x * blockDim.x + threadIdx.x;
    if (idx >= M * HID) return;
    int j = idx & (HID - 1);
    float mean = sums[j] / M;
    float istd = rsqrtf(sums[HID + j] / M - mean * mean + EPSV);
    float v = fmaxf((bf2f(X[idx]) - mean) * istd * g[j] + b[j], 0.f);
    Y[idx] = f2bf(v);
}

// ========== fused ATTConv (GATv2): single-pass flash-style online softmax ==========
// One wave per node; lane l -> channels 4l..4l+3, head h = l>>5.
// Per edge: ONE xl row load serves logit AND accumulation; online max/denom rescale.
// Logits cached in LDS only for alpha output (att2); parallel alpha write post-loop.
#define ATT_CAP 192
template <int CONCAT, int WITH_ALPHA>
__global__ __launch_bounds__(256) void k_att_fused(const ushort4* __restrict__ xl,
                                                   const ushort4* __restrict__ xr,
                                                   const int* __restrict__ rowptr,
                                                   const int* __restrict__ srcs,
                                                   const int* __restrict__ eids,
                                                   const float* __restrict__ att,
                                                   const float* __restrict__ bias,
                                                   void* __restrict__ outp,
                                                   float* __restrict__ alpha_out) {
    __shared__ float s_lg[4][ATT_CAP][2];
    const int t = threadIdx.x;
    const int wave = t >> 6, l = t & 63;
    const int n = blockIdx.x * 4 + wave;   // N_NODES % 4 == 0
    const int h = l >> 5;
    ushort4 ur = xr[((size_t)n << 6) + l];
    float xr4[4] = {bf2f(ur.x), bf2f(ur.y), bf2f(ur.z), bf2f(ur.w)};
    const float* ap = &att[h * HID + ((l & 31) << 2)];
    float at4[4] = {ap[0], ap[1], ap[2], ap[3]};
    const int p0 = rowptr[n], p1 = rowptr[n + 1];

    float m = -INFINITY, ssum = 0.f;
    float acc[4] = {0.f, 0.f, 0.f, 0.f};

#define ATT_LOGIT(uv, x4, tl) do { \
        x4[0] = bf2f(uv.x); x4[1] = bf2f(uv.y); x4[2] = bf2f(uv.z); x4[3] = bf2f(uv.w); \
        float v0 = x4[0] + xr4[0]; v0 = (v0 > 0.f) ? v0 : 0.2f * v0; \
        float v1 = x4[1] + xr4[1]; v1 = (v1 > 0.f) ? v1 : 0.2f * v1; \
        float v2 = x4[2] + xr4[2]; v2 = (v2 > 0.f) ? v2 : 0.2f * v2; \
        float v3 = x4[3] + xr4[3]; v3 = (v3 > 0.f) ? v3 : 0.2f * v3; \
        tl = at4[0] * v0 + at4[1] * v1 + at4[2] * v2 + at4[3] * v3; \
    } while (0)

#define ATT_ONLINE(x4, tl, idx) do { \
        float mn = fmaxf(m, tl); \
        float sc = __expf(m - mn); \
        float w  = __expf(tl - mn); \
        ssum = ssum * sc + w; \
        acc[0] = acc[0] * sc + w * x4[0]; \
        acc[1] = acc[1] * sc + w * x4[1]; \
        acc[2] = acc[2] * sc + w * x4[2]; \
        acc[3] = acc[3] * sc + w * x4[3]; \
        m = mn; \
        if (WITH_ALPHA && (idx) < ATT_CAP && (l & 31) == 0) s_lg[wave][idx][h] = tl; \
    } while (0)

    int p = p0;
    for (; p + 4 <= p1; p += 4) {
        float x4[4][4], tl[4];
        ushort4 uv[4];
#pragma unroll
        for (int j = 0; j < 4; j++) uv[j] = xl[((size_t)srcs[p + j] << 6) + l];
#pragma unroll
        for (int j = 0; j < 4; j++) ATT_LOGIT(uv[j], x4[j], tl[j]);
#pragma unroll
        for (int k = 1; k <= 16; k <<= 1) {
#pragma unroll
            for (int j = 0; j < 4; j++) tl[j] += __shfl_xor(tl[j], k, 64);
        }
#pragma unroll
        for (int j = 0; j < 4; j++) ATT_ONLINE(x4[j], tl[j], p + j - p0);
    }
    for (; p < p1; p++) {
        float x4[4], tl;
        ushort4 uv = xl[((size_t)srcs[p] << 6) + l];
        ATT_LOGIT(uv, x4, tl);
#pragma unroll
        for (int k = 1; k <= 16; k <<= 1) tl += __shfl_xor(tl, k, 64);
        ATT_ONLINE(x4, tl, p - p0);
    }
    float inv = 1.f / (ssum + 1e-16f);

    // ---- alpha output (att2): parallel from LDS cache ----
    if (WITH_ALPHA) {
        __syncthreads();  // no-op ordering safety for LDS (wave-private region, cheap)
        float m_o   = __shfl_xor(m, 32, 64);
        float inv_o = __shfl_xor(inv, 32, 64);
        float m2[2], i2[2];
        m2[h] = m; m2[1 - h] = m_o;
        i2[h] = inv; i2[1 - h] = inv_o;
        int cnt = p1 - p0;
        int ccnt = (cnt < ATT_CAP) ? cnt : ATT_CAP;
        for (int i = l; i < ccnt * 2; i += 64) {
            int idx = i >> 1, hh = i & 1;
            float a = __expf(s_lg[wave][idx][hh] - m2[hh]) * i2[hh];
            alpha_out[eids[p0 + idx] * HEADS + hh] = a;
        }
        // overflow fallback (deg > ATT_CAP): serial recompute (practically never taken)
        for (int pp = p0 + ATT_CAP; pp < p1; pp++) {
            float x4[4], tl;
            ushort4 uv = xl[((size_t)srcs[pp] << 6) + l];
            ATT_LOGIT(uv, x4, tl);
#pragma unroll
            for (int k = 1; k <= 16; k <<= 1) tl += __shfl_xor(tl, k, 64);
            if ((l & 31) == 0) alpha_out[eids[pp] * HEADS + h] = __expf(tl - m) * inv;
        }
    }

    // ---- epilogue ----
    if (CONCAT) {
        const float* bp = &bias[l << 2];
        ushort4 o;
        o.x = f2bf(fmaxf(acc[0] * inv + bp[0], 0.f));
        o.y = f2bf(fmaxf(acc[1] * inv + bp[1], 0.f));
        o.z = f2bf(fmaxf(acc[2] * inv + bp[2], 0.f));
        o.w = f2bf(fmaxf(acc[3] * inv + bp[3], 0.f));
        ((ushort4*)outp)[((size_t)n << 6) + l] = o;
    } else {
        float o[4];
#pragma unroll
        for (int i = 0; i < 4; i++) {
            float v = acc[i] * inv;
            float other = __shfl_xor(v, 32, 64);
            o[i] = 0.5f * (v + other);
        }
        if (l < 32) {
            const float* bp = &bias[(l & 31) << 2];
            float4 ov;
            ov.x = fmaxf(o[0] + bp[0], 0.f); ov.y = fmaxf(o[1] + bp[1], 0.f);
            ov.z = fmaxf(o[2] + bp[2], 0.f); ov.w = fmaxf(o[3] + bp[3], 0.f);
            ((float4*)outp)[((size_t)n << 5) + l] = ov;
        }
    }
#undef ATT_LOGIT
#undef ATT_ONLINE
}

// ================= pooling over sorted batch_index (node-parallel) =================
template <int C>
__global__ __launch_bounds__(256) void k_pool_atomic(const float* __restrict__ X,
                                                     const int* __restrict__ batch,
                                                     float* __restrict__ pool, int npb) {
    const int RP = 256 / C;
    int c = threadIdx.x & (C - 1);
    int rofs = threadIdx.x / C;
    int i0 = blockIdx.x * npb;
    int i1 = min(i0 + npb, N_NODES);
    float acc = 0.f;
    int gcur = -1;
    for (int i = i0 + rofs; i < i1; i += RP) {
        int g = batch[i];
        if (g != gcur) {
            if (gcur >= 0) atomicAdd(&pool[gcur * C + c], acc);
            acc = 0.f; gcur = g;
        }
        acc += X[(size_t)i * C + c];
    }
    if (gcur >= 0) atomicAdd(&pool[gcur * C + c], acc);
}

// ================= final prediction head =================
__global__ void k_head(const float* __restrict__ pool0, const float* __restrict__ poolL,
                       const float* __restrict__ p0w, const float* __restrict__ p0b,
                       const float* __restrict__ pLw, const float* __restrict__ pLb,
                       const float* __restrict__ ow, const float* __restrict__ ob,
                       float* __restrict__ outputs) {
    int g = blockIdx.x;
    int m = threadIdx.x;
    __shared__ float sh[MIDD];
    if (m < MIDD) {
        float s = p0b[m] + pLb[m];
        for (int k = 0; k < F_INN; k++) s += pool0[g * F_INN + k] * p0w[k * MIDD + m];
        for (int k = 0; k < HID; k++)  s += poolL[g * HID + k] * pLw[k * MIDD + m];
        sh[m] = fmaxf(s, 0.f);
    }
    __syncthreads();
    if (m == 0) {
        float s = ob[0];
        for (int k = 0; k < MIDD; k++) s += sh[k] * ow[k];
        outputs[g] = s;
    }
}

extern "C" void kernel_launch(void* const* d_in, const int* in_sizes, int n_in,
                              void* d_out, int out_size, void* d_ws, size_t ws_size,
                              hipStream_t stream) {
    // ---- inputs ----
    const float* x      = (const float*)d_in[0];
    const int*   ei     = (const int*)d_in[1];
    const int*   aei    = (const int*)d_in[2];
    const int*   batch  = (const int*)d_in[3];
    const float* g0_w1  = (const float*)d_in[4];
    const float* g0_b1  = (const float*)d_in[5];
    const float* g0_bng = (const float*)d_in[6];
    const float* g0_bnb = (const float*)d_in[7];
    const float* g0_w2  = (const float*)d_in[8];
    const float* g0_b2  = (const float*)d_in[9];
    const float* g1_w1  = (const float*)d_in[10];
    const float* g1_b1  = (const float*)d_in[11];
    const float* g1_bng = (const float*)d_in[12];
    const float* g1_bnb = (const float*)d_in[13];
    const float* g1_w2  = (const float*)d_in[14];
    const float* g1_b2  = (const float*)d_in[15];
    const float* bn0_g  = (const float*)d_in[16];
    const float* bn0_b  = (const float*)d_in[17];
    const float* bn1_g  = (const float*)d_in[18];
    const float* bn1_b  = (const float*)d_in[19];
    const float* a1_wl  = (const float*)d_in[20];
    const float* a1_bl  = (const float*)d_in[21];
    const float* a1_wr  = (const float*)d_in[22];
    const float* a1_br  = (const float*)d_in[23];
    const float* a1_att = (const float*)d_in[24];
    const float* a1_bias= (const float*)d_in[25];
    const float* a2_wl  = (const float*)d_in[26];
    const float* a2_bl  = (const float*)d_in[27];
    const float* a2_wr  = (const float*)d_in[28];
    const float* a2_br  = (const float*)d_in[29];
    const float* a2_att = (const float*)d_in[30];
    const float* a2_bias= (const float*)d_in[31];
    const float* p0w    = (const float*)d_in[32];
    const float* p0b    = (const float*)d_in[33];
    const float* pLw    = (const float*)d_in[34];
    const float* pLb    = (const float*)d_in[35];
    const float* ow     = (const float*)d_in[36];
    const float* ob     = (const float*)d_in[37];

    // ---- outputs ----
    float* out_head  = (float*)d_out;
    float* atten_out = out_head + G_GR;
    float* alpha_out = atten_out + (size_t)N_NODES * HID;

    // ---- workspace ----
    float* ws = (float*)d_ws;
    float* sums4 = ws;                                 // 4*256
    float* pool0 = sums4 + 4 * 256;                    // G*64
    float* poolL = pool0 + G_GR * F_INN;               // G*128
    int*   deg3  = (int*)(poolL + G_GR * HID);         // 3*N
    const size_t zero_bytes = (4 * 256 + G_GR * F_INN + G_GR * HID + 3 * N_NODES) * 4;

    int* ip = deg3 + 3 * N_NODES;
    int* cursor3 = ip; ip += 3 * N_NODES;
    int* rowptr[3]; int* eids[3]; int* srcs[3];
    for (int c = 0; c < 3; c++) {
        rowptr[c] = ip; ip += N_NODES + 1;
        eids[c]   = ip; ip += E_EDGES;
        srcs[c]   = ip; ip += E_EDGES;
    }
    const size_t NB = (size_t)N_NODES * HC;
    unsigned short* BFa = (unsigned short*)ip;         // [N,HC] bf16
    unsigned short* BFb = BFa + NB;
    unsigned short* BFc = BFb + NB;
    unsigned short* BFh1 = BFc + NB;                   // [N,HID] bf16
    unsigned short* g0w1t = BFh1 + (size_t)N_NODES * HID;
    unsigned short* g0w2t = g0w1t + 128 * 64;
    unsigned short* g1w1t = g0w2t + 128 * 128;
    unsigned short* g1w2t = g1w1t + 128 * 128;
    unsigned short* a1wlt = g1w2t + 128 * 128;
    unsigned short* a1wrt = a1wlt + 256 * 128;
    unsigned short* a2wlt = a1wrt + 256 * 128;
    unsigned short* a2wrt = a2wlt + 256 * 256;

    const int* e_row = ei;
    const int* e_col = ei + E_EDGES;
    const int* a_src = aei;
    const int* a_dst = aei + E_EDGES;

    const int TB = 256;
#define GRID1(n) dim3(CDIV((n), TB))

    // ===== weight transpose+cast =====
    {
        WtJobs jobs;
        jobs.j[0] = {g0_w1, g0w1t, F_INN, HID};
        jobs.j[1] = {g0_w2, g0w2t, HID,   HID};
        jobs.j[2] = {g1_w1, g1w1t, HID,   HID};
        jobs.j[3] = {g1_w2, g1w2t, HID,   HID};
        jobs.j[4] = {a1_wl, a1wlt, HID,   HC};
        jobs.j[5] = {a1_wr, a1wrt, HID,   HC};
        jobs.j[6] = {a2_wl, a2wlt, HC,    HC};
        jobs.j[7] = {a2_wr, a2wrt, HC,    HC};
        k_wt_cast<<<dim3(32, 8), TB, 0, stream>>>(jobs);
    }

    // ===== zero sums/pools/deg in one shot; build 3 CSRs batched =====
    hipMemsetAsync(sums4, 0, zero_bytes, stream);
    {
        Csr3 c;
        c.key[0] = e_row; c.other[0] = e_col;   // GANConv: agg by row
        c.key[1] = e_col; c.other[1] = e_row;   // ATT1: dst = e_col
        c.key[2] = a_dst; c.other[2] = a_src;   // ATT2: dst = a_dst
        c.deg = deg3; c.cursor = cursor3;
        for (int i = 0; i < 3; i++) { c.rowptr[i] = rowptr[i]; c.eids[i] = eids[i]; c.srcs[i] = srcs[i]; }
        k_hist3<<<dim3(CDIV(E_EDGES, TB), 3), TB, 0, stream>>>(c);
        k_scan3<<<dim3(3), 1024, 0, stream>>>(c);
        k_scatter3<<<dim3(CDIV(E_EDGES, TB), 3), TB, 0, stream>>>(c);
    }

    const dim3 gemm_g1(1, CDIV(N_NODES, 64));    // N=128, TM=64 tiles (313 blocks)
    const dim3 gemm_g2(2, CDIV(N_NODES, 128));   // N=256, TM=128 tiles (314 blocks)

    // ===== GANConv 0 =====
    k_gather_f32<<<GRID1(N_NODES * 16), TB, 0, stream>>>((const float4*)x, rowptr[0], srcs[0], BFa);
    k_mfma_gemm<1, 64><<<gemm_g1, TB, 0, stream>>>(BFa, g0w1t, g0_b1, BFb, N_NODES, F_INN, HID, sums4 + 0);
    k_bn_apply_bf<<<GRID1(N_NODES * HID), TB, 0, stream>>>(BFb, BFa, N_NODES, sums4 + 0, g0_bng, g0_bnb);
    k_mfma_gemm<1, 64><<<gemm_g1, TB, 0, stream>>>(BFa, g0w2t, g0_b2, BFb, N_NODES, HID, HID, sums4 + 256);
    k_bn_apply_bf<<<GRID1(N_NODES * HID), TB, 0, stream>>>(BFb, BFh1, N_NODES, sums4 + 256, bn0_g, bn0_b);
    // h1 bf16 in BFh1

    // ===== GANConv 1 =====
    k_gather_bf<<<GRID1(N_NODES * 16), TB, 0, stream>>>((const u16x8*)BFh1, rowptr[0], srcs[0], (u16x8*)BFa);
    k_mfma_gemm<1, 64><<<gemm_g1, TB, 0, stream>>>(BFa, g1w1t, g1_b1, BFb, N_NODES, HID, HID, sums4 + 512);
    k_bn_apply_bf<<<GRID1(N_NODES * HID), TB, 0, stream>>>(BFb, BFa, N_NODES, sums4 + 512, g1_bng, g1_bnb);
    k_mfma_gemm<1, 64><<<gemm_g1, TB, 0, stream>>>(BFa, g1w2t, g1_b2, BFb, N_NODES, HID, HID, sums4 + 768);
    k_bn_apply_bf<<<GRID1(N_NODES * HID), TB, 0, stream>>>(BFb, BFa, N_NODES, sums4 + 768, bn1_g, bn1_b);
    // h2 bf16 in BFa [N,HID]

    // ===== ATTConv 1 (src=e_row, dst=e_col, concat=True) =====
    k_mfma_gemm<0, 128><<<gemm_g2, TB, 0, stream>>>(BFa, a1wlt, a1_bl, BFb, N_NODES, HID, HC, nullptr);
    k_mfma_gemm<0, 128><<<gemm_g2, TB, 0, stream>>>(BFa, a1wrt, a1_br, BFc, N_NODES, HID, HC, nullptr);
    k_att_fused<1, 0><<<dim3(N_NODES / 4), TB, 0, stream>>>(
        (const ushort4*)BFb, (const ushort4*)BFc, rowptr[1], srcs[1], eids[1],
        a1_att, a1_bias, (void*)BFa, nullptr);
    // emb bf16 in BFa [N,HC]

    // ===== ATTConv 2 (src=a_src, dst=a_dst, concat=False) =====
    k_mfma_gemm<0, 128><<<gemm_g2, TB, 0, stream>>>(BFa, a2wlt, a2_bl, BFb, N_NODES, HC, HC, nullptr);
    k_mfma_gemm<0, 128><<<gemm_g2, TB, 0, stream>>>(BFa, a2wrt, a2_br, BFc, N_NODES, HC, HC, nullptr);
    k_att_fused<0, 1><<<dim3(N_NODES / 4), TB, 0, stream>>>(
        (const ushort4*)BFb, (const ushort4*)BFc, rowptr[2], srcs[2], eids[2],
        a2_att, a2_bias, (void*)atten_out, alpha_out);

    // ===== pooling + head =====
    {
        const int npb = 64;  // 313 blocks
        k_pool_atomic<F_INN><<<dim3(CDIV(N_NODES, npb)), TB, 0, stream>>>(x, batch, pool0, npb);
        k_pool_atomic<HID><<<dim3(CDIV(N_NODES, npb)), TB, 0, stream>>>(atten_out, batch, poolL, npb);
    }
    k_head<<<dim3(G_GR), 64, 0, stream>>>(pool0, poolL, p0w, p0b, pLw, pLb, ow, ob, out_head);
}

// Round 9
// 564.216 us; speedup vs baseline: 6.5275x; 1.0266x over previous
//
#include <hip/hip_runtime.h>
#include <hip/hip_bf16.h>

#define N_NODES 20000
#define E_EDGES 320000
#define F_INN   64
#define HID     128
#define HEADS   2
#define HC      (HEADS * HID)   // 256
#define G_GR    64
#define MIDD    32
#define EPSV    1e-5f

#define CDIV(a, b) (((a) + (b) - 1) / (b))

typedef __attribute__((ext_vector_type(8))) short          bf16x8;  // MFMA A/B frag
typedef __attribute__((ext_vector_type(4))) float          f32x4;   // MFMA C/D frag
typedef __attribute__((ext_vector_type(8))) unsigned short u16x8;

// ---------- bf16 helpers (RNE) ----------
__device__ inline float bf2f(unsigned short u) { return __uint_as_float((unsigned)u << 16); }
__device__ inline unsigned short f2bf(float f) {
    unsigned u = __float_as_uint(f);
    unsigned r = u + 0x7FFFu + ((u >> 16) & 1u);
    return (unsigned short)(r >> 16);
}

// ================= CSR construction (3 CSRs batched, 1 payload stream each) ========
// CSR0 (GAN, key=e_row): payload = e_col[e] (src)
// CSR1 (ATT1, key=e_col): payload = e_row[e] (src)
// CSR2 (ATT2, key=a_dst): payload = e (edge id; src derived via a_src[e])
struct Csr3 {
    const int* key[3];
    const int* other[3];   // payload source for y=0,1; unused for y=2
    int* deg;       // [3*N]
    int* cursor;    // [3*N]
    int* rowptr[3]; // [N+1]
    int* out[3];    // [E] payload
};

__global__ void k_hist3(Csr3 c) {
    int e = blockIdx.x * blockDim.x + threadIdx.x;
    int y = blockIdx.y;
    if (e < E_EDGES) atomicAdd(&c.deg[y * N_NODES + c.key[y][e]], 1);
}

__global__ __launch_bounds__(1024) void k_scan3(Csr3 c) {
    const int PER = (N_NODES + 1023) / 1024;  // 20
    __shared__ int part[1024];
    const int y = blockIdx.x;
    const int* deg = c.deg + y * N_NODES;
    int* cursor = c.cursor + y * N_NODES;
    int* rowptr = c.rowptr[y];
    const int tid = threadIdx.x;
    const int base = tid * PER;
    int lv[PER];
    int lsum = 0;
#pragma unroll
    for (int i = 0; i < PER; i++) {
        int idx = base + i;
        int v = (idx < N_NODES) ? deg[idx] : 0;
        lv[i] = v; lsum += v;
    }
    part[tid] = lsum;
    __syncthreads();
    for (int off = 1; off < 1024; off <<= 1) {
        int t = (tid >= off) ? part[tid - off] : 0;
        __syncthreads();
        part[tid] += t;
        __syncthreads();
    }
    int run = part[tid] - lsum;
    if (tid == 0) rowptr[0] = 0;
#pragma unroll
    for (int i = 0; i < PER; i++) {
        int idx = base + i;
        if (idx < N_NODES) {
            cursor[idx] = run;
            run += lv[i];
            rowptr[idx + 1] = run;
        }
    }
}

__global__ void k_scatter3(Csr3 c) {
    int e = blockIdx.x * blockDim.x + threadIdx.x;
    int y = blockIdx.y;
    if (e >= E_EDGES) return;
    int k = c.key[y][e];
    int pos = atomicAdd(&c.cursor[y * N_NODES + k], 1);
    c.out[y][pos] = (y == 2) ? e : c.other[y][e];
}

// ===== GANConv0 aggregation: z[n] = bf16(x[n] + sum x[srcs]) , fp32 input =====
__global__ __launch_bounds__(256) void k_gather_f32(const float4* __restrict__ x,
                                                    const int* __restrict__ rowptr,
                                                    const int* __restrict__ srcs,
                                                    unsigned short* __restrict__ z) {
    int gid = blockIdx.x * blockDim.x + threadIdx.x;
    int n = gid >> 4;
    if (n >= N_NODES) return;
    int q = gid & 15;
    float4 acc = x[((size_t)n << 4) + q];
    int p1 = rowptr[n + 1];
    for (int p = rowptr[n]; p < p1; p++) {
        float4 v = x[((size_t)srcs[p] << 4) + q];
        acc.x += v.x; acc.y += v.y; acc.z += v.z; acc.w += v.w;
    }
    ushort4 o;
    o.x = f2bf(acc.x); o.y = f2bf(acc.y); o.z = f2bf(acc.z); o.w = f2bf(acc.w);
    *(ushort4*)&z[((size_t)n << 6) + (q << 2)] = o;
}

// ===== GANConv1 aggregation with fused BN+relu on load:
// h1 = relu(bn(raw)); z[n] = bf16(h1[n] + sum h1[srcs]) =====
__global__ __launch_bounds__(256) void k_gather_bn(const u16x8* __restrict__ raw,
                                                   const int* __restrict__ rowptr,
                                                   const int* __restrict__ srcs,
                                                   const float* __restrict__ bn_sums,
                                                   const float* __restrict__ g,
                                                   const float* __restrict__ b,
                                                   u16x8* __restrict__ z) {
    int gid = blockIdx.x * blockDim.x + threadIdx.x;
    int n = gid >> 4;
    if (n >= N_NODES) return;
    int q = gid & 15;
    // per-thread channel BN params (channels q*8..q*8+7)
    float sc[8], sh[8];
#pragma unroll
    for (int i = 0; i < 8; i++) {
        int c = (q << 3) + i;
        float mean = bn_sums[c] / N_NODES;
        float istd = rsqrtf(bn_sums[HID + c] / N_NODES - mean * mean + EPSV);
        float s = istd * g[c];
        sc[i] = s;
        sh[i] = b[c] - mean * s;
    }
    u16x8 u0 = raw[((size_t)n << 4) + q];
    float acc[8];
#pragma unroll
    for (int i = 0; i < 8; i++) acc[i] = fmaxf(bf2f(u0[i]) * sc[i] + sh[i], 0.f);
    int p1 = rowptr[n + 1];
    for (int p = rowptr[n]; p < p1; p++) {
        u16x8 v = raw[((size_t)srcs[p] << 4) + q];
#pragma unroll
        for (int i = 0; i < 8; i++) acc[i] += fmaxf(bf2f(v[i]) * sc[i] + sh[i], 0.f);
    }
    u16x8 o;
#pragma unroll
    for (int i = 0; i < 8; i++) o[i] = f2bf(acc[i]);
    z[((size_t)n << 4) + q] = o;
}

// ===== weight prep: Wt[n][k] = bf16(W[k][n]) for 8 weights in one launch =====
struct WtJob  { const float* src; unsigned short* dst; int K; int N; };
struct WtJobs { WtJob j[8]; };
__global__ void k_wt_cast(WtJobs jobs) {
    WtJob jb = jobs.j[blockIdx.y];
    int total = jb.K * jb.N;
    for (int i = blockIdx.x * blockDim.x + threadIdx.x; i < total; i += gridDim.x * blockDim.x) {
        int nn = i / jb.K, kk = i - nn * jb.K;
        jb.dst[i] = f2bf(jb.src[(size_t)kk * jb.N + nn]);
    }
}

// ===== MFMA bf16 GEMM: C[M,N] = A'[M,K] @ Wt[N,K]^T + bias; bf16 out =====
// A' = BNA ? relu(bn(A)) : A   (BN params from bn_sums/g/b, K==HID when BNA)
// STATS: per-column sum/sumsq of output (incl bias) via atomics (for next BN).
template <int STATS, int BNA, int TM>
__global__ __launch_bounds__(256) void k_mfma_gemm(const unsigned short* __restrict__ A,
                                                   const unsigned short* __restrict__ Wt,
                                                   const float* __restrict__ bias,
                                                   unsigned short* __restrict__ Cout,
                                                   int M, int K, int N,
                                                   float* __restrict__ stats_sums,
                                                   const float* __restrict__ bn_sums,
                                                   const float* __restrict__ bn_g,
                                                   const float* __restrict__ bn_b) {
    constexpr int BNF = (TM == 128) ? 4 : 2;      // n-frags per wave
    __shared__ unsigned short As[TM][40];
    __shared__ unsigned short Bs[128][40];
    __shared__ float s_scale[BNA ? HID : 1], s_shift[BNA ? HID : 1];
    const int t = threadIdx.x;
    if (BNA) {
        if (t < HID) {
            float mean = bn_sums[t] / M;
            float istd = rsqrtf(bn_sums[HID + t] / M - mean * mean + EPSV);
            float s = istd * bn_g[t];
            s_scale[t] = s;
            s_shift[t] = bn_b[t] - mean * s;
        }
        __syncthreads();
    }
    const int wave = t >> 6, lane = t & 63;
    const int row0 = blockIdx.y * TM, col0 = blockIdx.x * 128;
    const int wm = (TM == 128) ? ((wave & 1) << 6) : 0;
    const int wn = (TM == 128) ? ((wave >> 1) << 6) : (wave << 5);
    const int lm = lane & 15, lk = (lane >> 4) << 3;
    constexpr int APASS = TM / 64;
    f32x4 acc[4][BNF] = {};
    for (int k0 = 0; k0 < K; k0 += 32) {
        u16x8 av[APASS], wv[2];
#pragma unroll
        for (int i = 0; i < APASS; i++) {
            int c = t + (i << 8);
            int r = c >> 2, ko = (c & 3) << 3;
            u16x8 zv = {};
            int gr = row0 + r;
            av[i] = (gr < M) ? *(const u16x8*)&A[(size_t)gr * K + k0 + ko] : zv;
            if (BNA) {
#pragma unroll
                for (int j = 0; j < 8; j++) {
                    int kc = k0 + ko + j;
                    float v = fmaxf(bf2f(av[i][j]) * s_scale[kc] + s_shift[kc], 0.f);
                    av[i][j] = f2bf(v);
                }
            }
        }
#pragma unroll
        for (int i = 0; i < 2; i++) {
            int c = t + (i << 8);
            int r = c >> 2, ko = (c & 3) << 3;
            wv[i] = *(const u16x8*)&Wt[(size_t)(col0 + r) * K + k0 + ko];
        }
        __syncthreads();
#pragma unroll
        for (int i = 0; i < APASS; i++) {
            int c = t + (i << 8);
            int r = c >> 2, ko = (c & 3) << 3;
            *(u16x8*)&As[r][ko] = av[i];
        }
#pragma unroll
        for (int i = 0; i < 2; i++) {
            int c = t + (i << 8);
            int r = c >> 2, ko = (c & 3) << 3;
            *(u16x8*)&Bs[r][ko] = wv[i];
        }
        __syncthreads();
        bf16x8 af[4], bfm[BNF];
#pragma unroll
        for (int i = 0; i < 4; i++) af[i]  = *(const bf16x8*)&As[wm + (i << 4) + lm][lk];
#pragma unroll
        for (int j = 0; j < BNF; j++) bfm[j] = *(const bf16x8*)&Bs[wn + (j << 4) + lm][lk];
#pragma unroll
        for (int i = 0; i < 4; i++)
#pragma unroll
            for (int j = 0; j < BNF; j++)
                acc[i][j] = __builtin_amdgcn_mfma_f32_16x16x32_bf16(af[i], bfm[j], acc[i][j], 0, 0, 0);
    }
    const int lr4 = (lane >> 4) << 2;
    float s1[BNF], s2[BNF];
#pragma unroll
    for (int j = 0; j < BNF; j++) { s1[j] = 0.f; s2[j] = 0.f; }
#pragma unroll
    for (int j = 0; j < BNF; j++) {
        int col = col0 + wn + (j << 4) + lm;
        float bv = bias[col];
#pragma unroll
        for (int i = 0; i < 4; i++) {
#pragma unroll
            for (int r = 0; r < 4; r++) {
                int row = row0 + wm + (i << 4) + lr4 + r;
                if (row < M) {
                    float v = acc[i][j][r] + bv;
                    Cout[(size_t)row * N + col] = f2bf(v);
                    if (STATS) { s1[j] += v; s2[j] += v * v; }
                }
            }
        }
    }
    if (STATS) {
#pragma unroll
        for (int j = 0; j < BNF; j++) {
            s1[j] += __shfl_xor(s1[j], 16, 64); s1[j] += __shfl_xor(s1[j], 32, 64);
            s2[j] += __shfl_xor(s2[j], 16, 64); s2[j] += __shfl_xor(s2[j], 32, 64);
        }
        if ((lane >> 4) == 0) {
#pragma unroll
            for (int j = 0; j < BNF; j++) {
                int col = col0 + wn + (j << 4) + lm;   // < 128 for stats GEMMs
                atomicAdd(&stats_sums[col], s1[j]);
                atomicAdd(&stats_sums[HID + col], s2[j]);
            }
        }
    }
}

// ========== fused ATTConv (GATv2): single-pass flash-style online softmax ==========
// One wave per node; lane l -> channels 4l..4l+3, head h = l>>5.
// WITH_ALPHA also means INDIRECT: plist holds edge ids, src = other[e].
#define ATT_CAP 192
template <int CONCAT, int WITH_ALPHA>
__global__ __launch_bounds__(256) void k_att_fused(const ushort4* __restrict__ xl,
                                                   const ushort4* __restrict__ xr,
                                                   const int* __restrict__ rowptr,
                                                   const int* __restrict__ plist,
                                                   const int* __restrict__ other,
                                                   const float* __restrict__ att,
                                                   const float* __restrict__ bias,
                                                   void* __restrict__ outp,
                                                   float* __restrict__ alpha_out) {
    __shared__ float s_lg[4][ATT_CAP][2];
    const int t = threadIdx.x;
    const int wave = t >> 6, l = t & 63;
    const int n = blockIdx.x * 4 + wave;   // N_NODES % 4 == 0
    const int h = l >> 5;
    ushort4 ur = xr[((size_t)n << 6) + l];
    float xr4[4] = {bf2f(ur.x), bf2f(ur.y), bf2f(ur.z), bf2f(ur.w)};
    const float* ap = &att[h * HID + ((l & 31) << 2)];
    float at4[4] = {ap[0], ap[1], ap[2], ap[3]};
    const int p0 = rowptr[n], p1 = rowptr[n + 1];

    float m = -INFINITY, ssum = 0.f;
    float acc[4] = {0.f, 0.f, 0.f, 0.f};

#define ATT_SRC(p) (WITH_ALPHA ? other[plist[p]] : plist[p])

#define ATT_LOGIT(uv, x4, tl) do { \
        x4[0] = bf2f(uv.x); x4[1] = bf2f(uv.y); x4[2] = bf2f(uv.z); x4[3] = bf2f(uv.w); \
        float v0 = x4[0] + xr4[0]; v0 = (v0 > 0.f) ? v0 : 0.2f * v0; \
        float v1 = x4[1] + xr4[1]; v1 = (v1 > 0.f) ? v1 : 0.2f * v1; \
        float v2 = x4[2] + xr4[2]; v2 = (v2 > 0.f) ? v2 : 0.2f * v2; \
        float v3 = x4[3] + xr4[3]; v3 = (v3 > 0.f) ? v3 : 0.2f * v3; \
        tl = at4[0] * v0 + at4[1] * v1 + at4[2] * v2 + at4[3] * v3; \
    } while (0)

#define ATT_ONLINE(x4, tl, idx) do { \
        float mn = fmaxf(m, tl); \
        float sc = __expf(m - mn); \
        float w  = __expf(tl - mn); \
        ssum = ssum * sc + w; \
        acc[0] = acc[0] * sc + w * x4[0]; \
        acc[1] = acc[1] * sc + w * x4[1]; \
        acc[2] = acc[2] * sc + w * x4[2]; \
        acc[3] = acc[3] * sc + w * x4[3]; \
        m = mn; \
        if (WITH_ALPHA && (idx) < ATT_CAP && (l & 31) == 0) s_lg[wave][idx][h] = tl; \
    } while (0)

    int p = p0;
    for (; p + 4 <= p1; p += 4) {
        float x4[4][4], tl[4];
        ushort4 uv[4];
        int ss[4];
#pragma unroll
        for (int j = 0; j < 4; j++) ss[j] = ATT_SRC(p + j);
#pragma unroll
        for (int j = 0; j < 4; j++) uv[j] = xl[((size_t)ss[j] << 6) + l];
#pragma unroll
        for (int j = 0; j < 4; j++) ATT_LOGIT(uv[j], x4[j], tl[j]);
#pragma unroll
        for (int k = 1; k <= 16; k <<= 1) {
#pragma unroll
            for (int j = 0; j < 4; j++) tl[j] += __shfl_xor(tl[j], k, 64);
        }
#pragma unroll
        for (int j = 0; j < 4; j++) ATT_ONLINE(x4[j], tl[j], p + j - p0);
    }
    for (; p < p1; p++) {
        float x4[4], tl;
        ushort4 uv = xl[((size_t)ATT_SRC(p) << 6) + l];
        ATT_LOGIT(uv, x4, tl);
#pragma unroll
        for (int k = 1; k <= 16; k <<= 1) tl += __shfl_xor(tl, k, 64);
        ATT_ONLINE(x4, tl, p - p0);
    }
    float inv = 1.f / (ssum + 1e-16f);

    // ---- alpha output (att2): parallel from LDS cache ----
    if (WITH_ALPHA) {
        float m_o   = __shfl_xor(m, 32, 64);
        float inv_o = __shfl_xor(inv, 32, 64);
        float m2[2], i2[2];
        m2[h] = m; m2[1 - h] = m_o;
        i2[h] = inv; i2[1 - h] = inv_o;
        int cnt = p1 - p0;
        int ccnt = (cnt < ATT_CAP) ? cnt : ATT_CAP;
        for (int i = l; i < ccnt * 2; i += 64) {
            int idx = i >> 1, hh = i & 1;
            float a = __expf(s_lg[wave][idx][hh] - m2[hh]) * i2[hh];
            alpha_out[plist[p0 + idx] * HEADS + hh] = a;
        }
        // overflow fallback (deg > ATT_CAP): serial recompute (practically never taken)
        for (int pp = p0 + ATT_CAP; pp < p1; pp++) {
            float x4[4], tl;
            ushort4 uv = xl[((size_t)ATT_SRC(pp) << 6) + l];
            ATT_LOGIT(uv, x4, tl);
#pragma unroll
            for (int k = 1; k <= 16; k <<= 1) tl += __shfl_xor(tl, k, 64);
            if ((l & 31) == 0) alpha_out[plist[pp] * HEADS + h] = __expf(tl - m) * inv;
        }
    }

    // ---- epilogue ----
    if (CONCAT) {
        const float* bp = &bias[l << 2];
        ushort4 o;
        o.x = f2bf(fmaxf(acc[0] * inv + bp[0], 0.f));
        o.y = f2bf(fmaxf(acc[1] * inv + bp[1], 0.f));
        o.z = f2bf(fmaxf(acc[2] * inv + bp[2], 0.f));
        o.w = f2bf(fmaxf(acc[3] * inv + bp[3], 0.f));
        ((ushort4*)outp)[((size_t)n << 6) + l] = o;
    } else {
        float o[4];
#pragma unroll
        for (int i = 0; i < 4; i++) {
            float v = acc[i] * inv;
            float other_v = __shfl_xor(v, 32, 64);
            o[i] = 0.5f * (v + other_v);
        }
        if (l < 32) {
            const float* bp = &bias[(l & 31) << 2];
            float4 ov;
            ov.x = fmaxf(o[0] + bp[0], 0.f); ov.y = fmaxf(o[1] + bp[1], 0.f);
            ov.z = fmaxf(o[2] + bp[2], 0.f); ov.w = fmaxf(o[3] + bp[3], 0.f);
            ((float4*)outp)[((size_t)n << 5) + l] = ov;
        }
    }
#undef ATT_SRC
#undef ATT_LOGIT
#undef ATT_ONLINE
}

// ================= pooling over sorted batch_index (node-parallel) =================
template <int C>
__global__ __launch_bounds__(256) void k_pool_atomic(const float* __restrict__ X,
                                                     const int* __restrict__ batch,
                                                     float* __restrict__ pool, int npb) {
    const int RP = 256 / C;
    int c = threadIdx.x & (C - 1);
    int rofs = threadIdx.x / C;
    int i0 = blockIdx.x * npb;
    int i1 = min(i0 + npb, N_NODES);
    float acc = 0.f;
    int gcur = -1;
    for (int i = i0 + rofs; i < i1; i += RP) {
        int g = batch[i];
        if (g != gcur) {
            if (gcur >= 0) atomicAdd(&pool[gcur * C + c], acc);
            acc = 0.f; gcur = g;
        }
        acc += X[(size_t)i * C + c];
    }
    if (gcur >= 0) atomicAdd(&pool[gcur * C + c], acc);
}

// ================= final prediction head =================
__global__ void k_head(const float* __restrict__ pool0, const float* __restrict__ poolL,
                       const float* __restrict__ p0w, const float* __restrict__ p0b,
                       const float* __restrict__ pLw, const float* __restrict__ pLb,
                       const float* __restrict__ ow, const float* __restrict__ ob,
                       float* __restrict__ outputs) {
    int g = blockIdx.x;
    int m = threadIdx.x;
    __shared__ float sh[MIDD];
    if (m < MIDD) {
        float s = p0b[m] + pLb[m];
        for (int k = 0; k < F_INN; k++) s += pool0[g * F_INN + k] * p0w[k * MIDD + m];
        for (int k = 0; k < HID; k++)  s += poolL[g * HID + k] * pLw[k * MIDD + m];
        sh[m] = fmaxf(s, 0.f);
    }
    __syncthreads();
    if (m == 0) {
        float s = ob[0];
        for (int k = 0; k < MIDD; k++) s += sh[k] * ow[k];
        outputs[g] = s;
    }
}

extern "C" void kernel_launch(void* const* d_in, const int* in_sizes, int n_in,
                              void* d_out, int out_size, void* d_ws, size_t ws_size,
                              hipStream_t stream) {
    // ---- inputs ----
    const float* x      = (const float*)d_in[0];
    const int*   ei     = (const int*)d_in[1];
    const int*   aei    = (const int*)d_in[2];
    const int*   batch  = (const int*)d_in[3];
    const float* g0_w1  = (const float*)d_in[4];
    const float* g0_b1  = (const float*)d_in[5];
    const float* g0_bng = (const float*)d_in[6];
    const float* g0_bnb = (const float*)d_in[7];
    const float* g0_w2  = (const float*)d_in[8];
    const float* g0_b2  = (const float*)d_in[9];
    const float* g1_w1  = (const float*)d_in[10];
    const float* g1_b1  = (const float*)d_in[11];
    const float* g1_bng = (const float*)d_in[12];
    const float* g1_bnb = (const float*)d_in[13];
    const float* g1_w2  = (const float*)d_in[14];
    const float* g1_b2  = (const float*)d_in[15];
    const float* bn0_g  = (const float*)d_in[16];
    const float* bn0_b  = (const float*)d_in[17];
    const float* bn1_g  = (const float*)d_in[18];
    const float* bn1_b  = (const float*)d_in[19];
    const float* a1_wl  = (const float*)d_in[20];
    const float* a1_bl  = (const float*)d_in[21];
    const float* a1_wr  = (const float*)d_in[22];
    const float* a1_br  = (const float*)d_in[23];
    const float* a1_att = (const float*)d_in[24];
    const float* a1_bias= (const float*)d_in[25];
    const float* a2_wl  = (const float*)d_in[26];
    const float* a2_bl  = (const float*)d_in[27];
    const float* a2_wr  = (const float*)d_in[28];
    const float* a2_br  = (const float*)d_in[29];
    const float* a2_att = (const float*)d_in[30];
    const float* a2_bias= (const float*)d_in[31];
    const float* p0w    = (const float*)d_in[32];
    const float* p0b    = (const float*)d_in[33];
    const float* pLw    = (const float*)d_in[34];
    const float* pLb    = (const float*)d_in[35];
    const float* ow     = (const float*)d_in[36];
    const float* ob     = (const float*)d_in[37];

    // ---- outputs ----
    float* out_head  = (float*)d_out;
    float* atten_out = out_head + G_GR;
    float* alpha_out = atten_out + (size_t)N_NODES * HID;

    // ---- workspace ----
    float* ws = (float*)d_ws;
    float* sums4 = ws;                                 // 4*256 (s0|s1|s2|s3)
    float* pool0 = sums4 + 4 * 256;                    // G*64
    float* poolL = pool0 + G_GR * F_INN;               // G*128
    int*   deg3  = (int*)(poolL + G_GR * HID);         // 3*N
    const size_t zero_bytes = (4 * 256 + G_GR * F_INN + G_GR * HID + 3 * N_NODES) * 4;

    int* ip = deg3 + 3 * N_NODES;
    int* cursor3 = ip; ip += 3 * N_NODES;
    int* rowptr[3]; int* payload[3];
    for (int c = 0; c < 3; c++) {
        rowptr[c]  = ip; ip += N_NODES + 1;
        payload[c] = ip; ip += E_EDGES;
    }
    const size_t NB = (size_t)N_NODES * HC;
    unsigned short* BFa = (unsigned short*)ip;         // [N,HC] bf16
    unsigned short* BFb = BFa + NB;
    unsigned short* BFc = BFb + NB;
    unsigned short* g0w1t = BFc + NB;
    unsigned short* g0w2t = g0w1t + 128 * 64;
    unsigned short* g1w1t = g0w2t + 128 * 128;
    unsigned short* g1w2t = g1w1t + 128 * 128;
    unsigned short* a1wlt = g1w2t + 128 * 128;
    unsigned short* a1wrt = a1wlt + 256 * 128;
    unsigned short* a2wlt = a1wrt + 256 * 128;
    unsigned short* a2wrt = a2wlt + 256 * 256;

    const int* e_row = ei;
    const int* e_col = ei + E_EDGES;
    const int* a_src = aei;
    const int* a_dst = aei + E_EDGES;

    const int TB = 256;
#define GRID1(n) dim3(CDIV((n), TB))

    // ===== weight transpose+cast =====
    {
        WtJobs jobs;
        jobs.j[0] = {g0_w1, g0w1t, F_INN, HID};
        jobs.j[1] = {g0_w2, g0w2t, HID,   HID};
        jobs.j[2] = {g1_w1, g1w1t, HID,   HID};
        jobs.j[3] = {g1_w2, g1w2t, HID,   HID};
        jobs.j[4] = {a1_wl, a1wlt, HID,   HC};
        jobs.j[5] = {a1_wr, a1wrt, HID,   HC};
        jobs.j[6] = {a2_wl, a2wlt, HC,    HC};
        jobs.j[7] = {a2_wr, a2wrt, HC,    HC};
        k_wt_cast<<<dim3(32, 8), TB, 0, stream>>>(jobs);
    }

    // ===== zero sums/pools/deg in one shot; build 3 CSRs batched =====
    hipMemsetAsync(sums4, 0, zero_bytes, stream);
    {
        Csr3 c;
        c.key[0] = e_row; c.other[0] = e_col;   // GANConv: group by dst=e_row, payload src
        c.key[1] = e_col; c.other[1] = e_row;   // ATT1: group by dst=e_col, payload src
        c.key[2] = a_dst; c.other[2] = a_src;   // ATT2: group by dst, payload edge id
        c.deg = deg3; c.cursor = cursor3;
        for (int i = 0; i < 3; i++) { c.rowptr[i] = rowptr[i]; c.out[i] = payload[i]; }
        k_hist3<<<dim3(CDIV(E_EDGES, TB), 3), TB, 0, stream>>>(c);
        k_scan3<<<dim3(3), 1024, 0, stream>>>(c);
        k_scatter3<<<dim3(CDIV(E_EDGES, TB), 3), TB, 0, stream>>>(c);
    }

    const dim3 gemm_g1(1, CDIV(N_NODES, 64));    // N=128, TM=64 (313 blocks)
    const dim3 gemm_g2(2, CDIV(N_NODES, 128));   // N=256, TM=128 (314 blocks)
    const float* NOF = nullptr;

    // ===== GANConv 0: z->BFa, raw1->BFb, raw2->BFc =====
    k_gather_f32<<<GRID1(N_NODES * 16), TB, 0, stream>>>((const float4*)x, rowptr[0], payload[0], BFa);
    k_mfma_gemm<1, 0, 64><<<gemm_g1, TB, 0, stream>>>(BFa, g0w1t, g0_b1, BFb, N_NODES, F_INN, HID,
                                                      sums4 + 0, NOF, NOF, NOF);
    k_mfma_gemm<1, 1, 64><<<gemm_g1, TB, 0, stream>>>(BFb, g0w2t, g0_b2, BFc, N_NODES, HID, HID,
                                                      sums4 + 256, sums4 + 0, g0_bng, g0_bnb);
    // raw2 (pre-bn0) in BFc

    // ===== GANConv 1: z2->BFa, raw3->BFb, raw4->BFc... reuse =====
    k_gather_bn<<<GRID1(N_NODES * 16), TB, 0, stream>>>((const u16x8*)BFc, rowptr[0], payload[0],
                                                        sums4 + 256, bn0_g, bn0_b, (u16x8*)BFa);
    k_mfma_gemm<1, 0, 64><<<gemm_g1, TB, 0, stream>>>(BFa, g1w1t, g1_b1, BFb, N_NODES, HID, HID,
                                                      sums4 + 512, NOF, NOF, NOF);
    k_mfma_gemm<1, 1, 64><<<gemm_g1, TB, 0, stream>>>(BFb, g1w2t, g1_b2, BFc, N_NODES, HID, HID,
                                                      sums4 + 768, sums4 + 512, g1_bng, g1_bnb);
    // raw4 (pre-bn1 = h2 raw) in BFc

    // ===== ATTConv 1 (dst=e_col, concat=True): xl->BFb, xr->BFa, emb->BFc after =====
    k_mfma_gemm<0, 1, 128><<<gemm_g2, TB, 0, stream>>>(BFc, a1wlt, a1_bl, BFb, N_NODES, HID, HC,
                                                       nullptr, sums4 + 768, bn1_g, bn1_b);
    k_mfma_gemm<0, 1, 128><<<gemm_g2, TB, 0, stream>>>(BFc, a1wrt, a1_br, BFa, N_NODES, HID, HC,
                                                       nullptr, sums4 + 768, bn1_g, bn1_b);
    k_att_fused<1, 0><<<dim3(N_NODES / 4), TB, 0, stream>>>(
        (const ushort4*)BFb, (const ushort4*)BFa, rowptr[1], payload[1], nullptr,
        a1_att, a1_bias, (void*)BFc, nullptr);
    // emb bf16 in BFc [N,HC]

    // ===== ATTConv 2 (dst=a_dst, concat=False): xl->BFb, xr->BFa =====
    k_mfma_gemm<0, 0, 128><<<gemm_g2, TB, 0, stream>>>(BFc, a2wlt, a2_bl, BFb, N_NODES, HC, HC,
                                                       nullptr, NOF, NOF, NOF);
    k_mfma_gemm<0, 0, 128><<<gemm_g2, TB, 0, stream>>>(BFc, a2wrt, a2_br, BFa, N_NODES, HC, HC,
                                                       nullptr, NOF, NOF, NOF);
    k_att_fused<0, 1><<<dim3(N_NODES / 4), TB, 0, stream>>>(
        (const ushort4*)BFb, (const ushort4*)BFa, rowptr[2], payload[2], a_src,
        a2_att, a2_bias, (void*)atten_out, alpha_out);

    // ===== pooling + head =====
    {
        const int npb = 64;  // 313 blocks
        k_pool_atomic<F_INN><<<dim3(CDIV(N_NODES, npb)), TB, 0, stream>>>(x, batch, pool0, npb);
        k_pool_atomic<HID><<<dim3(CDIV(N_NODES, npb)), TB, 0, stream>>>(atten_out, batch, poolL, npb);
    }
    k_head<<<dim3(G_GR), 64, 0, stream>>>(pool0, poolL, p0w, p0b, pLw, pLb, ow, ob, out_head);
}

// Round 10
// 554.329 us; speedup vs baseline: 6.6439x; 1.0178x over previous
//
#include <hip/hip_runtime.h>
#include <hip/hip_bf16.h>

#define N_NODES 20000
#define E_EDGES 320000
#define F_INN   64
#define HID     128
#define HEADS   2
#define HC      (HEADS * HID)   // 256
#define G_GR    64
#define MIDD    32
#define EPSV    1e-5f

#define CDIV(a, b) (((a) + (b) - 1) / (b))

typedef __attribute__((ext_vector_type(8))) short          bf16x8;  // MFMA A/B frag
typedef __attribute__((ext_vector_type(4))) float          f32x4;   // MFMA C/D frag
typedef __attribute__((ext_vector_type(8))) unsigned short u16x8;

// ---------- bf16 helpers (RNE) ----------
__device__ inline float bf2f(unsigned short u) { return __uint_as_float((unsigned)u << 16); }
__device__ inline unsigned short f2bf(float f) {
    unsigned u = __float_as_uint(f);
    unsigned r = u + 0x7FFFu + ((u >> 16) & 1u);
    return (unsigned short)(r >> 16);
}

// ================= CSR construction (3 CSRs batched, 1 payload stream each) ========
// CSR0 (GAN, key=e_row): payload = e_col[e] (src)
// CSR1 (ATT1, key=e_col): payload = e_row[e] (src)
// CSR2 (ATT2, key=a_dst): payload = e (edge id; src derived via a_src[e])
struct Csr3 {
    const int* key[3];
    const int* other[3];   // payload source for y=0,1; unused for y=2
    int* deg;       // [3*N]
    int* cursor;    // [3*N]
    int* rowptr[3]; // [N+1]
    int* out[3];    // [E] payload
};

__global__ void k_hist3(Csr3 c) {
    int e = blockIdx.x * blockDim.x + threadIdx.x;
    int y = blockIdx.y;
    if (e < E_EDGES) atomicAdd(&c.deg[y * N_NODES + c.key[y][e]], 1);
}

__global__ __launch_bounds__(1024) void k_scan3(Csr3 c) {
    const int PER = (N_NODES + 1023) / 1024;  // 20
    __shared__ int part[1024];
    const int y = blockIdx.x;
    const int* deg = c.deg + y * N_NODES;
    int* cursor = c.cursor + y * N_NODES;
    int* rowptr = c.rowptr[y];
    const int tid = threadIdx.x;
    const int base = tid * PER;
    int lv[PER];
    int lsum = 0;
#pragma unroll
    for (int i = 0; i < PER; i++) {
        int idx = base + i;
        int v = (idx < N_NODES) ? deg[idx] : 0;
        lv[i] = v; lsum += v;
    }
    part[tid] = lsum;
    __syncthreads();
    for (int off = 1; off < 1024; off <<= 1) {
        int t = (tid >= off) ? part[tid - off] : 0;
        __syncthreads();
        part[tid] += t;
        __syncthreads();
    }
    int run = part[tid] - lsum;
    if (tid == 0) rowptr[0] = 0;
#pragma unroll
    for (int i = 0; i < PER; i++) {
        int idx = base + i;
        if (idx < N_NODES) {
            cursor[idx] = run;
            run += lv[i];
            rowptr[idx + 1] = run;
        }
    }
}

// payload written with atomicExch: device-scope atomics write through at ~16B
// (measured r2), avoiding the ~9x cross-XCD dirty-line writeback amplification
// that plain scattered 4B stores showed (r8->r9 WRITE_SIZE decomposition).
__global__ void k_scatter3(Csr3 c) {
    int e = blockIdx.x * blockDim.x + threadIdx.x;
    int y = blockIdx.y;
    if (e >= E_EDGES) return;
    int k = c.key[y][e];
    int pos = atomicAdd(&c.cursor[y * N_NODES + k], 1);
    int val = (y == 2) ? e : c.other[y][e];
    atomicExch(&c.out[y][pos], val);
}

// ===== GANConv0 aggregation: z[n] = bf16(x[n] + sum x[srcs]) , fp32 input =====
__global__ __launch_bounds__(256) void k_gather_f32(const float4* __restrict__ x,
                                                    const int* __restrict__ rowptr,
                                                    const int* __restrict__ srcs,
                                                    unsigned short* __restrict__ z) {
    int gid = blockIdx.x * blockDim.x + threadIdx.x;
    int n = gid >> 4;
    if (n >= N_NODES) return;
    int q = gid & 15;
    float4 acc = x[((size_t)n << 4) + q];
    int p1 = rowptr[n + 1];
    for (int p = rowptr[n]; p < p1; p++) {
        float4 v = x[((size_t)srcs[p] << 4) + q];
        acc.x += v.x; acc.y += v.y; acc.z += v.z; acc.w += v.w;
    }
    ushort4 o;
    o.x = f2bf(acc.x); o.y = f2bf(acc.y); o.z = f2bf(acc.z); o.w = f2bf(acc.w);
    *(ushort4*)&z[((size_t)n << 6) + (q << 2)] = o;
}

// ===== GANConv1 aggregation with fused BN+relu on load =====
__global__ __launch_bounds__(256) void k_gather_bn(const u16x8* __restrict__ raw,
                                                   const int* __restrict__ rowptr,
                                                   const int* __restrict__ srcs,
                                                   const float* __restrict__ bn_sums,
                                                   const float* __restrict__ g,
                                                   const float* __restrict__ b,
                                                   u16x8* __restrict__ z) {
    int gid = blockIdx.x * blockDim.x + threadIdx.x;
    int n = gid >> 4;
    if (n >= N_NODES) return;
    int q = gid & 15;
    float sc[8], sh[8];
#pragma unroll
    for (int i = 0; i < 8; i++) {
        int c = (q << 3) + i;
        float mean = bn_sums[c] / N_NODES;
        float istd = rsqrtf(bn_sums[HID + c] / N_NODES - mean * mean + EPSV);
        float s = istd * g[c];
        sc[i] = s;
        sh[i] = b[c] - mean * s;
    }
    u16x8 u0 = raw[((size_t)n << 4) + q];
    float acc[8];
#pragma unroll
    for (int i = 0; i < 8; i++) acc[i] = fmaxf(bf2f(u0[i]) * sc[i] + sh[i], 0.f);
    int p1 = rowptr[n + 1];
    for (int p = rowptr[n]; p < p1; p++) {
        u16x8 v = raw[((size_t)srcs[p] << 4) + q];
#pragma unroll
        for (int i = 0; i < 8; i++) acc[i] += fmaxf(bf2f(v[i]) * sc[i] + sh[i], 0.f);
    }
    u16x8 o;
#pragma unroll
    for (int i = 0; i < 8; i++) o[i] = f2bf(acc[i]);
    z[((size_t)n << 4) + q] = o;
}

// ===== weight prep: Wt[n][k] = bf16(W[k][n]) for 8 weights in one launch =====
struct WtJob  { const float* src; unsigned short* dst; int K; int N; };
struct WtJobs { WtJob j[8]; };
__global__ void k_wt_cast(WtJobs jobs) {
    WtJob jb = jobs.j[blockIdx.y];
    int total = jb.K * jb.N;
    for (int i = blockIdx.x * blockDim.x + threadIdx.x; i < total; i += gridDim.x * blockDim.x) {
        int nn = i / jb.K, kk = i - nn * jb.K;
        jb.dst[i] = f2bf(jb.src[(size_t)kk * jb.N + nn]);
    }
}

// ===== MFMA bf16 GEMM: C[M,N] = A'[M,K] @ Wt[N,K]^T + bias; bf16 out =====
// A' = BNA ? relu(bn(A)) : A. STATS: per-column output sum/sumsq via atomics.
// BIAS2: bias split biasL[0:256) | biasR[256:N).
template <int STATS, int BNA, int TM, int BIAS2>
__global__ __launch_bounds__(256) void k_mfma_gemm(const unsigned short* __restrict__ A,
                                                   const unsigned short* __restrict__ Wt,
                                                   const float* __restrict__ biasL,
                                                   const float* __restrict__ biasR,
                                                   unsigned short* __restrict__ Cout,
                                                   int M, int K, int N,
                                                   float* __restrict__ stats_sums,
                                                   const float* __restrict__ bn_sums,
                                                   const float* __restrict__ bn_g,
                                                   const float* __restrict__ bn_b) {
    constexpr int BNF = (TM == 128) ? 4 : 2;      // n-frags per wave
    __shared__ unsigned short As[TM][40];
    __shared__ unsigned short Bs[128][40];
    __shared__ float s_scale[BNA ? HID : 1], s_shift[BNA ? HID : 1];
    const int t = threadIdx.x;
    if (BNA) {
        if (t < HID) {
            float mean = bn_sums[t] / M;
            float istd = rsqrtf(bn_sums[HID + t] / M - mean * mean + EPSV);
            float s = istd * bn_g[t];
            s_scale[t] = s;
            s_shift[t] = bn_b[t] - mean * s;
        }
        __syncthreads();
    }
    const int wave = t >> 6, lane = t & 63;
    const int row0 = blockIdx.y * TM, col0 = blockIdx.x * 128;
    const int wm = (TM == 128) ? ((wave & 1) << 6) : 0;
    const int wn = (TM == 128) ? ((wave >> 1) << 6) : (wave << 5);
    const int lm = lane & 15, lk = (lane >> 4) << 3;
    constexpr int APASS = TM / 64;
    f32x4 acc[4][BNF] = {};
    for (int k0 = 0; k0 < K; k0 += 32) {
        u16x8 av[APASS], wv[2];
#pragma unroll
        for (int i = 0; i < APASS; i++) {
            int c = t + (i << 8);
            int r = c >> 2, ko = (c & 3) << 3;
            u16x8 zv = {};
            int gr = row0 + r;
            av[i] = (gr < M) ? *(const u16x8*)&A[(size_t)gr * K + k0 + ko] : zv;
            if (BNA) {
#pragma unroll
                for (int j = 0; j < 8; j++) {
                    int kc = k0 + ko + j;
                    float v = fmaxf(bf2f(av[i][j]) * s_scale[kc] + s_shift[kc], 0.f);
                    av[i][j] = f2bf(v);
                }
            }
        }
#pragma unroll
        for (int i = 0; i < 2; i++) {
            int c = t + (i << 8);
            int r = c >> 2, ko = (c & 3) << 3;
            wv[i] = *(const u16x8*)&Wt[(size_t)(col0 + r) * K + k0 + ko];
        }
        __syncthreads();
#pragma unroll
        for (int i = 0; i < APASS; i++) {
            int c = t + (i << 8);
            int r = c >> 2, ko = (c & 3) << 3;
            *(u16x8*)&As[r][ko] = av[i];
        }
#pragma unroll
        for (int i = 0; i < 2; i++) {
            int c = t + (i << 8);
            int r = c >> 2, ko = (c & 3) << 3;
            *(u16x8*)&Bs[r][ko] = wv[i];
        }
        __syncthreads();
        bf16x8 af[4], bfm[BNF];
#pragma unroll
        for (int i = 0; i < 4; i++) af[i]  = *(const bf16x8*)&As[wm + (i << 4) + lm][lk];
#pragma unroll
        for (int j = 0; j < BNF; j++) bfm[j] = *(const bf16x8*)&Bs[wn + (j << 4) + lm][lk];
#pragma unroll
        for (int i = 0; i < 4; i++)
#pragma unroll
            for (int j = 0; j < BNF; j++)
                acc[i][j] = __builtin_amdgcn_mfma_f32_16x16x32_bf16(af[i], bfm[j], acc[i][j], 0, 0, 0);
    }
    const int lr4 = (lane >> 4) << 2;
    float s1[BNF], s2[BNF];
#pragma unroll
    for (int j = 0; j < BNF; j++) { s1[j] = 0.f; s2[j] = 0.f; }
#pragma unroll
    for (int j = 0; j < BNF; j++) {
        int col = col0 + wn + (j << 4) + lm;
        float bv = BIAS2 ? ((col < 256) ? biasL[col] : biasR[col - 256]) : biasL[col];
#pragma unroll
        for (int i = 0; i < 4; i++) {
#pragma unroll
            for (int r = 0; r < 4; r++) {
                int row = row0 + wm + (i << 4) + lr4 + r;
                if (row < M) {
                    float v = acc[i][j][r] + bv;
                    Cout[(size_t)row * N + col] = f2bf(v);
                    if (STATS) { s1[j] += v; s2[j] += v * v; }
                }
            }
        }
    }
    if (STATS) {
#pragma unroll
        for (int j = 0; j < BNF; j++) {
            s1[j] += __shfl_xor(s1[j], 16, 64); s1[j] += __shfl_xor(s1[j], 32, 64);
            s2[j] += __shfl_xor(s2[j], 16, 64); s2[j] += __shfl_xor(s2[j], 32, 64);
        }
        if ((lane >> 4) == 0) {
#pragma unroll
            for (int j = 0; j < BNF; j++) {
                int col = col0 + wn + (j << 4) + lm;   // < 128 for stats GEMMs
                atomicAdd(&stats_sums[col], s1[j]);
                atomicAdd(&stats_sums[HID + col], s2[j]);
            }
        }
    }
}

// ========== fused ATTConv (GATv2): single-pass flash-style online softmax ==========
// One wave per node; lane l -> channels 4l..4l+3, head h = l>>5.
// Q is the merged projection buffer [N,512]: xl = row[0:256), xr = row[256:512).
// WITH_ALPHA also means INDIRECT: plist holds edge ids, src = other[e].
#define ATT_CAP 192
template <int CONCAT, int WITH_ALPHA>
__global__ __launch_bounds__(256) void k_att_fused(const ushort4* __restrict__ Q,
                                                   const int* __restrict__ rowptr,
                                                   const int* __restrict__ plist,
                                                   const int* __restrict__ other,
                                                   const float* __restrict__ att,
                                                   const float* __restrict__ bias,
                                                   void* __restrict__ outp,
                                                   float* __restrict__ alpha_out) {
    __shared__ float s_lg[4][ATT_CAP][2];
    const int t = threadIdx.x;
    const int wave = t >> 6, l = t & 63;
    const int n = blockIdx.x * 4 + wave;   // N_NODES % 4 == 0
    const int h = l >> 5;
    ushort4 ur = Q[((size_t)n << 7) + 64 + l];   // xr slice
    float xr4[4] = {bf2f(ur.x), bf2f(ur.y), bf2f(ur.z), bf2f(ur.w)};
    const float* ap = &att[h * HID + ((l & 31) << 2)];
    float at4[4] = {ap[0], ap[1], ap[2], ap[3]};
    const int p0 = rowptr[n], p1 = rowptr[n + 1];

    float m = -INFINITY, ssum = 0.f;
    float acc[4] = {0.f, 0.f, 0.f, 0.f};

#define ATT_SRC(p) (WITH_ALPHA ? other[plist[p]] : plist[p])

#define ATT_LOGIT(uv, x4, tl) do { \
        x4[0] = bf2f(uv.x); x4[1] = bf2f(uv.y); x4[2] = bf2f(uv.z); x4[3] = bf2f(uv.w); \
        float v0 = x4[0] + xr4[0]; v0 = (v0 > 0.f) ? v0 : 0.2f * v0; \
        float v1 = x4[1] + xr4[1]; v1 = (v1 > 0.f) ? v1 : 0.2f * v1; \
        float v2 = x4[2] + xr4[2]; v2 = (v2 > 0.f) ? v2 : 0.2f * v2; \
        float v3 = x4[3] + xr4[3]; v3 = (v3 > 0.f) ? v3 : 0.2f * v3; \
        tl = at4[0] * v0 + at4[1] * v1 + at4[2] * v2 + at4[3] * v3; \
    } while (0)

#define ATT_ONLINE(x4, tl, idx) do { \
        float mn = fmaxf(m, tl); \
        float sc = __expf(m - mn); \
        float w  = __expf(tl - mn); \
        ssum = ssum * sc + w; \
        acc[0] = acc[0] * sc + w * x4[0]; \
        acc[1] = acc[1] * sc + w * x4[1]; \
        acc[2] = acc[2] * sc + w * x4[2]; \
        acc[3] = acc[3] * sc + w * x4[3]; \
        m = mn; \
        if (WITH_ALPHA && (idx) < ATT_CAP && (l & 31) == 0) s_lg[wave][idx][h] = tl; \
    } while (0)

    int p = p0;
    for (; p + 4 <= p1; p += 4) {
        float x4[4][4], tl[4];
        ushort4 uv[4];
        int ss[4];
#pragma unroll
        for (int j = 0; j < 4; j++) ss[j] = ATT_SRC(p + j);
#pragma unroll
        for (int j = 0; j < 4; j++) uv[j] = Q[((size_t)ss[j] << 7) + l];
#pragma unroll
        for (int j = 0; j < 4; j++) ATT_LOGIT(uv[j], x4[j], tl[j]);
#pragma unroll
        for (int k = 1; k <= 16; k <<= 1) {
#pragma unroll
            for (int j = 0; j < 4; j++) tl[j] += __shfl_xor(tl[j], k, 64);
        }
#pragma unroll
        for (int j = 0; j < 4; j++) ATT_ONLINE(x4[j], tl[j], p + j - p0);
    }
    for (; p < p1; p++) {
        float x4[4], tl;
        ushort4 uv = Q[((size_t)ATT_SRC(p) << 7) + l];
        ATT_LOGIT(uv, x4, tl);
#pragma unroll
        for (int k = 1; k <= 16; k <<= 1) tl += __shfl_xor(tl, k, 64);
        ATT_ONLINE(x4, tl, p - p0);
    }
    float inv = 1.f / (ssum + 1e-16f);

    // ---- alpha output (att2): parallel from LDS cache ----
    if (WITH_ALPHA) {
        float m_o   = __shfl_xor(m, 32, 64);
        float inv_o = __shfl_xor(inv, 32, 64);
        float m2[2], i2[2];
        m2[h] = m; m2[1 - h] = m_o;
        i2[h] = inv; i2[1 - h] = inv_o;
        int cnt = p1 - p0;
        int ccnt = (cnt < ATT_CAP) ? cnt : ATT_CAP;
        for (int i = l; i < ccnt * 2; i += 64) {
            int idx = i >> 1, hh = i & 1;
            float a = __expf(s_lg[wave][idx][hh] - m2[hh]) * i2[hh];
            alpha_out[plist[p0 + idx] * HEADS + hh] = a;
        }
        // overflow fallback (deg > ATT_CAP): serial recompute (practically never taken)
        for (int pp = p0 + ATT_CAP; pp < p1; pp++) {
            float x4[4], tl;
            ushort4 uv = Q[((size_t)ATT_SRC(pp) << 7) + l];
            ATT_LOGIT(uv, x4, tl);
#pragma unroll
            for (int k = 1; k <= 16; k <<= 1) tl += __shfl_xor(tl, k, 64);
            if ((l & 31) == 0) alpha_out[plist[pp] * HEADS + h] = __expf(tl - m) * inv;
        }
    }

    // ---- epilogue ----
    if (CONCAT) {
        const float* bp = &bias[l << 2];
        ushort4 o;
        o.x = f2bf(fmaxf(acc[0] * inv + bp[0], 0.f));
        o.y = f2bf(fmaxf(acc[1] * inv + bp[1], 0.f));
        o.z = f2bf(fmaxf(acc[2] * inv + bp[2], 0.f));
        o.w = f2bf(fmaxf(acc[3] * inv + bp[3], 0.f));
        ((ushort4*)outp)[((size_t)n << 6) + l] = o;
    } else {
        float o[4];
#pragma unroll
        for (int i = 0; i < 4; i++) {
            float v = acc[i] * inv;
            float other_v = __shfl_xor(v, 32, 64);
            o[i] = 0.5f * (v + other_v);
        }
        if (l < 32) {
            const float* bp = &bias[(l & 31) << 2];
            float4 ov;
            ov.x = fmaxf(o[0] + bp[0], 0.f); ov.y = fmaxf(o[1] + bp[1], 0.f);
            ov.z = fmaxf(o[2] + bp[2], 0.f); ov.w = fmaxf(o[3] + bp[3], 0.f);
            ((float4*)outp)[((size_t)n << 5) + l] = ov;
        }
    }
#undef ATT_SRC
#undef ATT_LOGIT
#undef ATT_ONLINE
}

// ================= pooling over sorted batch_index (node-parallel) =================
template <int C>
__global__ __launch_bounds__(256) void k_pool_atomic(const float* __restrict__ X,
                                                     const int* __restrict__ batch,
                                                     float* __restrict__ pool, int npb) {
    const int RP = 256 / C;
    int c = threadIdx.x & (C - 1);
    int rofs = threadIdx.x / C;
    int i0 = blockIdx.x * npb;
    int i1 = min(i0 + npb, N_NODES);
    float acc = 0.f;
    int gcur = -1;
    for (int i = i0 + rofs; i < i1; i += RP) {
        int g = batch[i];
        if (g != gcur) {
            if (gcur >= 0) atomicAdd(&pool[gcur * C + c], acc);
            acc = 0.f; gcur = g;
        }
        acc += X[(size_t)i * C + c];
    }
    if (gcur >= 0) atomicAdd(&pool[gcur * C + c], acc);
}

// ================= final prediction head =================
__global__ void k_head(const float* __restrict__ pool0, const float* __restrict__ poolL,
                       const float* __restrict__ p0w, const float* __restrict__ p0b,
                       const float* __restrict__ pLw, const float* __restrict__ pLb,
                       const float* __restrict__ ow, const float* __restrict__ ob,
                       float* __restrict__ outputs) {
    int g = blockIdx.x;
    int m = threadIdx.x;
    __shared__ float sh[MIDD];
    if (m < MIDD) {
        float s = p0b[m] + pLb[m];
        for (int k = 0; k < F_INN; k++) s += pool0[g * F_INN + k] * p0w[k * MIDD + m];
        for (int k = 0; k < HID; k++)  s += poolL[g * HID + k] * pLw[k * MIDD + m];
        sh[m] = fmaxf(s, 0.f);
    }
    __syncthreads();
    if (m == 0) {
        float s = ob[0];
        for (int k = 0; k < MIDD; k++) s += sh[k] * ow[k];
        outputs[g] = s;
    }
}

extern "C" void kernel_launch(void* const* d_in, const int* in_sizes, int n_in,
                              void* d_out, int out_size, void* d_ws, size_t ws_size,
                              hipStream_t stream) {
    // ---- inputs ----
    const float* x      = (const float*)d_in[0];
    const int*   ei     = (const int*)d_in[1];
    const int*   aei    = (const int*)d_in[2];
    const int*   batch  = (const int*)d_in[3];
    const float* g0_w1  = (const float*)d_in[4];
    const float* g0_b1  = (const float*)d_in[5];
    const float* g0_bng = (const float*)d_in[6];
    const float* g0_bnb = (const float*)d_in[7];
    const float* g0_w2  = (const float*)d_in[8];
    const float* g0_b2  = (const float*)d_in[9];
    const float* g1_w1  = (const float*)d_in[10];
    const float* g1_b1  = (const float*)d_in[11];
    const float* g1_bng = (const float*)d_in[12];
    const float* g1_bnb = (const float*)d_in[13];
    const float* g1_w2  = (const float*)d_in[14];
    const float* g1_b2  = (const float*)d_in[15];
    const float* bn0_g  = (const float*)d_in[16];
    const float* bn0_b  = (const float*)d_in[17];
    const float* bn1_g  = (const float*)d_in[18];
    const float* bn1_b  = (const float*)d_in[19];
    const float* a1_wl  = (const float*)d_in[20];
    const float* a1_bl  = (const float*)d_in[21];
    const float* a1_wr  = (const float*)d_in[22];
    const float* a1_br  = (const float*)d_in[23];
    const float* a1_att = (const float*)d_in[24];
    const float* a1_bias= (const float*)d_in[25];
    const float* a2_wl  = (const float*)d_in[26];
    const float* a2_bl  = (const float*)d_in[27];
    const float* a2_wr  = (const float*)d_in[28];
    const float* a2_br  = (const float*)d_in[29];
    const float* a2_att = (const float*)d_in[30];
    const float* a2_bias= (const float*)d_in[31];
    const float* p0w    = (const float*)d_in[32];
    const float* p0b    = (const float*)d_in[33];
    const float* pLw    = (const float*)d_in[34];
    const float* pLb    = (const float*)d_in[35];
    const float* ow     = (const float*)d_in[36];
    const float* ob     = (const float*)d_in[37];

    // ---- outputs ----
    float* out_head  = (float*)d_out;
    float* atten_out = out_head + G_GR;
    float* alpha_out = atten_out + (size_t)N_NODES * HID;

    // ---- workspace ----
    float* ws = (float*)d_ws;
    float* sums4 = ws;                                 // 4*256 (s0|s1|s2|s3)
    float* pool0 = sums4 + 4 * 256;                    // G*64
    float* poolL = pool0 + G_GR * F_INN;               // G*128
    int*   deg3  = (int*)(poolL + G_GR * HID);         // 3*N
    const size_t zero_bytes = (4 * 256 + G_GR * F_INN + G_GR * HID + 3 * N_NODES) * 4;

    int* ip = deg3 + 3 * N_NODES;
    int* cursor3 = ip; ip += 3 * N_NODES;
    int* rowptr[3]; int* payload[3];
    for (int c = 0; c < 3; c++) {
        rowptr[c]  = ip; ip += N_NODES + 1;
        payload[c] = ip; ip += E_EDGES;
    }
    const size_t NB = (size_t)N_NODES * HC;
    unsigned short* B1 = (unsigned short*)ip;          // [N,HC] bf16
    unsigned short* B2 = B1 + NB;                      // [N,HC] bf16
    unsigned short* Qb = B2 + NB;                      // [N,512] bf16 merged projections
    unsigned short* g0w1t = Qb + 2 * NB;
    unsigned short* g0w2t = g0w1t + 128 * 64;
    unsigned short* g1w1t = g0w2t + 128 * 128;
    unsigned short* g1w2t = g1w1t + 128 * 128;
    unsigned short* a1wlt = g1w2t + 128 * 128;         // [256,128]
    unsigned short* a1wrt = a1wlt + 256 * 128;         // contiguous -> [512,128]
    unsigned short* a2wlt = a1wrt + 256 * 128;         // [256,256]
    unsigned short* a2wrt = a2wlt + 256 * 256;         // contiguous -> [512,256]

    const int* e_row = ei;
    const int* e_col = ei + E_EDGES;
    const int* a_src = aei;
    const int* a_dst = aei + E_EDGES;

    const int TB = 256;
#define GRID1(n) dim3(CDIV((n), TB))

    // ===== weight transpose+cast =====
    {
        WtJobs jobs;
        jobs.j[0] = {g0_w1, g0w1t, F_INN, HID};
        jobs.j[1] = {g0_w2, g0w2t, HID,   HID};
        jobs.j[2] = {g1_w1, g1w1t, HID,   HID};
        jobs.j[3] = {g1_w2, g1w2t, HID,   HID};
        jobs.j[4] = {a1_wl, a1wlt, HID,   HC};
        jobs.j[5] = {a1_wr, a1wrt, HID,   HC};
        jobs.j[6] = {a2_wl, a2wlt, HC,    HC};
        jobs.j[7] = {a2_wr, a2wrt, HC,    HC};
        k_wt_cast<<<dim3(32, 8), TB, 0, stream>>>(jobs);
    }

    // ===== zero sums/pools/deg in one shot; build 3 CSRs batched =====
    hipMemsetAsync(sums4, 0, zero_bytes, stream);
    {
        Csr3 c;
        c.key[0] = e_row; c.other[0] = e_col;
        c.key[1] = e_col; c.other[1] = e_row;
        c.key[2] = a_dst; c.other[2] = a_src;
        c.deg = deg3; c.cursor = cursor3;
        for (int i = 0; i < 3; i++) { c.rowptr[i] = rowptr[i]; c.out[i] = payload[i]; }
        k_hist3<<<dim3(CDIV(E_EDGES, TB), 3), TB, 0, stream>>>(c);
        k_scan3<<<dim3(3), 1024, 0, stream>>>(c);
        k_scatter3<<<dim3(CDIV(E_EDGES, TB), 3), TB, 0, stream>>>(c);
    }

    const dim3 gemm_g1(1, CDIV(N_NODES, 64));    // N=128, TM=64 (313 blocks)
    const dim3 gemm_gq(4, CDIV(N_NODES, 128));   // N=512, TM=128 (628 blocks)
    const float* NOF = nullptr;

    // ===== GANConv 0 (ping-pong B1/B2 as [N,128]) =====
    k_gather_f32<<<GRID1(N_NODES * 16), TB, 0, stream>>>((const float4*)x, rowptr[0], payload[0], B1);
    k_mfma_gemm<1, 0, 64, 0><<<gemm_g1, TB, 0, stream>>>(B1, g0w1t, g0_b1, NOF, B2, N_NODES, F_INN, HID,
                                                         sums4 + 0, NOF, NOF, NOF);
    k_mfma_gemm<1, 1, 64, 0><<<gemm_g1, TB, 0, stream>>>(B2, g0w2t, g0_b2, NOF, B1, N_NODES, HID, HID,
                                                         sums4 + 256, sums4 + 0, g0_bng, g0_bnb);
    // raw2 (pre-bn0) in B1

    // ===== GANConv 1 =====
    k_gather_bn<<<GRID1(N_NODES * 16), TB, 0, stream>>>((const u16x8*)B1, rowptr[0], payload[0],
                                                        sums4 + 256, bn0_g, bn0_b, (u16x8*)B2);
    k_mfma_gemm<1, 0, 64, 0><<<gemm_g1, TB, 0, stream>>>(B2, g1w1t, g1_b1, NOF, B1, N_NODES, HID, HID,
                                                         sums4 + 512, NOF, NOF, NOF);
    k_mfma_gemm<1, 1, 64, 0><<<gemm_g1, TB, 0, stream>>>(B1, g1w2t, g1_b2, NOF, B2, N_NODES, HID, HID,
                                                         sums4 + 768, sums4 + 512, g1_bng, g1_bnb);
    // raw4 (pre-bn1 = h2 raw) in B2

    // ===== ATTConv 1 (dst=e_col, concat=True): merged wl|wr GEMM -> Q [N,512] =====
    k_mfma_gemm<0, 1, 128, 1><<<gemm_gq, TB, 0, stream>>>(B2, a1wlt, a1_bl, a1_br, Qb, N_NODES, HID, 512,
                                                          nullptr, sums4 + 768, bn1_g, bn1_b);
    k_att_fused<1, 0><<<dim3(N_NODES / 4), TB, 0, stream>>>(
        (const ushort4*)Qb, rowptr[1], payload[1], nullptr, a1_att, a1_bias, (void*)B1, nullptr);
    // emb bf16 in B1 [N,HC]

    // ===== ATTConv 2 (dst=a_dst, concat=False): merged GEMM K=256 -> Q =====
    k_mfma_gemm<0, 0, 128, 1><<<gemm_gq, TB, 0, stream>>>(B1, a2wlt, a2_bl, a2_br, Qb, N_NODES, HC, 512,
                                                          nullptr, NOF, NOF, NOF);
    k_att_fused<0, 1><<<dim3(N_NODES / 4), TB, 0, stream>>>(
        (const ushort4*)Qb, rowptr[2], payload[2], a_src, a2_att, a2_bias, (void*)atten_out, alpha_out);

    // ===== pooling + head =====
    {
        const int npb = 64;  // 313 blocks
        k_pool_atomic<F_INN><<<dim3(CDIV(N_NODES, npb)), TB, 0, stream>>>(x, batch, pool0, npb);
        k_pool_atomic<HID><<<dim3(CDIV(N_NODES, npb)), TB, 0, stream>>>(atten_out, batch, poolL, npb);
    }
    k_head<<<dim3(G_GR), 64, 0, stream>>>(pool0, poolL, p0w, p0b, pLw, pLb, ow, ob, out_head);
}

// Round 11
// 484.670 us; speedup vs baseline: 7.5988x; 1.1437x over previous
//
#include <hip/hip_runtime.h>
#include <hip/hip_bf16.h>

#define N_NODES 20000
#define E_EDGES 320000
#define F_INN   64
#define HID     128
#define HEADS   2
#define HC      (HEADS * HID)   // 256
#define G_GR    64
#define MIDD    32
#define EPSV    1e-5f
#define NBUK    79              // ceil(20000/256); bucket = node >> 8

#define CDIV(a, b) (((a) + (b) - 1) / (b))

typedef __attribute__((ext_vector_type(8))) short          bf16x8;  // MFMA A/B frag
typedef __attribute__((ext_vector_type(4))) float          f32x4;   // MFMA C/D frag
typedef __attribute__((ext_vector_type(8))) unsigned short u16x8;

// ---------- bf16 helpers (RNE) ----------
__device__ inline float bf2f(unsigned short u) { return __uint_as_float((unsigned)u << 16); }
__device__ inline unsigned short f2bf(float f) {
    unsigned u = __float_as_uint(f);
    unsigned r = u + 0x7FFFu + ((u >> 16) & 1u);
    return (unsigned short)(r >> 16);
}

// ================= CSR construction (3 CSRs, bucketed two-pass scatter) ========
// CSR0 (GAN, key=e_row): payload = e_col[e] (src)
// CSR1 (ATT1, key=e_col): payload = e_row[e] (src)
// CSR2 (ATT2, key=a_dst): payload = e (edge id; src derived via a_src[e])
struct Csr3 {
    const int* key[3];
    const int* other[3];   // payload source for y=0,1; y=2 stores edge id
    int* deg;       // [3*N]
    int* rowptr[3]; // [N+1]
    int* out[3];    // [E] payload (final, CSR order)
    int2* tmp;      // [3*E] (key,payload) bucket-partitioned
    int* bcur;      // [3*NBUK] bucket cursors (init = bucket start)
};

__global__ void k_hist3(Csr3 c) {
    int e = blockIdx.x * blockDim.x + threadIdx.x;
    int y = blockIdx.y;
    if (e < E_EDGES) atomicAdd(&c.deg[y * N_NODES + c.key[y][e]], 1);
}

__global__ __launch_bounds__(1024) void k_scan3(Csr3 c) {
    const int PER = (N_NODES + 1023) / 1024;  // 20
    __shared__ int part[1024];
    const int y = blockIdx.x;
    const int* deg = c.deg + y * N_NODES;
    int* rowptr = c.rowptr[y];
    const int tid = threadIdx.x;
    const int base = tid * PER;
    int lv[PER];
    int lsum = 0;
#pragma unroll
    for (int i = 0; i < PER; i++) {
        int idx = base + i;
        int v = (idx < N_NODES) ? deg[idx] : 0;
        lv[i] = v; lsum += v;
    }
    part[tid] = lsum;
    __syncthreads();
    for (int off = 1; off < 1024; off <<= 1) {
        int t = (tid >= off) ? part[tid - off] : 0;
        __syncthreads();
        part[tid] += t;
        __syncthreads();
    }
    int run = part[tid] - lsum;
    if (tid == 0) rowptr[0] = 0;
#pragma unroll
    for (int i = 0; i < PER; i++) {
        int idx = base + i;
        if (idx < N_NODES) {
            run += lv[i];
            rowptr[idx + 1] = run;
        }
        if (idx < N_NODES && i == 0) rowptr[idx] = part[tid] - lsum;  // no-op guard
    }
    // rowptr[idx] for idx>0 written as rowptr[idx+1] of predecessor; rowptr[0]=0.
    __syncthreads();
    if (tid < NBUK) c.bcur[y * NBUK + tid] = rowptr[tid << 8];
}

// Pass A: partition edges into NBUK buckets; dense (key,payload) runs into tmp,
// laid out at final bucket offsets (bcur starts at rowptr[bucket_base]).
__global__ __launch_bounds__(256) void k_bucketA(Csr3 c) {
    __shared__ int hist[NBUK], base[NBUK], off[NBUK];
    const int y = blockIdx.y;
    const int chunk0 = blockIdx.x * 4096;
    const int t = threadIdx.x;
    for (int i = t; i < NBUK; i += 256) { hist[i] = 0; off[i] = 0; }
    __syncthreads();
    int keys[16], vals[16], bks[16];
#pragma unroll
    for (int i = 0; i < 16; i++) {
        int e = chunk0 + (i << 8) + t;
        bool ok = (e < E_EDGES);
        int k = ok ? c.key[y][e] : 0;
        keys[i] = k;
        vals[i] = ok ? ((y == 2) ? e : c.other[y][e]) : 0;
        bks[i] = ok ? (k >> 8) : -1;
        if (ok) atomicAdd(&hist[k >> 8], 1);
    }
    __syncthreads();
    if (t < NBUK && hist[t] > 0) base[t] = atomicAdd(&c.bcur[y * NBUK + t], hist[t]);
    __syncthreads();
    int2* ty = c.tmp + (size_t)y * E_EDGES;
#pragma unroll
    for (int i = 0; i < 16; i++) {
        int b = bks[i];
        if (b >= 0) {
            int o = atomicAdd(&off[b], 1);
            ty[base[b] + o] = make_int2(keys[i], vals[i]);
        }
    }
}

// Pass B: one workgroup per (bucket, csr). Per-node counts + prefix in LDS
// (zero global atomics); payload placed within the bucket's ~16KB span.
__global__ __launch_bounds__(256) void k_bucketB(Csr3 c) {
    __shared__ int cnt[256], lbase[256], run[256];
    const int y = blockIdx.y;
    const int b = blockIdx.x;
    const int nbase = b << 8;
    const int t = threadIdx.x;
    cnt[t] = 0; run[t] = 0;
    __syncthreads();
    const int* rowptr = c.rowptr[y];
    const int start = rowptr[nbase];
    const int nend = min(nbase + 256, N_NODES);
    const int end = rowptr[nend];
    const int2* ty = c.tmp + (size_t)y * E_EDGES;
    for (int i = start + t; i < end; i += 256)
        atomicAdd(&cnt[ty[i].x - nbase], 1);
    __syncthreads();
    int v = cnt[t];
    lbase[t] = v;
    __syncthreads();
    for (int off = 1; off < 256; off <<= 1) {
        int u = (t >= off) ? lbase[t - off] : 0;
        __syncthreads();
        lbase[t] += u;
        __syncthreads();
    }
    int excl = lbase[t] - v;
    __syncthreads();
    lbase[t] = excl;
    __syncthreads();
    int* outy = c.out[y];
    for (int i = start + t; i < end; i += 256) {
        int2 kv = ty[i];
        int k = kv.x - nbase;
        int o = atomicAdd(&run[k], 1);
        outy[start + lbase[k] + o] = kv.y;
    }
}

// ===== GANConv0 aggregation: z[n] = bf16(x[n] + sum x[srcs]) , fp32 input =====
__global__ __launch_bounds__(256) void k_gather_f32(const float4* __restrict__ x,
                                                    const int* __restrict__ rowptr,
                                                    const int* __restrict__ srcs,
                                                    unsigned short* __restrict__ z) {
    int gid = blockIdx.x * blockDim.x + threadIdx.x;
    int n = gid >> 4;
    if (n >= N_NODES) return;
    int q = gid & 15;
    float4 acc = x[((size_t)n << 4) + q];
    int p1 = rowptr[n + 1];
    for (int p = rowptr[n]; p < p1; p++) {
        float4 v = x[((size_t)srcs[p] << 4) + q];
        acc.x += v.x; acc.y += v.y; acc.z += v.z; acc.w += v.w;
    }
    ushort4 o;
    o.x = f2bf(acc.x); o.y = f2bf(acc.y); o.z = f2bf(acc.z); o.w = f2bf(acc.w);
    *(ushort4*)&z[((size_t)n << 6) + (q << 2)] = o;
}

// ===== GANConv1 aggregation with fused BN+relu on load =====
__global__ __launch_bounds__(256) void k_gather_bn(const u16x8* __restrict__ raw,
                                                   const int* __restrict__ rowptr,
                                                   const int* __restrict__ srcs,
                                                   const float* __restrict__ bn_sums,
                                                   const float* __restrict__ g,
                                                   const float* __restrict__ b,
                                                   u16x8* __restrict__ z) {
    int gid = blockIdx.x * blockDim.x + threadIdx.x;
    int n = gid >> 4;
    if (n >= N_NODES) return;
    int q = gid & 15;
    float sc[8], sh[8];
#pragma unroll
    for (int i = 0; i < 8; i++) {
        int c = (q << 3) + i;
        float mean = bn_sums[c] / N_NODES;
        float istd = rsqrtf(bn_sums[HID + c] / N_NODES - mean * mean + EPSV);
        float s = istd * g[c];
        sc[i] = s;
        sh[i] = b[c] - mean * s;
    }
    u16x8 u0 = raw[((size_t)n << 4) + q];
    float acc[8];
#pragma unroll
    for (int i = 0; i < 8; i++) acc[i] = fmaxf(bf2f(u0[i]) * sc[i] + sh[i], 0.f);
    int p1 = rowptr[n + 1];
    for (int p = rowptr[n]; p < p1; p++) {
        u16x8 v = raw[((size_t)srcs[p] << 4) + q];
#pragma unroll
        for (int i = 0; i < 8; i++) acc[i] += fmaxf(bf2f(v[i]) * sc[i] + sh[i], 0.f);
    }
    u16x8 o;
#pragma unroll
    for (int i = 0; i < 8; i++) o[i] = f2bf(acc[i]);
    z[((size_t)n << 4) + q] = o;
}

// ===== weight prep: Wt[n][k] = bf16(W[k][n]) for 8 weights in one launch =====
struct WtJob  { const float* src; unsigned short* dst; int K; int N; };
struct WtJobs { WtJob j[8]; };
__global__ void k_wt_cast(WtJobs jobs) {
    WtJob jb = jobs.j[blockIdx.y];
    int total = jb.K * jb.N;
    for (int i = blockIdx.x * blockDim.x + threadIdx.x; i < total; i += gridDim.x * blockDim.x) {
        int nn = i / jb.K, kk = i - nn * jb.K;
        jb.dst[i] = f2bf(jb.src[(size_t)kk * jb.N + nn]);
    }
}

// ===== MFMA bf16 GEMM: C[M,N] = A'[M,K] @ Wt[N,K]^T + bias; bf16 out =====
// A' = BNA ? relu(bn(A)) : A. STATS: per-column output sum/sumsq via atomics.
// BIAS2: bias split biasL[0:256) | biasR[256:N).
template <int STATS, int BNA, int TM, int BIAS2>
__global__ __launch_bounds__(256) void k_mfma_gemm(const unsigned short* __restrict__ A,
                                                   const unsigned short* __restrict__ Wt,
                                                   const float* __restrict__ biasL,
                                                   const float* __restrict__ biasR,
                                                   unsigned short* __restrict__ Cout,
                                                   int M, int K, int N,
                                                   float* __restrict__ stats_sums,
                                                   const float* __restrict__ bn_sums,
                                                   const float* __restrict__ bn_g,
                                                   const float* __restrict__ bn_b) {
    constexpr int BNF = (TM == 128) ? 4 : 2;      // n-frags per wave
    __shared__ unsigned short As[TM][40];
    __shared__ unsigned short Bs[128][40];
    __shared__ float s_scale[BNA ? HID : 1], s_shift[BNA ? HID : 1];
    const int t = threadIdx.x;
    if (BNA) {
        if (t < HID) {
            float mean = bn_sums[t] / M;
            float istd = rsqrtf(bn_sums[HID + t] / M - mean * mean + EPSV);
            float s = istd * bn_g[t];
            s_scale[t] = s;
            s_shift[t] = bn_b[t] - mean * s;
        }
        __syncthreads();
    }
    const int wave = t >> 6, lane = t & 63;
    const int row0 = blockIdx.y * TM, col0 = blockIdx.x * 128;
    const int wm = (TM == 128) ? ((wave & 1) << 6) : 0;
    const int wn = (TM == 128) ? ((wave >> 1) << 6) : (wave << 5);
    const int lm = lane & 15, lk = (lane >> 4) << 3;
    constexpr int APASS = TM / 64;
    f32x4 acc[4][BNF] = {};
    for (int k0 = 0; k0 < K; k0 += 32) {
        u16x8 av[APASS], wv[2];
#pragma unroll
        for (int i = 0; i < APASS; i++) {
            int c = t + (i << 8);
            int r = c >> 2, ko = (c & 3) << 3;
            u16x8 zv = {};
            int gr = row0 + r;
            av[i] = (gr < M) ? *(const u16x8*)&A[(size_t)gr * K + k0 + ko] : zv;
            if (BNA) {
#pragma unroll
                for (int j = 0; j < 8; j++) {
                    int kc = k0 + ko + j;
                    float v = fmaxf(bf2f(av[i][j]) * s_scale[kc] + s_shift[kc], 0.f);
                    av[i][j] = f2bf(v);
                }
            }
        }
#pragma unroll
        for (int i = 0; i < 2; i++) {
            int c = t + (i << 8);
            int r = c >> 2, ko = (c & 3) << 3;
            wv[i] = *(const u16x8*)&Wt[(size_t)(col0 + r) * K + k0 + ko];
        }
        __syncthreads();
#pragma unroll
        for (int i = 0; i < APASS; i++) {
            int c = t + (i << 8);
            int r = c >> 2, ko = (c & 3) << 3;
            *(u16x8*)&As[r][ko] = av[i];
        }
#pragma unroll
        for (int i = 0; i < 2; i++) {
            int c = t + (i << 8);
            int r = c >> 2, ko = (c & 3) << 3;
            *(u16x8*)&Bs[r][ko] = wv[i];
        }
        __syncthreads();
        bf16x8 af[4], bfm[BNF];
#pragma unroll
        for (int i = 0; i < 4; i++) af[i]  = *(const bf16x8*)&As[wm + (i << 4) + lm][lk];
#pragma unroll
        for (int j = 0; j < BNF; j++) bfm[j] = *(const bf16x8*)&Bs[wn + (j << 4) + lm][lk];
#pragma unroll
        for (int i = 0; i < 4; i++)
#pragma unroll
            for (int j = 0; j < BNF; j++)
                acc[i][j] = __builtin_amdgcn_mfma_f32_16x16x32_bf16(af[i], bfm[j], acc[i][j], 0, 0, 0);
    }
    const int lr4 = (lane >> 4) << 2;
    float s1[BNF], s2[BNF];
#pragma unroll
    for (int j = 0; j < BNF; j++) { s1[j] = 0.f; s2[j] = 0.f; }
#pragma unroll
    for (int j = 0; j < BNF; j++) {
        int col = col0 + wn + (j << 4) + lm;
        float bv = BIAS2 ? ((col < 256) ? biasL[col] : biasR[col - 256]) : biasL[col];
#pragma unroll
        for (int i = 0; i < 4; i++) {
#pragma unroll
            for (int r = 0; r < 4; r++) {
                int row = row0 + wm + (i << 4) + lr4 + r;
                if (row < M) {
                    float v = acc[i][j][r] + bv;
                    Cout[(size_t)row * N + col] = f2bf(v);
                    if (STATS) { s1[j] += v; s2[j] += v * v; }
                }
            }
        }
    }
    if (STATS) {
#pragma unroll
        for (int j = 0; j < BNF; j++) {
            s1[j] += __shfl_xor(s1[j], 16, 64); s1[j] += __shfl_xor(s1[j], 32, 64);
            s2[j] += __shfl_xor(s2[j], 16, 64); s2[j] += __shfl_xor(s2[j], 32, 64);
        }
        if ((lane >> 4) == 0) {
#pragma unroll
            for (int j = 0; j < BNF; j++) {
                int col = col0 + wn + (j << 4) + lm;   // < 128 for stats GEMMs
                atomicAdd(&stats_sums[col], s1[j]);
                atomicAdd(&stats_sums[HID + col], s2[j]);
            }
        }
    }
}

// ========== fused ATTConv (GATv2): single-pass flash-style online softmax ==========
// One wave per node; lane l -> channels 4l..4l+3, head h = l>>5.
// Q is the merged projection buffer [N,512]: xl = row[0:256), xr = row[256:512).
// WITH_ALPHA also means INDIRECT: plist holds edge ids, src = other[e].
#define ATT_CAP 192
template <int CONCAT, int WITH_ALPHA>
__global__ __launch_bounds__(256) void k_att_fused(const ushort4* __restrict__ Q,
                                                   const int* __restrict__ rowptr,
                                                   const int* __restrict__ plist,
                                                   const int* __restrict__ other,
                                                   const float* __restrict__ att,
                                                   const float* __restrict__ bias,
                                                   void* __restrict__ outp,
                                                   float* __restrict__ alpha_out) {
    __shared__ float s_lg[4][ATT_CAP][2];
    const int t = threadIdx.x;
    const int wave = t >> 6, l = t & 63;
    const int n = blockIdx.x * 4 + wave;   // N_NODES % 4 == 0
    const int h = l >> 5;
    ushort4 ur = Q[((size_t)n << 7) + 64 + l];   // xr slice
    float xr4[4] = {bf2f(ur.x), bf2f(ur.y), bf2f(ur.z), bf2f(ur.w)};
    const float* ap = &att[h * HID + ((l & 31) << 2)];
    float at4[4] = {ap[0], ap[1], ap[2], ap[3]};
    const int p0 = rowptr[n], p1 = rowptr[n + 1];

    float m = -INFINITY, ssum = 0.f;
    float acc[4] = {0.f, 0.f, 0.f, 0.f};

#define ATT_SRC(p) (WITH_ALPHA ? other[plist[p]] : plist[p])

#define ATT_LOGIT(uv, x4, tl) do { \
        x4[0] = bf2f(uv.x); x4[1] = bf2f(uv.y); x4[2] = bf2f(uv.z); x4[3] = bf2f(uv.w); \
        float v0 = x4[0] + xr4[0]; v0 = (v0 > 0.f) ? v0 : 0.2f * v0; \
        float v1 = x4[1] + xr4[1]; v1 = (v1 > 0.f) ? v1 : 0.2f * v1; \
        float v2 = x4[2] + xr4[2]; v2 = (v2 > 0.f) ? v2 : 0.2f * v2; \
        float v3 = x4[3] + xr4[3]; v3 = (v3 > 0.f) ? v3 : 0.2f * v3; \
        tl = at4[0] * v0 + at4[1] * v1 + at4[2] * v2 + at4[3] * v3; \
    } while (0)

#define ATT_ONLINE(x4, tl, idx) do { \
        float mn = fmaxf(m, tl); \
        float sc = __expf(m - mn); \
        float w  = __expf(tl - mn); \
        ssum = ssum * sc + w; \
        acc[0] = acc[0] * sc + w * x4[0]; \
        acc[1] = acc[1] * sc + w * x4[1]; \
        acc[2] = acc[2] * sc + w * x4[2]; \
        acc[3] = acc[3] * sc + w * x4[3]; \
        m = mn; \
        if (WITH_ALPHA && (idx) < ATT_CAP && (l & 31) == 0) s_lg[wave][idx][h] = tl; \
    } while (0)

    int p = p0;
    for (; p + 4 <= p1; p += 4) {
        float x4[4][4], tl[4];
        ushort4 uv[4];
        int ss[4];
#pragma unroll
        for (int j = 0; j < 4; j++) ss[j] = ATT_SRC(p + j);
#pragma unroll
        for (int j = 0; j < 4; j++) uv[j] = Q[((size_t)ss[j] << 7) + l];
#pragma unroll
        for (int j = 0; j < 4; j++) ATT_LOGIT(uv[j], x4[j], tl[j]);
#pragma unroll
        for (int k = 1; k <= 16; k <<= 1) {
#pragma unroll
            for (int j = 0; j < 4; j++) tl[j] += __shfl_xor(tl[j], k, 64);
        }
#pragma unroll
        for (int j = 0; j < 4; j++) ATT_ONLINE(x4[j], tl[j], p + j - p0);
    }
    for (; p < p1; p++) {
        float x4[4], tl;
        ushort4 uv = Q[((size_t)ATT_SRC(p) << 7) + l];
        ATT_LOGIT(uv, x4, tl);
#pragma unroll
        for (int k = 1; k <= 16; k <<= 1) tl += __shfl_xor(tl, k, 64);
        ATT_ONLINE(x4, tl, p - p0);
    }
    float inv = 1.f / (ssum + 1e-16f);

    // ---- alpha output (att2): parallel from LDS cache ----
    if (WITH_ALPHA) {
        float m_o   = __shfl_xor(m, 32, 64);
        float inv_o = __shfl_xor(inv, 32, 64);
        float m2[2], i2[2];
        m2[h] = m; m2[1 - h] = m_o;
        i2[h] = inv; i2[1 - h] = inv_o;
        int cnt = p1 - p0;
        int ccnt = (cnt < ATT_CAP) ? cnt : ATT_CAP;
        for (int i = l; i < ccnt * 2; i += 64) {
            int idx = i >> 1, hh = i & 1;
            float a = __expf(s_lg[wave][idx][hh] - m2[hh]) * i2[hh];
            alpha_out[plist[p0 + idx] * HEADS + hh] = a;
        }
        // overflow fallback (deg > ATT_CAP): serial recompute (practically never taken)
        for (int pp = p0 + ATT_CAP; pp < p1; pp++) {
            float x4[4], tl;
            ushort4 uv = Q[((size_t)ATT_SRC(pp) << 7) + l];
            ATT_LOGIT(uv, x4, tl);
#pragma unroll
            for (int k = 1; k <= 16; k <<= 1) tl += __shfl_xor(tl, k, 64);
            if ((l & 31) == 0) alpha_out[plist[pp] * HEADS + h] = __expf(tl - m) * inv;
        }
    }

    // ---- epilogue ----
    if (CONCAT) {
        const float* bp = &bias[l << 2];
        ushort4 o;
        o.x = f2bf(fmaxf(acc[0] * inv + bp[0], 0.f));
        o.y = f2bf(fmaxf(acc[1] * inv + bp[1], 0.f));
        o.z = f2bf(fmaxf(acc[2] * inv + bp[2], 0.f));
        o.w = f2bf(fmaxf(acc[3] * inv + bp[3], 0.f));
        ((ushort4*)outp)[((size_t)n << 6) + l] = o;
    } else {
        float o[4];
#pragma unroll
        for (int i = 0; i < 4; i++) {
            float v = acc[i] * inv;
            float other_v = __shfl_xor(v, 32, 64);
            o[i] = 0.5f * (v + other_v);
        }
        if (l < 32) {
            const float* bp = &bias[(l & 31) << 2];
            float4 ov;
            ov.x = fmaxf(o[0] + bp[0], 0.f); ov.y = fmaxf(o[1] + bp[1], 0.f);
            ov.z = fmaxf(o[2] + bp[2], 0.f); ov.w = fmaxf(o[3] + bp[3], 0.f);
            ((float4*)outp)[((size_t)n << 5) + l] = ov;
        }
    }
#undef ATT_SRC
#undef ATT_LOGIT
#undef ATT_ONLINE
}

// ================= pooling over sorted batch_index (node-parallel) =================
template <int C>
__global__ __launch_bounds__(256) void k_pool_atomic(const float* __restrict__ X,
                                                     const int* __restrict__ batch,
                                                     float* __restrict__ pool, int npb) {
    const int RP = 256 / C;
    int c = threadIdx.x & (C - 1);
    int rofs = threadIdx.x / C;
    int i0 = blockIdx.x * npb;
    int i1 = min(i0 + npb, N_NODES);
    float acc = 0.f;
    int gcur = -1;
    for (int i = i0 + rofs; i < i1; i += RP) {
        int g = batch[i];
        if (g != gcur) {
            if (gcur >= 0) atomicAdd(&pool[gcur * C + c], acc);
            acc = 0.f; gcur = g;
        }
        acc += X[(size_t)i * C + c];
    }
    if (gcur >= 0) atomicAdd(&pool[gcur * C + c], acc);
}

// ================= final prediction head =================
__global__ void k_head(const float* __restrict__ pool0, const float* __restrict__ poolL,
                       const float* __restrict__ p0w, const float* __restrict__ p0b,
                       const float* __restrict__ pLw, const float* __restrict__ pLb,
                       const float* __restrict__ ow, const float* __restrict__ ob,
                       float* __restrict__ outputs) {
    int g = blockIdx.x;
    int m = threadIdx.x;
    __shared__ float sh[MIDD];
    if (m < MIDD) {
        float s = p0b[m] + pLb[m];
        for (int k = 0; k < F_INN; k++) s += pool0[g * F_INN + k] * p0w[k * MIDD + m];
        for (int k = 0; k < HID; k++)  s += poolL[g * HID + k] * pLw[k * MIDD + m];
        sh[m] = fmaxf(s, 0.f);
    }
    __syncthreads();
    if (m == 0) {
        float s = ob[0];
        for (int k = 0; k < MIDD; k++) s += sh[k] * ow[k];
        outputs[g] = s;
    }
}

extern "C" void kernel_launch(void* const* d_in, const int* in_sizes, int n_in,
                              void* d_out, int out_size, void* d_ws, size_t ws_size,
                              hipStream_t stream) {
    // ---- inputs ----
    const float* x      = (const float*)d_in[0];
    const int*   ei     = (const int*)d_in[1];
    const int*   aei    = (const int*)d_in[2];
    const int*   batch  = (const int*)d_in[3];
    const float* g0_w1  = (const float*)d_in[4];
    const float* g0_b1  = (const float*)d_in[5];
    const float* g0_bng = (const float*)d_in[6];
    const float* g0_bnb = (const float*)d_in[7];
    const float* g0_w2  = (const float*)d_in[8];
    const float* g0_b2  = (const float*)d_in[9];
    const float* g1_w1  = (const float*)d_in[10];
    const float* g1_b1  = (const float*)d_in[11];
    const float* g1_bng = (const float*)d_in[12];
    const float* g1_bnb = (const float*)d_in[13];
    const float* g1_w2  = (const float*)d_in[14];
    const float* g1_b2  = (const float*)d_in[15];
    const float* bn0_g  = (const float*)d_in[16];
    const float* bn0_b  = (const float*)d_in[17];
    const float* bn1_g  = (const float*)d_in[18];
    const float* bn1_b  = (const float*)d_in[19];
    const float* a1_wl  = (const float*)d_in[20];
    const float* a1_bl  = (const float*)d_in[21];
    const float* a1_wr  = (const float*)d_in[22];
    const float* a1_br  = (const float*)d_in[23];
    const float* a1_att = (const float*)d_in[24];
    const float* a1_bias= (const float*)d_in[25];
    const float* a2_wl  = (const float*)d_in[26];
    const float* a2_bl  = (const float*)d_in[27];
    const float* a2_wr  = (const float*)d_in[28];
    const float* a2_br  = (const float*)d_in[29];
    const float* a2_att = (const float*)d_in[30];
    const float* a2_bias= (const float*)d_in[31];
    const float* p0w    = (const float*)d_in[32];
    const float* p0b    = (const float*)d_in[33];
    const float* pLw    = (const float*)d_in[34];
    const float* pLb    = (const float*)d_in[35];
    const float* ow     = (const float*)d_in[36];
    const float* ob     = (const float*)d_in[37];

    // ---- outputs ----
    float* out_head  = (float*)d_out;
    float* atten_out = out_head + G_GR;
    float* alpha_out = atten_out + (size_t)N_NODES * HID;

    // ---- workspace ----
    float* ws = (float*)d_ws;
    float* sums4 = ws;                                 // 4*256 (s0|s1|s2|s3)
    float* pool0 = sums4 + 4 * 256;                    // G*64
    float* poolL = pool0 + G_GR * F_INN;               // G*128
    int*   deg3  = (int*)(poolL + G_GR * HID);         // 3*N
    const size_t zero_bytes = (4 * 256 + G_GR * F_INN + G_GR * HID + 3 * N_NODES) * 4;

    int* ip = deg3 + 3 * N_NODES;
    int* bcur = ip; ip += 3 * NBUK;
    int* rowptr[3]; int* payload[3];
    for (int c = 0; c < 3; c++) {
        rowptr[c]  = ip; ip += N_NODES + 1;
        payload[c] = ip; ip += E_EDGES;
    }
    int2* tmp3 = (int2*)ip; ip += 2 * 3 * E_EDGES;     // [3][E] int2
    const size_t NB = (size_t)N_NODES * HC;
    unsigned short* B1 = (unsigned short*)ip;          // [N,HC] bf16
    unsigned short* B2 = B1 + NB;                      // [N,HC] bf16
    unsigned short* Qb = B2 + NB;                      // [N,512] bf16 merged projections
    unsigned short* g0w1t = Qb + 2 * NB;
    unsigned short* g0w2t = g0w1t + 128 * 64;
    unsigned short* g1w1t = g0w2t + 128 * 128;
    unsigned short* g1w2t = g1w1t + 128 * 128;
    unsigned short* a1wlt = g1w2t + 128 * 128;         // [256,128]
    unsigned short* a1wrt = a1wlt + 256 * 128;         // contiguous -> [512,128]
    unsigned short* a2wlt = a1wrt + 256 * 128;         // [256,256]
    unsigned short* a2wrt = a2wlt + 256 * 256;         // contiguous -> [512,256]

    const int* e_row = ei;
    const int* e_col = ei + E_EDGES;
    const int* a_src = aei;
    const int* a_dst = aei + E_EDGES;

    const int TB = 256;
#define GRID1(n) dim3(CDIV((n), TB))

    // ===== weight transpose+cast =====
    {
        WtJobs jobs;
        jobs.j[0] = {g0_w1, g0w1t, F_INN, HID};
        jobs.j[1] = {g0_w2, g0w2t, HID,   HID};
        jobs.j[2] = {g1_w1, g1w1t, HID,   HID};
        jobs.j[3] = {g1_w2, g1w2t, HID,   HID};
        jobs.j[4] = {a1_wl, a1wlt, HID,   HC};
        jobs.j[5] = {a1_wr, a1wrt, HID,   HC};
        jobs.j[6] = {a2_wl, a2wlt, HC,    HC};
        jobs.j[7] = {a2_wr, a2wrt, HC,    HC};
        k_wt_cast<<<dim3(32, 8), TB, 0, stream>>>(jobs);
    }

    // ===== zero sums/pools/deg in one shot; build 3 CSRs (bucketed) =====
    hipMemsetAsync(sums4, 0, zero_bytes, stream);
    {
        Csr3 c;
        c.key[0] = e_row; c.other[0] = e_col;
        c.key[1] = e_col; c.other[1] = e_row;
        c.key[2] = a_dst; c.other[2] = a_src;
        c.deg = deg3; c.tmp = tmp3; c.bcur = bcur;
        for (int i = 0; i < 3; i++) { c.rowptr[i] = rowptr[i]; c.out[i] = payload[i]; }
        k_hist3<<<dim3(CDIV(E_EDGES, TB), 3), TB, 0, stream>>>(c);
        k_scan3<<<dim3(3), 1024, 0, stream>>>(c);
        k_bucketA<<<dim3(CDIV(E_EDGES, 4096), 3), TB, 0, stream>>>(c);
        k_bucketB<<<dim3(NBUK, 3), TB, 0, stream>>>(c);
    }

    const dim3 gemm_g1(1, CDIV(N_NODES, 64));    // N=128, TM=64 (313 blocks)
    const dim3 gemm_gq(4, CDIV(N_NODES, 128));   // N=512, TM=128 (628 blocks)
    const float* NOF = nullptr;

    // ===== GANConv 0 (ping-pong B1/B2 as [N,128]) =====
    k_gather_f32<<<GRID1(N_NODES * 16), TB, 0, stream>>>((const float4*)x, rowptr[0], payload[0], B1);
    k_mfma_gemm<1, 0, 64, 0><<<gemm_g1, TB, 0, stream>>>(B1, g0w1t, g0_b1, NOF, B2, N_NODES, F_INN, HID,
                                                         sums4 + 0, NOF, NOF, NOF);
    k_mfma_gemm<1, 1, 64, 0><<<gemm_g1, TB, 0, stream>>>(B2, g0w2t, g0_b2, NOF, B1, N_NODES, HID, HID,
                                                         sums4 + 256, sums4 + 0, g0_bng, g0_bnb);
    // raw2 (pre-bn0) in B1

    // ===== GANConv 1 =====
    k_gather_bn<<<GRID1(N_NODES * 16), TB, 0, stream>>>((const u16x8*)B1, rowptr[0], payload[0],
                                                        sums4 + 256, bn0_g, bn0_b, (u16x8*)B2);
    k_mfma_gemm<1, 0, 64, 0><<<gemm_g1, TB, 0, stream>>>(B2, g1w1t, g1_b1, NOF, B1, N_NODES, HID, HID,
                                                         sums4 + 512, NOF, NOF, NOF);
    k_mfma_gemm<1, 1, 64, 0><<<gemm_g1, TB, 0, stream>>>(B1, g1w2t, g1_b2, NOF, B2, N_NODES, HID, HID,
                                                         sums4 + 768, sums4 + 512, g1_bng, g1_bnb);
    // raw4 (pre-bn1 = h2 raw) in B2

    // ===== ATTConv 1 (dst=e_col, concat=True): merged wl|wr GEMM -> Q [N,512] =====
    k_mfma_gemm<0, 1, 128, 1><<<gemm_gq, TB, 0, stream>>>(B2, a1wlt, a1_bl, a1_br, Qb, N_NODES, HID, 512,
                                                          nullptr, sums4 + 768, bn1_g, bn1_b);
    k_att_fused<1, 0><<<dim3(N_NODES / 4), TB, 0, stream>>>(
        (const ushort4*)Qb, rowptr[1], payload[1], nullptr, a1_att, a1_bias, (void*)B1, nullptr);
    // emb bf16 in B1 [N,HC]

    // ===== ATTConv 2 (dst=a_dst, concat=False): merged GEMM K=256 -> Q =====
    k_mfma_gemm<0, 0, 128, 1><<<gemm_gq, TB, 0, stream>>>(B1, a2wlt, a2_bl, a2_br, Qb, N_NODES, HC, 512,
                                                          nullptr, NOF, NOF, NOF);
    k_att_fused<0, 1><<<dim3(N_NODES / 4), TB, 0, stream>>>(
        (const ushort4*)Qb, rowptr[2], payload[2], a_src, a2_att, a2_bias, (void*)atten_out, alpha_out);

    // ===== pooling + head =====
    {
        const int npb = 64;  // 313 blocks
        k_pool_atomic<F_INN><<<dim3(CDIV(N_NODES, npb)), TB, 0, stream>>>(x, batch, pool0, npb);
        k_pool_atomic<HID><<<dim3(CDIV(N_NODES, npb)), TB, 0, stream>>>(atten_out, batch, poolL, npb);
    }
    k_head<<<dim3(G_GR), 64, 0, stream>>>(pool0, poolL, p0w, p0b, pLw, pLb, ow, ob, out_head);
}

// Round 12
// 446.016 us; speedup vs baseline: 8.2574x; 1.0867x over previous
//
#include <hip/hip_runtime.h>
#include <hip/hip_bf16.h>

#define N_NODES 20000
#define E_EDGES 320000
#define F_INN   64
#define HID     128
#define HEADS   2
#define HC      (HEADS * HID)   // 256
#define G_GR    64
#define MIDD    32
#define EPSV    1e-5f
#define NBUK    79              // ceil(20000/256); bucket = node >> 8

#define CDIV(a, b) (((a) + (b) - 1) / (b))

typedef __attribute__((ext_vector_type(8))) short          bf16x8;  // MFMA A/B frag
typedef __attribute__((ext_vector_type(4))) float          f32x4;   // MFMA C/D frag
typedef __attribute__((ext_vector_type(8))) unsigned short u16x8;

// ---------- bf16 helpers (RNE) ----------
__device__ inline float bf2f(unsigned short u) { return __uint_as_float((unsigned)u << 16); }
__device__ inline unsigned short f2bf(float f) {
    unsigned u = __float_as_uint(f);
    unsigned r = u + 0x7FFFu + ((u >> 16) & 1u);
    return (unsigned short)(r >> 16);
}

// ================= CSR construction (3 CSRs, bucket-granular two-pass) ========
// CSR0 (GAN, key=e_row): payload = e_col[e] (src)
// CSR1 (ATT1, key=e_col): payload = e_row[e] (src)
// CSR2 (ATT2, key=a_dst): payload = e (edge id; src derived via a_src[e])
struct Csr3 {
    const int* key[3];
    const int* other[3];   // payload source for y=0,1; y=2 stores edge id
    int* btot;      // [3*NBUK] bucket totals (zeroed)
    int* bstart;    // [3*(NBUK+1)] bucket starts
    int* bcur;      // [3*NBUK] bucket cursors
    int* rowptr[3]; // [N+1] (written by bucketB)
    int* out[3];    // [E] payload (final, CSR order)
    int2* tmp;      // [3*E] (key,payload) bucket-partitioned
};

// bucket-level histogram: LDS-accumulated, 79 atomic targets per block
__global__ __launch_bounds__(256) void k_bhist(Csr3 c) {
    __shared__ int hist[NBUK];
    const int y = blockIdx.y;
    const int chunk0 = blockIdx.x * 4096;
    const int t = threadIdx.x;
    for (int i = t; i < NBUK; i += 256) hist[i] = 0;
    __syncthreads();
#pragma unroll
    for (int i = 0; i < 16; i++) {
        int e = chunk0 + (i << 8) + t;
        if (e < E_EDGES) atomicAdd(&hist[c.key[y][e] >> 8], 1);
    }
    __syncthreads();
    for (int i = t; i < NBUK; i += 256)
        if (hist[i] > 0) atomicAdd(&c.btot[y * NBUK + i], hist[i]);
}

// tiny bucket prefix (3 x 79) + bcur init
__global__ void k_bscan(Csr3 c) {
    __shared__ int sh[3 * NBUK];
    int t = threadIdx.x;
    for (int i = t; i < 3 * NBUK; i += 256) sh[i] = c.btot[i];
    __syncthreads();
    if (t < 3) {
        int run = 0;
        int* bs = c.bstart + t * (NBUK + 1);
        for (int b = 0; b < NBUK; b++) {
            bs[b] = run;
            c.bcur[t * NBUK + b] = run;
            run += sh[t * NBUK + b];
        }
        bs[NBUK] = run;   // == E_EDGES
    }
}

// Pass A: partition edges into NBUK buckets; dense (key,payload) runs into tmp.
__global__ __launch_bounds__(256) void k_bucketA(Csr3 c) {
    __shared__ int hist[NBUK], base[NBUK], off[NBUK];
    const int y = blockIdx.y;
    const int chunk0 = blockIdx.x * 4096;
    const int t = threadIdx.x;
    for (int i = t; i < NBUK; i += 256) { hist[i] = 0; off[i] = 0; }
    __syncthreads();
    int keys[16], vals[16], bks[16];
#pragma unroll
    for (int i = 0; i < 16; i++) {
        int e = chunk0 + (i << 8) + t;
        bool ok = (e < E_EDGES);
        int k = ok ? c.key[y][e] : 0;
        keys[i] = k;
        vals[i] = ok ? ((y == 2) ? e : c.other[y][e]) : 0;
        bks[i] = ok ? (k >> 8) : -1;
        if (ok) atomicAdd(&hist[k >> 8], 1);
    }
    __syncthreads();
    if (t < NBUK && hist[t] > 0) base[t] = atomicAdd(&c.bcur[y * NBUK + t], hist[t]);
    __syncthreads();
    int2* ty = c.tmp + (size_t)y * E_EDGES;
#pragma unroll
    for (int i = 0; i < 16; i++) {
        int b = bks[i];
        if (b >= 0) {
            int o = atomicAdd(&off[b], 1);
            ty[base[b] + o] = make_int2(keys[i], vals[i]);
        }
    }
}

// Pass B: one workgroup per (bucket, csr). Per-node counts + prefix in LDS;
// WRITES node-level rowptr; places payloads within the bucket's span.
__global__ __launch_bounds__(256) void k_bucketB(Csr3 c) {
    __shared__ int cnt[256], lbase[256], run[256];
    const int y = blockIdx.y;
    const int b = blockIdx.x;
    const int nbase = b << 8;
    const int t = threadIdx.x;
    cnt[t] = 0; run[t] = 0;
    __syncthreads();
    const int bs = c.bstart[y * (NBUK + 1) + b];
    const int be = c.bstart[y * (NBUK + 1) + b + 1];
    const int2* ty = c.tmp + (size_t)y * E_EDGES;
    for (int i = bs + t; i < be; i += 256)
        atomicAdd(&cnt[ty[i].x - nbase], 1);
    __syncthreads();
    int v = cnt[t];
    lbase[t] = v;
    __syncthreads();
    for (int off = 1; off < 256; off <<= 1) {
        int u = (t >= off) ? lbase[t - off] : 0;
        __syncthreads();
        lbase[t] += u;
        __syncthreads();
    }
    int excl = lbase[t] - v;
    __syncthreads();
    lbase[t] = excl;
    __syncthreads();
    int n = nbase + t;
    if (n < N_NODES) c.rowptr[y][n] = bs + excl;
    if (b == NBUK - 1 && t == 0) c.rowptr[y][N_NODES] = E_EDGES;
    int* outy = c.out[y];
    for (int i = bs + t; i < be; i += 256) {
        int2 kv = ty[i];
        int k = kv.x - nbase;
        int o = atomicAdd(&run[k], 1);
        outy[bs + lbase[k] + o] = kv.y;
    }
}

// ===== GANConv0 aggregation: z[n] = bf16(x[n] + sum x[srcs]) , fp32 input =====
__global__ __launch_bounds__(256) void k_gather_f32(const float4* __restrict__ x,
                                                    const int* __restrict__ rowptr,
                                                    const int* __restrict__ srcs,
                                                    unsigned short* __restrict__ z) {
    int gid = blockIdx.x * blockDim.x + threadIdx.x;
    int n = gid >> 4;
    if (n >= N_NODES) return;
    int q = gid & 15;
    float4 acc = x[((size_t)n << 4) + q];
    int p1 = rowptr[n + 1];
    for (int p = rowptr[n]; p < p1; p++) {
        float4 v = x[((size_t)srcs[p] << 4) + q];
        acc.x += v.x; acc.y += v.y; acc.z += v.z; acc.w += v.w;
    }
    ushort4 o;
    o.x = f2bf(acc.x); o.y = f2bf(acc.y); o.z = f2bf(acc.z); o.w = f2bf(acc.w);
    *(ushort4*)&z[((size_t)n << 6) + (q << 2)] = o;
}

// ===== GANConv1 aggregation with fused BN+relu on load =====
__global__ __launch_bounds__(256) void k_gather_bn(const u16x8* __restrict__ raw,
                                                   const int* __restrict__ rowptr,
                                                   const int* __restrict__ srcs,
                                                   const float* __restrict__ bn_sums,
                                                   const float* __restrict__ g,
                                                   const float* __restrict__ b,
                                                   u16x8* __restrict__ z) {
    int gid = blockIdx.x * blockDim.x + threadIdx.x;
    int n = gid >> 4;
    if (n >= N_NODES) return;
    int q = gid & 15;
    float sc[8], sh[8];
#pragma unroll
    for (int i = 0; i < 8; i++) {
        int c = (q << 3) + i;
        float mean = bn_sums[c] / N_NODES;
        float istd = rsqrtf(bn_sums[HID + c] / N_NODES - mean * mean + EPSV);
        float s = istd * g[c];
        sc[i] = s;
        sh[i] = b[c] - mean * s;
    }
    u16x8 u0 = raw[((size_t)n << 4) + q];
    float acc[8];
#pragma unroll
    for (int i = 0; i < 8; i++) acc[i] = fmaxf(bf2f(u0[i]) * sc[i] + sh[i], 0.f);
    int p1 = rowptr[n + 1];
    for (int p = rowptr[n]; p < p1; p++) {
        u16x8 v = raw[((size_t)srcs[p] << 4) + q];
#pragma unroll
        for (int i = 0; i < 8; i++) acc[i] += fmaxf(bf2f(v[i]) * sc[i] + sh[i], 0.f);
    }
    u16x8 o;
#pragma unroll
    for (int i = 0; i < 8; i++) o[i] = f2bf(acc[i]);
    z[((size_t)n << 4) + q] = o;
}

// ===== weight prep: Wt[n][k] = bf16(W[k][n]) for 8 weights in one launch =====
struct WtJob  { const float* src; unsigned short* dst; int K; int N; };
struct WtJobs { WtJob j[8]; };
__global__ void k_wt_cast(WtJobs jobs) {
    WtJob jb = jobs.j[blockIdx.y];
    int total = jb.K * jb.N;
    for (int i = blockIdx.x * blockDim.x + threadIdx.x; i < total; i += gridDim.x * blockDim.x) {
        int nn = i / jb.K, kk = i - nn * jb.K;
        jb.dst[i] = f2bf(jb.src[(size_t)kk * jb.N + nn]);
    }
}

// ===== MFMA bf16 GEMM: C[M,N] = A'[M,K] @ Wt[N,K]^T + bias; bf16 out =====
template <int STATS, int BNA, int TM, int BIAS2>
__global__ __launch_bounds__(256) void k_mfma_gemm(const unsigned short* __restrict__ A,
                                                   const unsigned short* __restrict__ Wt,
                                                   const float* __restrict__ biasL,
                                                   const float* __restrict__ biasR,
                                                   unsigned short* __restrict__ Cout,
                                                   int M, int K, int N,
                                                   float* __restrict__ stats_sums,
                                                   const float* __restrict__ bn_sums,
                                                   const float* __restrict__ bn_g,
                                                   const float* __restrict__ bn_b) {
    constexpr int BNF = (TM == 128) ? 4 : 2;      // n-frags per wave
    __shared__ unsigned short As[TM][40];
    __shared__ unsigned short Bs[128][40];
    __shared__ float s_scale[BNA ? HID : 1], s_shift[BNA ? HID : 1];
    const int t = threadIdx.x;
    if (BNA) {
        if (t < HID) {
            float mean = bn_sums[t] / M;
            float istd = rsqrtf(bn_sums[HID + t] / M - mean * mean + EPSV);
            float s = istd * bn_g[t];
            s_scale[t] = s;
            s_shift[t] = bn_b[t] - mean * s;
        }
        __syncthreads();
    }
    const int wave = t >> 6, lane = t & 63;
    const int row0 = blockIdx.y * TM, col0 = blockIdx.x * 128;
    const int wm = (TM == 128) ? ((wave & 1) << 6) : 0;
    const int wn = (TM == 128) ? ((wave >> 1) << 6) : (wave << 5);
    const int lm = lane & 15, lk = (lane >> 4) << 3;
    constexpr int APASS = TM / 64;
    f32x4 acc[4][BNF] = {};
    for (int k0 = 0; k0 < K; k0 += 32) {
        u16x8 av[APASS], wv[2];
#pragma unroll
        for (int i = 0; i < APASS; i++) {
            int c = t + (i << 8);
            int r = c >> 2, ko = (c & 3) << 3;
            u16x8 zv = {};
            int gr = row0 + r;
            av[i] = (gr < M) ? *(const u16x8*)&A[(size_t)gr * K + k0 + ko] : zv;
            if (BNA) {
#pragma unroll
                for (int j = 0; j < 8; j++) {
                    int kc = k0 + ko + j;
                    float v = fmaxf(bf2f(av[i][j]) * s_scale[kc] + s_shift[kc], 0.f);
                    av[i][j] = f2bf(v);
                }
            }
        }
#pragma unroll
        for (int i = 0; i < 2; i++) {
            int c = t + (i << 8);
            int r = c >> 2, ko = (c & 3) << 3;
            wv[i] = *(const u16x8*)&Wt[(size_t)(col0 + r) * K + k0 + ko];
        }
        __syncthreads();
#pragma unroll
        for (int i = 0; i < APASS; i++) {
            int c = t + (i << 8);
            int r = c >> 2, ko = (c & 3) << 3;
            *(u16x8*)&As[r][ko] = av[i];
        }
#pragma unroll
        for (int i = 0; i < 2; i++) {
            int c = t + (i << 8);
            int r = c >> 2, ko = (c & 3) << 3;
            *(u16x8*)&Bs[r][ko] = wv[i];
        }
        __syncthreads();
        bf16x8 af[4], bfm[BNF];
#pragma unroll
        for (int i = 0; i < 4; i++) af[i]  = *(const bf16x8*)&As[wm + (i << 4) + lm][lk];
#pragma unroll
        for (int j = 0; j < BNF; j++) bfm[j] = *(const bf16x8*)&Bs[wn + (j << 4) + lm][lk];
#pragma unroll
        for (int i = 0; i < 4; i++)
#pragma unroll
            for (int j = 0; j < BNF; j++)
                acc[i][j] = __builtin_amdgcn_mfma_f32_16x16x32_bf16(af[i], bfm[j], acc[i][j], 0, 0, 0);
    }
    const int lr4 = (lane >> 4) << 2;
    float s1[BNF], s2[BNF];
#pragma unroll
    for (int j = 0; j < BNF; j++) { s1[j] = 0.f; s2[j] = 0.f; }
#pragma unroll
    for (int j = 0; j < BNF; j++) {
        int col = col0 + wn + (j << 4) + lm;
        float bv = BIAS2 ? ((col < 256) ? biasL[col] : biasR[col - 256]) : biasL[col];
#pragma unroll
        for (int i = 0; i < 4; i++) {
#pragma unroll
            for (int r = 0; r < 4; r++) {
                int row = row0 + wm + (i << 4) + lr4 + r;
                if (row < M) {
                    float v = acc[i][j][r] + bv;
                    Cout[(size_t)row * N + col] = f2bf(v);
                    if (STATS) { s1[j] += v; s2[j] += v * v; }
                }
            }
        }
    }
    if (STATS) {
#pragma unroll
        for (int j = 0; j < BNF; j++) {
            s1[j] += __shfl_xor(s1[j], 16, 64); s1[j] += __shfl_xor(s1[j], 32, 64);
            s2[j] += __shfl_xor(s2[j], 16, 64); s2[j] += __shfl_xor(s2[j], 32, 64);
        }
        if ((lane >> 4) == 0) {
#pragma unroll
            for (int j = 0; j < BNF; j++) {
                int col = col0 + wn + (j << 4) + lm;   // < 128 for stats GEMMs
                atomicAdd(&stats_sums[col], s1[j]);
                atomicAdd(&stats_sums[HID + col], s2[j]);
            }
        }
    }
}

// ========== fused ATTConv (GATv2): single-pass flash-style online softmax ==========
// One wave per node; lane l -> channels 4l..4l+3, head h = l>>5.
// Q is the merged projection buffer [N,512]: xl = row[0:256), xr = row[256:512).
// Unroll-4 with GROUP-WISE online update: one max/rescale per 4 edges.
#define ATT_CAP 192
template <int CONCAT, int WITH_ALPHA>
__global__ __launch_bounds__(256) void k_att_fused(const ushort4* __restrict__ Q,
                                                   const int* __restrict__ rowptr,
                                                   const int* __restrict__ plist,
                                                   const int* __restrict__ other,
                                                   const float* __restrict__ att,
                                                   const float* __restrict__ bias,
                                                   void* __restrict__ outp,
                                                   float* __restrict__ alpha_out) {
    __shared__ float s_lg[4][ATT_CAP][2];
    const int t = threadIdx.x;
    const int wave = t >> 6, l = t & 63;
    const int n = blockIdx.x * 4 + wave;   // N_NODES % 4 == 0
    const int h = l >> 5;
    ushort4 ur = Q[((size_t)n << 7) + 64 + l];   // xr slice
    float xr4[4] = {bf2f(ur.x), bf2f(ur.y), bf2f(ur.z), bf2f(ur.w)};
    const float* ap = &att[h * HID + ((l & 31) << 2)];
    float at4[4] = {ap[0], ap[1], ap[2], ap[3]};
    const int p0 = rowptr[n], p1 = rowptr[n + 1];

    float m = -INFINITY, ssum = 0.f;
    float acc[4] = {0.f, 0.f, 0.f, 0.f};

#define ATT_SRC(p) (WITH_ALPHA ? other[plist[p]] : plist[p])

#define ATT_LOGIT(uv, x4, tl) do { \
        x4[0] = bf2f(uv.x); x4[1] = bf2f(uv.y); x4[2] = bf2f(uv.z); x4[3] = bf2f(uv.w); \
        float v0 = x4[0] + xr4[0]; v0 = (v0 > 0.f) ? v0 : 0.2f * v0; \
        float v1 = x4[1] + xr4[1]; v1 = (v1 > 0.f) ? v1 : 0.2f * v1; \
        float v2 = x4[2] + xr4[2]; v2 = (v2 > 0.f) ? v2 : 0.2f * v2; \
        float v3 = x4[3] + xr4[3]; v3 = (v3 > 0.f) ? v3 : 0.2f * v3; \
        tl = at4[0] * v0 + at4[1] * v1 + at4[2] * v2 + at4[3] * v3; \
    } while (0)

#define ATT_ONLINE(x4, tl, idx) do { \
        float mn = fmaxf(m, tl); \
        float sc = __expf(m - mn); \
        float w  = __expf(tl - mn); \
        ssum = ssum * sc + w; \
        acc[0] = acc[0] * sc + w * x4[0]; \
        acc[1] = acc[1] * sc + w * x4[1]; \
        acc[2] = acc[2] * sc + w * x4[2]; \
        acc[3] = acc[3] * sc + w * x4[3]; \
        m = mn; \
        if (WITH_ALPHA && (idx) < ATT_CAP && (l & 31) == 0) s_lg[wave][idx][h] = tl; \
    } while (0)

    int p = p0;
    for (; p + 4 <= p1; p += 4) {
        float x4[4][4], tl[4];
        ushort4 uv[4];
        int ss[4];
#pragma unroll
        for (int j = 0; j < 4; j++) ss[j] = ATT_SRC(p + j);
#pragma unroll
        for (int j = 0; j < 4; j++) uv[j] = Q[((size_t)ss[j] << 7) + l];
#pragma unroll
        for (int j = 0; j < 4; j++) ATT_LOGIT(uv[j], x4[j], tl[j]);
#pragma unroll
        for (int k = 1; k <= 16; k <<= 1) {
#pragma unroll
            for (int j = 0; j < 4; j++) tl[j] += __shfl_xor(tl[j], k, 64);
        }
        if (WITH_ALPHA && (l & 31) == 0) {
#pragma unroll
            for (int j = 0; j < 4; j++)
                if (p + j - p0 < ATT_CAP) s_lg[wave][p + j - p0][h] = tl[j];
        }
        // group-wise online update: ONE max + ONE rescale per 4 edges
        float tmax = fmaxf(fmaxf(tl[0], tl[1]), fmaxf(tl[2], tl[3]));
        float mn = fmaxf(m, tmax);
        float sc = __expf(m - mn);
        float w0 = __expf(tl[0] - mn), w1 = __expf(tl[1] - mn);
        float w2 = __expf(tl[2] - mn), w3 = __expf(tl[3] - mn);
        ssum = ssum * sc + (w0 + w1 + w2 + w3);
#pragma unroll
        for (int c = 0; c < 4; c++)
            acc[c] = acc[c] * sc + w0 * x4[0][c] + w1 * x4[1][c] + w2 * x4[2][c] + w3 * x4[3][c];
        m = mn;
    }
    for (; p < p1; p++) {
        float x4[4], tl;
        ushort4 uv = Q[((size_t)ATT_SRC(p) << 7) + l];
        ATT_LOGIT(uv, x4, tl);
#pragma unroll
        for (int k = 1; k <= 16; k <<= 1) tl += __shfl_xor(tl, k, 64);
        ATT_ONLINE(x4, tl, p - p0);
    }
    float inv = 1.f / (ssum + 1e-16f);

    // ---- alpha output (att2): parallel from LDS cache ----
    if (WITH_ALPHA) {
        float m_o   = __shfl_xor(m, 32, 64);
        float inv_o = __shfl_xor(inv, 32, 64);
        float m2[2], i2[2];
        m2[h] = m; m2[1 - h] = m_o;
        i2[h] = inv; i2[1 - h] = inv_o;
        int cnt = p1 - p0;
        int ccnt = (cnt < ATT_CAP) ? cnt : ATT_CAP;
        for (int i = l; i < ccnt * 2; i += 64) {
            int idx = i >> 1, hh = i & 1;
            float a = __expf(s_lg[wave][idx][hh] - m2[hh]) * i2[hh];
            alpha_out[plist[p0 + idx] * HEADS + hh] = a;
        }
        // overflow fallback (deg > ATT_CAP): serial recompute (practically never taken)
        for (int pp = p0 + ATT_CAP; pp < p1; pp++) {
            float x4[4], tl;
            ushort4 uv = Q[((size_t)ATT_SRC(pp) << 7) + l];
            ATT_LOGIT(uv, x4, tl);
#pragma unroll
            for (int k = 1; k <= 16; k <<= 1) tl += __shfl_xor(tl, k, 64);
            if ((l & 31) == 0) alpha_out[plist[pp] * HEADS + h] = __expf(tl - m) * inv;
        }
    }

    // ---- epilogue ----
    if (CONCAT) {
        const float* bp = &bias[l << 2];
        ushort4 o;
        o.x = f2bf(fmaxf(acc[0] * inv + bp[0], 0.f));
        o.y = f2bf(fmaxf(acc[1] * inv + bp[1], 0.f));
        o.z = f2bf(fmaxf(acc[2] * inv + bp[2], 0.f));
        o.w = f2bf(fmaxf(acc[3] * inv + bp[3], 0.f));
        ((ushort4*)outp)[((size_t)n << 6) + l] = o;
    } else {
        float o[4];
#pragma unroll
        for (int i = 0; i < 4; i++) {
            float v = acc[i] * inv;
            float other_v = __shfl_xor(v, 32, 64);
            o[i] = 0.5f * (v + other_v);
        }
        if (l < 32) {
            const float* bp = &bias[(l & 31) << 2];
            float4 ov;
            ov.x = fmaxf(o[0] + bp[0], 0.f); ov.y = fmaxf(o[1] + bp[1], 0.f);
            ov.z = fmaxf(o[2] + bp[2], 0.f); ov.w = fmaxf(o[3] + bp[3], 0.f);
            ((float4*)outp)[((size_t)n << 5) + l] = ov;
        }
    }
#undef ATT_SRC
#undef ATT_LOGIT
#undef ATT_ONLINE
}

// ================= pooling over sorted batch_index (node-parallel) =================
template <int C>
__global__ __launch_bounds__(256) void k_pool_atomic(const float* __restrict__ X,
                                                     const int* __restrict__ batch,
                                                     float* __restrict__ pool, int npb) {
    const int RP = 256 / C;
    int c = threadIdx.x & (C - 1);
    int rofs = threadIdx.x / C;
    int i0 = blockIdx.x * npb;
    int i1 = min(i0 + npb, N_NODES);
    float acc = 0.f;
    int gcur = -1;
    for (int i = i0 + rofs; i < i1; i += RP) {
        int g = batch[i];
        if (g != gcur) {
            if (gcur >= 0) atomicAdd(&pool[gcur * C + c], acc);
            acc = 0.f; gcur = g;
        }
        acc += X[(size_t)i * C + c];
    }
    if (gcur >= 0) atomicAdd(&pool[gcur * C + c], acc);
}

// ================= final prediction head =================
__global__ void k_head(const float* __restrict__ pool0, const float* __restrict__ poolL,
                       const float* __restrict__ p0w, const float* __restrict__ p0b,
                       const float* __restrict__ pLw, const float* __restrict__ pLb,
                       const float* __restrict__ ow, const float* __restrict__ ob,
                       float* __restrict__ outputs) {
    int g = blockIdx.x;
    int m = threadIdx.x;
    __shared__ float sh[MIDD];
    if (m < MIDD) {
        float s = p0b[m] + pLb[m];
        for (int k = 0; k < F_INN; k++) s += pool0[g * F_INN + k] * p0w[k * MIDD + m];
        for (int k = 0; k < HID; k++)  s += poolL[g * HID + k] * pLw[k * MIDD + m];
        sh[m] = fmaxf(s, 0.f);
    }
    __syncthreads();
    if (m == 0) {
        float s = ob[0];
        for (int k = 0; k < MIDD; k++) s += sh[k] * ow[k];
        outputs[g] = s;
    }
}

extern "C" void kernel_launch(void* const* d_in, const int* in_sizes, int n_in,
                              void* d_out, int out_size, void* d_ws, size_t ws_size,
                              hipStream_t stream) {
    // ---- inputs ----
    const float* x      = (const float*)d_in[0];
    const int*   ei     = (const int*)d_in[1];
    const int*   aei    = (const int*)d_in[2];
    const int*   batch  = (const int*)d_in[3];
    const float* g0_w1  = (const float*)d_in[4];
    const float* g0_b1  = (const float*)d_in[5];
    const float* g0_bng = (const float*)d_in[6];
    const float* g0_bnb = (const float*)d_in[7];
    const float* g0_w2  = (const float*)d_in[8];
    const float* g0_b2  = (const float*)d_in[9];
    const float* g1_w1  = (const float*)d_in[10];
    const float* g1_b1  = (const float*)d_in[11];
    const float* g1_bng = (const float*)d_in[12];
    const float* g1_bnb = (const float*)d_in[13];
    const float* g1_w2  = (const float*)d_in[14];
    const float* g1_b2  = (const float*)d_in[15];
    const float* bn0_g  = (const float*)d_in[16];
    const float* bn0_b  = (const float*)d_in[17];
    const float* bn1_g  = (const float*)d_in[18];
    const float* bn1_b  = (const float*)d_in[19];
    const float* a1_wl  = (const float*)d_in[20];
    const float* a1_bl  = (const float*)d_in[21];
    const float* a1_wr  = (const float*)d_in[22];
    const float* a1_br  = (const float*)d_in[23];
    const float* a1_att = (const float*)d_in[24];
    const float* a1_bias= (const float*)d_in[25];
    const float* a2_wl  = (const float*)d_in[26];
    const float* a2_bl  = (const float*)d_in[27];
    const float* a2_wr  = (const float*)d_in[28];
    const float* a2_br  = (const float*)d_in[29];
    const float* a2_att = (const float*)d_in[30];
    const float* a2_bias= (const float*)d_in[31];
    const float* p0w    = (const float*)d_in[32];
    const float* p0b    = (const float*)d_in[33];
    const float* pLw    = (const float*)d_in[34];
    const float* pLb    = (const float*)d_in[35];
    const float* ow     = (const float*)d_in[36];
    const float* ob     = (const float*)d_in[37];

    // ---- outputs ----
    float* out_head  = (float*)d_out;
    float* atten_out = out_head + G_GR;
    float* alpha_out = atten_out + (size_t)N_NODES * HID;

    // ---- workspace ----
    float* ws = (float*)d_ws;
    float* sums4 = ws;                                 // 4*256 (s0|s1|s2|s3)
    float* pool0 = sums4 + 4 * 256;                    // G*64
    float* poolL = pool0 + G_GR * F_INN;               // G*128
    int*   btot  = (int*)(poolL + G_GR * HID);         // 3*NBUK (zeroed)
    const size_t zero_bytes = (4 * 256 + G_GR * F_INN + G_GR * HID + 3 * NBUK) * 4;

    int* ip = btot + 3 * NBUK;
    int* bstart = ip; ip += 3 * (NBUK + 1);
    int* bcur   = ip; ip += 3 * NBUK;
    int* rowptr[3]; int* payload[3];
    for (int c = 0; c < 3; c++) {
        rowptr[c]  = ip; ip += N_NODES + 1;
        payload[c] = ip; ip += E_EDGES;
    }
    int2* tmp3 = (int2*)ip; ip += 2 * 3 * E_EDGES;     // [3][E] int2
    const size_t NB = (size_t)N_NODES * HC;
    unsigned short* B1 = (unsigned short*)ip;          // [N,HC] bf16
    unsigned short* B2 = B1 + NB;                      // [N,HC] bf16
    unsigned short* Qb = B2 + NB;                      // [N,512] bf16 merged projections
    unsigned short* g0w1t = Qb + 2 * NB;
    unsigned short* g0w2t = g0w1t + 128 * 64;
    unsigned short* g1w1t = g0w2t + 128 * 128;
    unsigned short* g1w2t = g1w1t + 128 * 128;
    unsigned short* a1wlt = g1w2t + 128 * 128;         // [256,128]
    unsigned short* a1wrt = a1wlt + 256 * 128;         // contiguous -> [512,128]
    unsigned short* a2wlt = a1wrt + 256 * 128;         // [256,256]
    unsigned short* a2wrt = a2wlt + 256 * 256;         // contiguous -> [512,256]

    const int* e_row = ei;
    const int* e_col = ei + E_EDGES;
    const int* a_src = aei;
    const int* a_dst = aei + E_EDGES;

    const int TB = 256;
#define GRID1(n) dim3(CDIV((n), TB))

    // ===== weight transpose+cast =====
    {
        WtJobs jobs;
        jobs.j[0] = {g0_w1, g0w1t, F_INN, HID};
        jobs.j[1] = {g0_w2, g0w2t, HID,   HID};
        jobs.j[2] = {g1_w1, g1w1t, HID,   HID};
        jobs.j[3] = {g1_w2, g1w2t, HID,   HID};
        jobs.j[4] = {a1_wl, a1wlt, HID,   HC};
        jobs.j[5] = {a1_wr, a1wrt, HID,   HC};
        jobs.j[6] = {a2_wl, a2wlt, HC,    HC};
        jobs.j[7] = {a2_wr, a2wrt, HC,    HC};
        k_wt_cast<<<dim3(32, 8), TB, 0, stream>>>(jobs);
    }

    // ===== zero sums/pools/btot in one shot; build 3 CSRs (bucket-granular) =====
    hipMemsetAsync(sums4, 0, zero_bytes, stream);
    {
        Csr3 c;
        c.key[0] = e_row; c.other[0] = e_col;
        c.key[1] = e_col; c.other[1] = e_row;
        c.key[2] = a_dst; c.other[2] = a_src;
        c.btot = btot; c.bstart = bstart; c.bcur = bcur; c.tmp = tmp3;
        for (int i = 0; i < 3; i++) { c.rowptr[i] = rowptr[i]; c.out[i] = payload[i]; }
        k_bhist<<<dim3(CDIV(E_EDGES, 4096), 3), TB, 0, stream>>>(c);
        k_bscan<<<dim3(1), TB, 0, stream>>>(c);
        k_bucketA<<<dim3(CDIV(E_EDGES, 4096), 3), TB, 0, stream>>>(c);
        k_bucketB<<<dim3(NBUK, 3), TB, 0, stream>>>(c);
    }

    const dim3 gemm_g1(1, CDIV(N_NODES, 64));    // N=128, TM=64 (313 blocks)
    const dim3 gemm_gq(4, CDIV(N_NODES, 128));   // N=512, TM=128 (628 blocks)
    const float* NOF = nullptr;

    // ===== GANConv 0 (ping-pong B1/B2 as [N,128]) =====
    k_gather_f32<<<GRID1(N_NODES * 16), TB, 0, stream>>>((const float4*)x, rowptr[0], payload[0], B1);
    k_mfma_gemm<1, 0, 64, 0><<<gemm_g1, TB, 0, stream>>>(B1, g0w1t, g0_b1, NOF, B2, N_NODES, F_INN, HID,
                                                         sums4 + 0, NOF, NOF, NOF);
    k_mfma_gemm<1, 1, 64, 0><<<gemm_g1, TB, 0, stream>>>(B2, g0w2t, g0_b2, NOF, B1, N_NODES, HID, HID,
                                                         sums4 + 256, sums4 + 0, g0_bng, g0_bnb);
    // raw2 (pre-bn0) in B1

    // ===== GANConv 1 =====
    k_gather_bn<<<GRID1(N_NODES * 16), TB, 0, stream>>>((const u16x8*)B1, rowptr[0], payload[0],
                                                        sums4 + 256, bn0_g, bn0_b, (u16x8*)B2);
    k_mfma_gemm<1, 0, 64, 0><<<gemm_g1, TB, 0, stream>>>(B2, g1w1t, g1_b1, NOF, B1, N_NODES, HID, HID,
                                                         sums4 + 512, NOF, NOF, NOF);
    k_mfma_gemm<1, 1, 64, 0><<<gemm_g1, TB, 0, stream>>>(B1, g1w2t, g1_b2, NOF, B2, N_NODES, HID, HID,
                                                         sums4 + 768, sums4 + 512, g1_bng, g1_bnb);
    // raw4 (pre-bn1 = h2 raw) in B2

    // ===== ATTConv 1 (dst=e_col, concat=True): merged wl|wr GEMM -> Q [N,512] =====
    k_mfma_gemm<0, 1, 128, 1><<<gemm_gq, TB, 0, stream>>>(B2, a1wlt, a1_bl, a1_br, Qb, N_NODES, HID, 512,
                                                          nullptr, sums4 + 768, bn1_g, bn1_b);
    k_att_fused<1, 0><<<dim3(N_NODES / 4), TB, 0, stream>>>(
        (const ushort4*)Qb, rowptr[1], payload[1], nullptr, a1_att, a1_bias, (void*)B1, nullptr);
    // emb bf16 in B1 [N,HC]

    // ===== ATTConv 2 (dst=a_dst, concat=False): merged GEMM K=256 -> Q =====
    k_mfma_gemm<0, 0, 128, 1><<<gemm_gq, TB, 0, stream>>>(B1, a2wlt, a2_bl, a2_br, Qb, N_NODES, HC, 512,
                                                          nullptr, NOF, NOF, NOF);
    k_att_fused<0, 1><<<dim3(N_NODES / 4), TB, 0, stream>>>(
        (const ushort4*)Qb, rowptr[2], payload[2], a_src, a2_att, a2_bias, (void*)atten_out, alpha_out);

    // ===== pooling + head =====
    {
        const int npb = 64;  // 313 blocks
        k_pool_atomic<F_INN><<<dim3(CDIV(N_NODES, npb)), TB, 0, stream>>>(x, batch, pool0, npb);
        k_pool_atomic<HID><<<dim3(CDIV(N_NODES, npb)), TB, 0, stream>>>(atten_out, batch, poolL, npb);
    }
    k_head<<<dim3(G_GR), 64, 0, stream>>>(pool0, poolL, p0w, p0b, pLw, pLb, ow, ob, out_head);
}